// Round 2
// 600.771 us; speedup vs baseline: 1.5276x; 1.5276x over previous
//
#include <hip/hip_runtime.h>
#include <hip/hip_bf16.h>
#include <math.h>

#define B_    4
#define C_    192
#define NPT   3136          // H*W points per batch
#define CO_   384           // Cout
#define KNN   9
#define CAND  64            // 4 j-chunks * merged top-16 per row
#define NROWS (B_*NPT)      // 12544 total points
#define SD    10            // per-lane screening stream depth

typedef _Float16 half8 __attribute__((ext_vector_type(8)));
typedef float    f32x4 __attribute__((ext_vector_type(4)));

__device__ __forceinline__ float u2f(unsigned short u) {
    unsigned int t = ((unsigned int)u) << 16;
    float f; __builtin_memcpy(&f, &t, 4); return f;
}
__device__ __forceinline__ unsigned short f2u(float f) {
    __hip_bfloat16 h = __float2bfloat16(f);
    unsigned short u; __builtin_memcpy(&u, &h, 2); return u;
}

// ---------------------------------------------------------------------------
// K1: per-point f64 norm stats from fp32 x.
// ---------------------------------------------------------------------------
__global__ __launch_bounds__(256) void k_norm(
    const float* __restrict__ x,
    float* __restrict__ invn32, double* __restrict__ invn64,
    double* __restrict__ sqd)
{
    int p = blockIdx.x * 256 + threadIdx.x;
    if (p >= NROWS) return;
    int b = p / NPT, n = p % NPT;
    const float* xb = x + (size_t)b * C_ * NPT + n;
    double S = 0.0;
    for (int c = 0; c < C_; ++c) {
        double v = (double)xb[(size_t)c * NPT];
        S = fma(v, v, S);
    }
    double nrm = sqrt(S);
    if (nrm < 1e-12) nrm = 1e-12;
    double iv = 1.0 / nrm;
    invn64[p] = iv;
    invn32[p] = (float)iv;
    sqd[p] = iv * iv * S;
}

// ---------------------------------------------------------------------------
// K1b: LDS-tiled transpose x [b][c][n] -> xT [b*NPT+n][c] (fp32, exact).
// ---------------------------------------------------------------------------
__global__ __launch_bounds__(256) void k_xpose(
    const float* __restrict__ x, float* __restrict__ xT)
{
    __shared__ float t[32][33];
    int blk = blockIdx.x;
    int b  = blk / 588;
    int r  = blk % 588;
    int ct = r / 98, nt = r % 98;
    int c0 = ct * 32, n0 = nt * 32;
    int tid = threadIdx.x;
    int tx = tid & 31, ty8 = tid >> 5;          // 8 rows per pass
    const float* xb = x + (size_t)b * C_ * NPT;
#pragma unroll
    for (int e = 0; e < 4; ++e) {
        int cc = ty8 + e * 8;
        t[cc][tx] = xb[(size_t)(c0 + cc) * NPT + n0 + tx];
    }
    __syncthreads();
#pragma unroll
    for (int e = 0; e < 4; ++e) {
        int nn = ty8 + e * 8;
        xT[(size_t)(b * NPT + n0 + nn) * C_ + c0 + tx] = t[tx][nn];
    }
}

// ---------------------------------------------------------------------------
// K1c: pack normalized fp16 fragments for MFMA screening.
//   packed[(b*196+t16)*6 + kk][lane][e] = xn[b][t16*16 + (lane&15)]
//                                           [kk*32 + (lane>>4)*8 + e]
//   One thread per (b,t16,kk,lane): reads 32B from xT, writes 16B coalesced.
// ---------------------------------------------------------------------------
__global__ __launch_bounds__(256) void k_pack(
    const float* __restrict__ xT, const float* __restrict__ invn32,
    _Float16* __restrict__ packed)
{
    int t = blockIdx.x * 256 + threadIdx.x;    // 0 .. 301055
    if (t >= B_ * 196 * 6 * 64) return;
    int l  = t & 63;
    int tk = t >> 6;            // (b*196 + t16)*6 + kk
    int kk = tk % 6;
    int bt = tk / 6;            // b*196 + t16  (NPT = 196*16, so bt*16 = b*NPT + t16*16)
    int row = bt * 16 + (l & 15);
    int kbase = kk * 32 + (l >> 4) * 8;
    const float* src = xT + (size_t)row * C_ + kbase;
    float iv = invn32[row];
    float4 v0 = *(const float4*)src;
    float4 v1 = *(const float4*)(src + 4);
    half8 h;
    h[0] = (_Float16)(v0.x * iv); h[1] = (_Float16)(v0.y * iv);
    h[2] = (_Float16)(v0.z * iv); h[3] = (_Float16)(v0.w * iv);
    h[4] = (_Float16)(v1.x * iv); h[5] = (_Float16)(v1.y * iv);
    h[6] = (_Float16)(v1.z * iv); h[7] = (_Float16)(v1.w * iv);
    *(half8*)(packed + (size_t)t * 8) = h;
}

// ---------------------------------------------------------------------------
// K2 (MFMA): fp16 matrix-core screening.
//   Block = 256 thr (4 waves), grid = B * 49 i-tiles(64) * 4 chunks.
//   Wave w owns i-tile16 (itile*4+w); iterates all j-tile16 of its chunk.
//   D = mfma(A=Xj_tile, B=Xi_tile): lane holds col i = lane&15,
//   rows j = (lane>>4)*4 + q  (guide-verified 16x16x32 C/D layout).
//   Per-lane stream = 4 j per tile -> depth-10 list; any true top-9 point
//   has <=8 stream-mates above it, so depth 10 + 4-way merge-16 retains it.
//   cand layout identical to previous k_screen3 -> k_refine unchanged.
// ---------------------------------------------------------------------------
__global__ __launch_bounds__(256) void k_screen_mfma(
    const _Float16* __restrict__ packed, unsigned short* __restrict__ cand)
{
    __shared__ float md[64][4][SD];
    __shared__ int   mi[64][4][SD];
    int blk   = blockIdx.x;
    int chunk = blk & 3;
    int t2    = blk >> 2;
    int b     = t2 / 49;
    int itile = t2 % 49;                 // 64-row i tile
    int tid   = threadIdx.x;
    int wave  = tid >> 6, lane = tid & 63;
    int it    = itile * 4 + wave;        // global 16-row tile within batch

    // B fragments (Xi rows), loaded once: 6 x 1KB coalesced wave loads.
    const _Float16* pb = packed + ((size_t)(b * 196 + it) * 6) * 512 + lane * 8;
    half8 bf[6];
#pragma unroll
    for (int kk = 0; kk < 6; ++kk)
        bf[kk] = *(const half8*)(pb + kk * 512);

    int jt0 = chunk * 48;                 // chunks: 768,768,768,832 cols
    int ntj = (chunk == 3) ? 52 : 48;

    float bd[SD]; int bi[SD];
#pragma unroll
    for (int q = 0; q < SD; ++q) { bd[q] = -1e30f; bi[q] = 0; }

    const _Float16* pa_base =
        packed + ((size_t)(b * 196 + jt0) * 6) * 512 + lane * 8;
    for (int jt = 0; jt < ntj; ++jt) {
        const _Float16* pa = pa_base + (size_t)jt * 6 * 512;
        f32x4 acc = {0.f, 0.f, 0.f, 0.f};
#pragma unroll
        for (int kk = 0; kk < 6; ++kk) {
            half8 af = *(const half8*)(pa + kk * 512);
            acc = __builtin_amdgcn_mfma_f32_16x16x32_f16(af, bf[kk], acc, 0, 0, 0);
        }
        int jbase = (jt0 + jt) * 16 + (lane >> 4) * 4;
#pragma unroll
        for (int q = 0; q < 4; ++q) {
            float d0 = acc[q];
            int jj = jbase + q;
            if (d0 > bd[SD - 1]) {
                bd[SD - 1] = d0; bi[SD - 1] = jj;
#pragma unroll
                for (int s = SD - 1; s > 0; --s)
                    if (bd[s] > bd[s - 1]) {
                        float td = bd[s]; bd[s] = bd[s-1]; bd[s-1] = td;
                        int   tj = bi[s]; bi[s] = bi[s-1]; bi[s-1] = tj;
                    }
            }
        }
    }

    // Dump per-lane streams; merge 4 streams -> 16 candidates per i-row.
    int ir = wave * 16 + (lane & 15);    // i-row within block (0..63)
    int g  = lane >> 4;                  // stream id
#pragma unroll
    for (int q = 0; q < SD; ++q) { md[ir][g][q] = bd[q]; mi[ir][g][q] = bi[q]; }
    __syncthreads();

    if (tid < 64) {
        int h[4] = {0, 0, 0, 0};
        unsigned short* cp =
            cand + ((size_t)b * NPT + itile * 64 + tid) * CAND + chunk * 16;
        const float* rd = &md[tid][0][0];
        const int*   ri = &mi[tid][0][0];
        for (int s = 0; s < 16; ++s) {
            float best = -2e30f; int bg = 0;
#pragma unroll
            for (int g2 = 0; g2 < 4; ++g2) {
                float v = (h[g2] < SD) ? rd[g2 * SD + h[g2]] : -2e30f;
                if (v > best) { best = v; bg = g2; }
            }
            cp[s] = (unsigned short)ri[bg * SD + h[bg]];
            h[bg]++;
        }
    }
}

// ---------------------------------------------------------------------------
// K3 v2: f64 refine from xT (coalesced 128B segments per 8-lane group).
//   Lane sub covers channels {q*32 + sub*4 + t}; full dot via 3 shuffles.
//   Selection: wave-wide argmin butterfly (dist asc, idx asc) — 9 rounds.
// ---------------------------------------------------------------------------
__global__ __launch_bounds__(256) void k_refine(
    const float* __restrict__ xT, const double* __restrict__ invn64,
    const double* __restrict__ sqd, const unsigned short* __restrict__ cand,
    float* __restrict__ e0)
{
    __shared__ double dbuf[4][CAND];
    __shared__ int    icand[4][CAND];
    int wave = threadIdx.x >> 6;
    int lane = threadIdx.x & 63;
    int row  = blockIdx.x * 4 + wave;
    int b    = row / NPT;

    icand[wave][lane] = (int)cand[(size_t)row * CAND + lane];
    __syncthreads();

    int sub = lane & 7, cg = lane >> 3;
    const float* xiRow = xT + (size_t)row * C_;
    float4 xif[6];
#pragma unroll
    for (int q = 0; q < 6; ++q)
        xif[q] = *(const float4*)&xiRow[q * 32 + sub * 4];
    double ivi = invn64[row], sqi = sqd[row];

    for (int cc = 0; cc < CAND / 8; ++cc) {
        int cidx = cc * 8 + cg;
        int j = icand[wave][cidx];
        const float* xjRow = xT + (size_t)(b * NPT + j) * C_;
        float4 v[6];
#pragma unroll
        for (int q = 0; q < 6; ++q)
            v[q] = *(const float4*)&xjRow[q * 32 + sub * 4];
        double d0 = 0.0, d1 = 0.0, d2 = 0.0, d3 = 0.0;
#pragma unroll
        for (int q = 0; q < 6; ++q) {
            d0 = fma((double)xif[q].x, (double)v[q].x, d0);
            d1 = fma((double)xif[q].y, (double)v[q].y, d1);
            d2 = fma((double)xif[q].z, (double)v[q].z, d2);
            d3 = fma((double)xif[q].w, (double)v[q].w, d3);
        }
        double dot = (d0 + d1) + (d2 + d3);
        dot += __shfl_xor(dot, 1);
        dot += __shfl_xor(dot, 2);
        dot += __shfl_xor(dot, 4);
        if (sub == 0)
            dbuf[wave][cidx] = sqi + sqd[(size_t)b * NPT + j]
                             - 2.0 * (ivi * invn64[(size_t)b * NPT + j] * dot);
    }
    __syncthreads();

    // wave-parallel top-9: lane <-> candidate (all 64 j distinct by constr.)
    double d = dbuf[wave][lane];
    int    j = icand[wave][lane];
    float* p0 = e0 + (size_t)row * KNN;
    for (int q = 0; q < KNN; ++q) {
        double bdv = d; int bjv = j;
#pragma unroll
        for (int off = 32; off > 0; off >>= 1) {
            double od = __shfl_xor(bdv, off);
            int    oj = __shfl_xor(bjv, off);
            if (od < bdv || (od == bdv && oj < bjv)) { bdv = od; bjv = oj; }
        }
        if (lane == 0) p0[q] = (float)bjv;
        if (j == bjv) d = 1e301;
    }
}

// ---------------------------------------------------------------------------
// K4: B = W2 * x for one batch, cols [bcol0, ...). Unchanged.
// ---------------------------------------------------------------------------
__global__ __launch_bounds__(256) void k_gemmB(
    const float* __restrict__ x, const float* __restrict__ cw,
    void* __restrict__ Bq, int b, int bcol0, int ldB, int storeBf16)
{
    __shared__ float Xt[16][68];
    __shared__ float Wt[16][68];
    int bm = blockIdx.x % 49;
    int bo = blockIdx.x / 49;
    int m0 = bm * 64;
    int tid = threadIdx.x;
    int tx = tid & 15, ty = tid >> 4;
    const float* xb = x + (size_t)b * C_ * NPT;
    float acc[4][4];
#pragma unroll
    for (int u = 0; u < 4; ++u)
#pragma unroll
        for (int v = 0; v < 4; ++v) acc[u][v] = 0.f;

    for (int ct = 0; ct < 12; ++ct) {
        int c0 = ct * 16;
        {
            int cc = tid >> 4, n4 = (tid & 15) * 4;
            *(float4*)&Xt[cc][n4] =
                *(const float4*)&xb[(size_t)(c0 + cc) * NPT + m0 + n4];
        }
        {
            int oo = tid >> 2, c4 = (tid & 3) * 4;
            int o = bcol0 + bo * 64 + oo;
            float4 w = *(const float4*)&cw[(size_t)o * 384 + C_ + c0 + c4];
            Wt[c4 + 0][oo] = w.x; Wt[c4 + 1][oo] = w.y;
            Wt[c4 + 2][oo] = w.z; Wt[c4 + 3][oo] = w.w;
        }
        __syncthreads();
#pragma unroll
        for (int cc = 0; cc < 16; ++cc) {
            float4 av = *(const float4*)&Xt[cc][ty * 4];
            float4 bv = *(const float4*)&Wt[cc][tx * 4];
            float a_[4] = {av.x, av.y, av.z, av.w};
            float b_[4] = {bv.x, bv.y, bv.z, bv.w};
#pragma unroll
            for (int u = 0; u < 4; ++u)
#pragma unroll
                for (int v = 0; v < 4; ++v)
                    acc[u][v] = fmaf(a_[u], b_[v], acc[u][v]);
        }
        __syncthreads();
    }
    if (!storeBf16) {
        float* Bf = (float*)Bq;
#pragma unroll
        for (int u = 0; u < 4; ++u) {
            float4 pk = {acc[u][0], acc[u][1], acc[u][2], acc[u][3]};
            *(float4*)&Bf[(size_t)(m0 + ty * 4 + u) * ldB + bo * 64 + tx * 4] = pk;
        }
    } else {
        unsigned short* Bh = (unsigned short*)Bq;
#pragma unroll
        for (int u = 0; u < 4; ++u) {
            ushort4 pk;
            pk.x = f2u(acc[u][0]); pk.y = f2u(acc[u][1]);
            pk.z = f2u(acc[u][2]); pk.w = f2u(acc[u][3]);
            *(ushort4*)&Bh[(size_t)(m0 + ty * 4 + u) * ldB + bo * 64 + tx * 4] = pk;
        }
    }
}

// ---------------------------------------------------------------------------
// K5: epilogue. Unchanged.
// ---------------------------------------------------------------------------
__global__ __launch_bounds__(256) void k_outA(
    const float* __restrict__ x, const float* __restrict__ cw,
    const float* __restrict__ e0, const float* __restrict__ cb,
    const float* __restrict__ gam, const float* __restrict__ bet,
    float* __restrict__ out, const void* __restrict__ Bq,
    int b, int o0base, int bcol0, int ldB, int readBf16)
{
    __shared__ float Xi[16][68];
    __shared__ float Wd[16][68];
    __shared__ int jidx[64 * KNN];
    int r  = blockIdx.x;
    int nt = r % 49, ot = r / 49;
    int n0 = nt * 64, o0 = o0base + ot * 64;
    int tid = threadIdx.x;
    int tx = tid & 15, ty = tid >> 4;
    const float* xb = x + (size_t)b * C_ * NPT;

    for (int e = tid; e < 64 * KNN; e += 256)
        jidx[e] = (int)e0[((size_t)b * NPT + n0 + e / KNN) * KNN + e % KNN];

    float zA[4][4];
#pragma unroll
    for (int u = 0; u < 4; ++u)
#pragma unroll
        for (int v = 0; v < 4; ++v) zA[u][v] = 0.f;

    for (int ct = 0; ct < 12; ++ct) {
        int c0 = ct * 16;
        {
            int cc = tid >> 4, n4 = (tid & 15) * 4;
            *(float4*)&Xi[cc][n4] =
                *(const float4*)&xb[(size_t)(c0 + cc) * NPT + n0 + n4];
        }
        {
            int oo = tid >> 2, c4 = (tid & 3) * 4;
            int o = o0 + oo;
            float4 w1 = *(const float4*)&cw[(size_t)o * 384 + c0 + c4];
            float4 w2 = *(const float4*)&cw[(size_t)o * 384 + C_ + c0 + c4];
            Wd[c4 + 0][oo] = w1.x - w2.x; Wd[c4 + 1][oo] = w1.y - w2.y;
            Wd[c4 + 2][oo] = w1.z - w2.z; Wd[c4 + 3][oo] = w1.w - w2.w;
        }
        __syncthreads();
#pragma unroll
        for (int cc = 0; cc < 16; ++cc) {
            float4 av = *(const float4*)&Xi[cc][ty * 4];
            float4 bv = *(const float4*)&Wd[cc][tx * 4];
            float a_[4] = {av.x, av.y, av.z, av.w};
            float b_[4] = {bv.x, bv.y, bv.z, bv.w};
#pragma unroll
            for (int u = 0; u < 4; ++u)
#pragma unroll
                for (int v = 0; v < 4; ++v)
                    zA[u][v] = fmaf(a_[u], b_[v], zA[u][v]);
        }
        __syncthreads();
    }

    const float inv_s = 0.9999950000374997f;  // 1/sqrt(1+1e-5)
    float gs[4], bts[4], cbs[4];
#pragma unroll
    for (int v = 0; v < 4; ++v) {
        int o = o0 + tx * 4 + v;
        gs[v]  = gam[o] * inv_s;
        bts[v] = bet[o];
        cbs[v] = cb[o];
    }

    float best[4][4];
#pragma unroll
    for (int u = 0; u < 4; ++u)
#pragma unroll
        for (int v = 0; v < 4; ++v) best[u][v] = -1e30f;

    int obB = o0 - bcol0;
    for (int k = 0; k < KNN; ++k) {
#pragma unroll
        for (int u = 0; u < 4; ++u) {
            int j = jidx[(ty * 4 + u) * KNN + k];
            float bvv[4];
            if (!readBf16) {
                float4 g = *(const float4*)
                    ((const float*)Bq + (size_t)j * ldB + obB + tx * 4);
                bvv[0] = g.x; bvv[1] = g.y; bvv[2] = g.z; bvv[3] = g.w;
            } else {
                ushort4 g = *(const ushort4*)
                    ((const unsigned short*)Bq + (size_t)j * ldB + obB + tx * 4);
                bvv[0] = u2f(g.x); bvv[1] = u2f(g.y);
                bvv[2] = u2f(g.z); bvv[3] = u2f(g.w);
            }
#pragma unroll
            for (int v = 0; v < 4; ++v) {
                float z = zA[u][v] + bvv[v] + cbs[v];
                float y = fmaf(z, gs[v], bts[v]);
                float ge = 0.5f * y * (1.0f + erff(y * 0.70710678118654752f));
                best[u][v] = fmaxf(best[u][v], ge);
            }
        }
    }

#pragma unroll
    for (int v = 0; v < 4; ++v) {
        int o = o0 + tx * 4 + v;
        float4 pk = {best[0][v], best[1][v], best[2][v], best[3][v]};
        *(float4*)(out + ((size_t)(b * CO_ + o)) * NPT + n0 + ty * 4) = pk;
    }
}

// ---------------------------------------------------------------------------
// K6: generate edge plane1 (center indices) last.
// ---------------------------------------------------------------------------
__global__ __launch_bounds__(256) void k_center(float* __restrict__ e1)
{
    int p = blockIdx.x * 256 + threadIdx.x;
    if (p >= NROWS * KNN) return;
    e1[p] = (float)((p / KNN) % NPT);
}

// ---------------------------------------------------------------------------
extern "C" void kernel_launch(void* const* d_in, const int* in_sizes, int n_in,
                              void* d_out, int out_size, void* d_ws, size_t ws_size,
                              hipStream_t stream)
{
    const float* x   = (const float*)d_in[0];
    const float* cw  = (const float*)d_in[1];
    const float* cb  = (const float*)d_in[2];
    const float* gam = (const float*)d_in[3];
    const float* bet = (const float*)d_in[4];

    // d_out: FLOAT32. out0 = floats [0, 4,816,896); e0 = [4,816,896,
    // 4,929,792); e1 = [4,929,792, 5,042,688).
    // Scratch liveness (all dead before their region's output write):
    //   head:   invn64/sqd/invn32/cand       bytes [0, 1,856,512)
    //   packed: fp16 MFMA fragments          bytes [1,856,512, 6,673,408)
    //           (dead after k_screen_mfma)
    //   xT:     floats [2,408,448, 4,816,896) = bytes [9,633,792, 19,267,584)
    //           (dead after k_refine)
    float* ou   = (float*)d_out;
    float* out0 = ou;
    double* invn64 = (double*)d_out;
    double* sqd    = (double*)((char*)d_out + 100352);
    float*  invn32 = (float*)((char*)d_out + 200704);
    unsigned short* cand =
        (unsigned short*)((char*)d_out + 250880);          // 1,605,632 B
    _Float16* packed = (_Float16*)(ou + 464128);           // 4,816,896 B
    float* xT = ou + 2408448;                              // 9.63 MB
    float* e0 = ou + 4816896;
    float* e1 = ou + 4929792;

    k_norm       <<<NROWS / 256, 256, 0, stream>>>(x, invn32, invn64, sqd);
    k_xpose      <<<B_ * 6 * 98, 256, 0, stream>>>(x, xT);
    k_pack       <<<1176, 256, 0, stream>>>(xT, invn32, packed);
    k_screen_mfma<<<B_ * 49 * 4, 256, 0, stream>>>(packed, cand);
    k_refine     <<<NROWS / 4, 256, 0, stream>>>(xT, invn64, sqd, cand, e0);

    // Batches 3,2,1: full B (3136x384 fp32 = 4.8 MB) in Q0 (free until b0).
    for (int b = 3; b >= 1; --b) {
        k_gemmB<<<49 * 6, 256, 0, stream>>>(x, cw, (void*)ou, b, 0, 384, 0);
        k_outA <<<49 * 6, 256, 0, stream>>>(x, cw, e0, cb, gam, bet, out0,
                                            (const void*)ou, b, 0, 0, 384, 0);
    }
    // Batch 0 in 3 bf16 col-chunks; B buffers in provably-dead space:
    //  1: cols [192,384) B bf16 @ Q0 bytes [0,1,204,224) out->[2,408,448,4,816,896)
    //  2: cols [ 64,192) B bf16 @ Q0 bytes [0,  802,816) out->[  802,816,2,408,448)
    //  3: cols [  0, 64) B bf16 @ e1      (401,408 B)    out->[        0,  802,816)
    k_gemmB<<<49 * 3, 256, 0, stream>>>(x, cw, (void*)ou, 0, 192, 192, 1);
    k_outA <<<49 * 3, 256, 0, stream>>>(x, cw, e0, cb, gam, bet, out0,
                                        (const void*)ou, 0, 192, 192, 192, 1);
    k_gemmB<<<49 * 2, 256, 0, stream>>>(x, cw, (void*)ou, 0, 64, 128, 1);
    k_outA <<<49 * 2, 256, 0, stream>>>(x, cw, e0, cb, gam, bet, out0,
                                        (const void*)ou, 0, 64, 64, 128, 1);
    k_gemmB<<<49 * 1, 256, 0, stream>>>(x, cw, (void*)e1, 0, 0, 64, 1);
    k_outA <<<49 * 1, 256, 0, stream>>>(x, cw, e0, cb, gam, bet, out0,
                                        (const void*)e1, 0, 0, 0, 64, 1);
    // Generate e1 (center plane) last.
    k_center<<<(NROWS * KNN + 255) / 256, 256, 0, stream>>>(e1);
}

// Round 3
// 515.410 us; speedup vs baseline: 1.7806x; 1.1656x over previous
//
#include <hip/hip_runtime.h>
#include <hip/hip_bf16.h>
#include <math.h>

#define B_    4
#define C_    192
#define NPT   3136          // H*W points per batch
#define CO_   384           // Cout
#define KNN   9
#define CAND  64            // 4 j-chunks * merged top-16 per row
#define NROWS (B_*NPT)      // 12544 total points
#define SD    10            // per-lane screening stream depth

typedef _Float16 half8 __attribute__((ext_vector_type(8)));
typedef float    f32x4 __attribute__((ext_vector_type(4)));

__device__ __forceinline__ float u2f(unsigned short u) {
    unsigned int t = ((unsigned int)u) << 16;
    float f; __builtin_memcpy(&f, &t, 4); return f;
}
__device__ __forceinline__ unsigned short f2u(float f) {
    __hip_bfloat16 h = __float2bfloat16(f);
    unsigned short u; __builtin_memcpy(&u, &h, 2); return u;
}

// ---------------------------------------------------------------------------
// K1: per-point f64 norm stats from fp32 x.
// ---------------------------------------------------------------------------
__global__ __launch_bounds__(256) void k_norm(
    const float* __restrict__ x,
    float* __restrict__ invn32, double* __restrict__ invn64,
    double* __restrict__ sqd)
{
    int p = blockIdx.x * 256 + threadIdx.x;
    if (p >= NROWS) return;
    int b = p / NPT, n = p % NPT;
    const float* xb = x + (size_t)b * C_ * NPT + n;
    double S = 0.0;
    for (int c = 0; c < C_; ++c) {
        double v = (double)xb[(size_t)c * NPT];
        S = fma(v, v, S);
    }
    double nrm = sqrt(S);
    if (nrm < 1e-12) nrm = 1e-12;
    double iv = 1.0 / nrm;
    invn64[p] = iv;
    invn32[p] = (float)iv;
    sqd[p] = iv * iv * S;
}

// ---------------------------------------------------------------------------
// K1b: LDS-tiled transpose x [b][c][n] -> xT [b*NPT+n][c] (fp32, exact).
// ---------------------------------------------------------------------------
__global__ __launch_bounds__(256) void k_xpose(
    const float* __restrict__ x, float* __restrict__ xT)
{
    __shared__ float t[32][33];
    int blk = blockIdx.x;
    int b  = blk / 588;
    int r  = blk % 588;
    int ct = r / 98, nt = r % 98;
    int c0 = ct * 32, n0 = nt * 32;
    int tid = threadIdx.x;
    int tx = tid & 31, ty8 = tid >> 5;          // 8 rows per pass
    const float* xb = x + (size_t)b * C_ * NPT;
#pragma unroll
    for (int e = 0; e < 4; ++e) {
        int cc = ty8 + e * 8;
        t[cc][tx] = xb[(size_t)(c0 + cc) * NPT + n0 + tx];
    }
    __syncthreads();
#pragma unroll
    for (int e = 0; e < 4; ++e) {
        int nn = ty8 + e * 8;
        xT[(size_t)(b * NPT + n0 + nn) * C_ + c0 + tx] = t[tx][nn];
    }
}

// ---------------------------------------------------------------------------
// K1c: pack normalized fp16 fragments for MFMA screening.
//   packed[(b*196+t16)*6 + kk][lane][e] = xn[b][t16*16 + (lane&15)]
//                                           [kk*32 + (lane>>4)*8 + e]
//   One thread per (b,t16,kk,lane): reads 32B from xT, writes 16B coalesced.
// ---------------------------------------------------------------------------
__global__ __launch_bounds__(256) void k_pack(
    const float* __restrict__ xT, const float* __restrict__ invn32,
    _Float16* __restrict__ packed)
{
    int t = blockIdx.x * 256 + threadIdx.x;    // 0 .. 301055
    if (t >= B_ * 196 * 6 * 64) return;
    int l  = t & 63;
    int tk = t >> 6;            // (b*196 + t16)*6 + kk
    int kk = tk % 6;
    int bt = tk / 6;            // b*196 + t16
    int row = bt * 16 + (l & 15);
    int kbase = kk * 32 + (l >> 4) * 8;
    const float* src = xT + (size_t)row * C_ + kbase;
    float iv = invn32[row];
    float4 v0 = *(const float4*)src;
    float4 v1 = *(const float4*)(src + 4);
    half8 h;
    h[0] = (_Float16)(v0.x * iv); h[1] = (_Float16)(v0.y * iv);
    h[2] = (_Float16)(v0.z * iv); h[3] = (_Float16)(v0.w * iv);
    h[4] = (_Float16)(v1.x * iv); h[5] = (_Float16)(v1.y * iv);
    h[6] = (_Float16)(v1.z * iv); h[7] = (_Float16)(v1.w * iv);
    *(half8*)(packed + (size_t)t * 8) = h;
}

// ---------------------------------------------------------------------------
// K2 (MFMA v2): fp16 matrix-core screening, branchless u32-key selection.
//   key = (bits(score+2.0f) & 0xFFFFF000) | jj  (score in [-1,1] -> s+2 in
//   [1,3] positive -> float bits monotone; 11 mantissa bits ~ 0.001 quantum;
//   jj < 3136 < 4096 fits 12 bits). Top-SD kept per lane-stream with a
//   branchless max/min bubble (2 VALU per step, no divergence).
//   A-fragments software-prefetched one j-tile ahead (select covers L2 lat).
//   Merge dump: md[64][41] u32 (stride 41 -> <=2-way banks, free).
//   cand layout identical to before -> k_refine unchanged.
// ---------------------------------------------------------------------------
__global__ __launch_bounds__(256) void k_screen_mfma(
    const _Float16* __restrict__ packed, unsigned short* __restrict__ cand)
{
    __shared__ unsigned md[64][4 * SD + 1];   // stride 41
    int blk   = blockIdx.x;
    int chunk = blk & 3;
    int t2    = blk >> 2;
    int b     = t2 / 49;
    int itile = t2 % 49;                 // 64-row i tile
    int tid   = threadIdx.x;
    int wave  = tid >> 6, lane = tid & 63;
    int it    = itile * 4 + wave;        // global 16-row tile within batch

    // B fragments (Xi rows), loaded once: 6 x 1KB coalesced wave loads.
    const _Float16* pb = packed + ((size_t)(b * 196 + it) * 6) * 512 + lane * 8;
    half8 bf[6];
#pragma unroll
    for (int kk = 0; kk < 6; ++kk)
        bf[kk] = *(const half8*)(pb + kk * 512);

    int jt0 = chunk * 48;                 // chunks: 768,768,768,832 cols
    int ntj = (chunk == 3) ? 52 : 48;

    unsigned bd[SD];
#pragma unroll
    for (int q = 0; q < SD; ++q) bd[q] = 0u;

    const _Float16* pa_base =
        packed + ((size_t)(b * 196 + jt0) * 6) * 512 + lane * 8;

    // prologue: load first tile's A fragments
    half8 af[6];
#pragma unroll
    for (int kk = 0; kk < 6; ++kk)
        af[kk] = *(const half8*)(pa_base + kk * 512);

    for (int jt = 0; jt < ntj; ++jt) {
        f32x4 acc = {0.f, 0.f, 0.f, 0.f};
#pragma unroll
        for (int kk = 0; kk < 6; ++kk)
            acc = __builtin_amdgcn_mfma_f32_16x16x32_f16(af[kk], bf[kk], acc, 0, 0, 0);

        // prefetch next tile's A fragments (independent of acc)
        if (jt + 1 < ntj) {
            const _Float16* pn = pa_base + (size_t)(jt + 1) * 6 * 512;
#pragma unroll
            for (int kk = 0; kk < 6; ++kk)
                af[kk] = *(const half8*)(pn + kk * 512);
        }

        unsigned jb = (unsigned)((jt0 + jt) * 16 + (lane >> 4) * 4);
#pragma unroll
        for (int q = 0; q < 4; ++q) {
            float s = acc[q] + 2.0f;
            unsigned fb = __float_as_uint(s);
            unsigned c = (fb & 0xFFFFF000u) | (jb + (unsigned)q);
#pragma unroll
            for (int t = 0; t < SD; ++t) {
                unsigned old = bd[t];
                unsigned mx = old > c ? old : c;    // v_max_u32
                c           = old > c ? c : old;    // v_min_u32
                bd[t] = mx;
            }
        }
    }

    // Dump per-lane streams; merge 4 streams -> 16 candidates per i-row.
    int ir = wave * 16 + (lane & 15);    // i-row within block (0..63)
    int g  = lane >> 4;                  // stream id
#pragma unroll
    for (int q = 0; q < SD; ++q) md[ir][g * SD + q] = bd[q];
    __syncthreads();

    if (tid < 64) {
        int h[4] = {0, 0, 0, 0};
        unsigned short* cp =
            cand + ((size_t)b * NPT + itile * 64 + tid) * CAND + chunk * 16;
        const unsigned* rd = &md[tid][0];
        for (int s = 0; s < 16; ++s) {
            unsigned best = 0u; int bg = 0;
#pragma unroll
            for (int g2 = 0; g2 < 4; ++g2) {
                unsigned v = (h[g2] < SD) ? rd[g2 * SD + h[g2]] : 0u;
                if (v > best) { best = v; bg = g2; }
            }
            cp[s] = (unsigned short)(best & 0xFFFu);
            h[bg]++;
        }
    }
}

// ---------------------------------------------------------------------------
// K3 v2: f64 refine from xT (coalesced 128B segments per 8-lane group).
//   Lane sub covers channels {q*32 + sub*4 + t}; full dot via 3 shuffles.
//   Selection: wave-wide argmin butterfly (dist asc, idx asc) — 9 rounds.
// ---------------------------------------------------------------------------
__global__ __launch_bounds__(256) void k_refine(
    const float* __restrict__ xT, const double* __restrict__ invn64,
    const double* __restrict__ sqd, const unsigned short* __restrict__ cand,
    float* __restrict__ e0)
{
    __shared__ double dbuf[4][CAND];
    __shared__ int    icand[4][CAND];
    int wave = threadIdx.x >> 6;
    int lane = threadIdx.x & 63;
    int row  = blockIdx.x * 4 + wave;
    int b    = row / NPT;

    icand[wave][lane] = (int)cand[(size_t)row * CAND + lane];
    __syncthreads();

    int sub = lane & 7, cg = lane >> 3;
    const float* xiRow = xT + (size_t)row * C_;
    float4 xif[6];
#pragma unroll
    for (int q = 0; q < 6; ++q)
        xif[q] = *(const float4*)&xiRow[q * 32 + sub * 4];
    double ivi = invn64[row], sqi = sqd[row];

    for (int cc = 0; cc < CAND / 8; ++cc) {
        int cidx = cc * 8 + cg;
        int j = icand[wave][cidx];
        const float* xjRow = xT + (size_t)(b * NPT + j) * C_;
        float4 v[6];
#pragma unroll
        for (int q = 0; q < 6; ++q)
            v[q] = *(const float4*)&xjRow[q * 32 + sub * 4];
        double d0 = 0.0, d1 = 0.0, d2 = 0.0, d3 = 0.0;
#pragma unroll
        for (int q = 0; q < 6; ++q) {
            d0 = fma((double)xif[q].x, (double)v[q].x, d0);
            d1 = fma((double)xif[q].y, (double)v[q].y, d1);
            d2 = fma((double)xif[q].z, (double)v[q].z, d2);
            d3 = fma((double)xif[q].w, (double)v[q].w, d3);
        }
        double dot = (d0 + d1) + (d2 + d3);
        dot += __shfl_xor(dot, 1);
        dot += __shfl_xor(dot, 2);
        dot += __shfl_xor(dot, 4);
        if (sub == 0)
            dbuf[wave][cidx] = sqi + sqd[(size_t)b * NPT + j]
                             - 2.0 * (ivi * invn64[(size_t)b * NPT + j] * dot);
    }
    __syncthreads();

    // wave-parallel top-9: lane <-> candidate (all 64 j distinct by constr.)
    double d = dbuf[wave][lane];
    int    j = icand[wave][lane];
    float* p0 = e0 + (size_t)row * KNN;
    for (int q = 0; q < KNN; ++q) {
        double bdv = d; int bjv = j;
#pragma unroll
        for (int off = 32; off > 0; off >>= 1) {
            double od = __shfl_xor(bdv, off);
            int    oj = __shfl_xor(bjv, off);
            if (od < bdv || (od == bdv && oj < bjv)) { bdv = od; bjv = oj; }
        }
        if (lane == 0) p0[q] = (float)bjv;
        if (j == bjv) d = 1e301;
    }
}

// ---------------------------------------------------------------------------
// K4: B = W2 * x for one batch, cols [bcol0, ...). Unchanged.
// ---------------------------------------------------------------------------
__global__ __launch_bounds__(256) void k_gemmB(
    const float* __restrict__ x, const float* __restrict__ cw,
    void* __restrict__ Bq, int b, int bcol0, int ldB, int storeBf16)
{
    __shared__ float Xt[16][68];
    __shared__ float Wt[16][68];
    int bm = blockIdx.x % 49;
    int bo = blockIdx.x / 49;
    int m0 = bm * 64;
    int tid = threadIdx.x;
    int tx = tid & 15, ty = tid >> 4;
    const float* xb = x + (size_t)b * C_ * NPT;
    float acc[4][4];
#pragma unroll
    for (int u = 0; u < 4; ++u)
#pragma unroll
        for (int v = 0; v < 4; ++v) acc[u][v] = 0.f;

    for (int ct = 0; ct < 12; ++ct) {
        int c0 = ct * 16;
        {
            int cc = tid >> 4, n4 = (tid & 15) * 4;
            *(float4*)&Xt[cc][n4] =
                *(const float4*)&xb[(size_t)(c0 + cc) * NPT + m0 + n4];
        }
        {
            int oo = tid >> 2, c4 = (tid & 3) * 4;
            int o = bcol0 + bo * 64 + oo;
            float4 w = *(const float4*)&cw[(size_t)o * 384 + C_ + c0 + c4];
            Wt[c4 + 0][oo] = w.x; Wt[c4 + 1][oo] = w.y;
            Wt[c4 + 2][oo] = w.z; Wt[c4 + 3][oo] = w.w;
        }
        __syncthreads();
#pragma unroll
        for (int cc = 0; cc < 16; ++cc) {
            float4 av = *(const float4*)&Xt[cc][ty * 4];
            float4 bv = *(const float4*)&Wt[cc][tx * 4];
            float a_[4] = {av.x, av.y, av.z, av.w};
            float b_[4] = {bv.x, bv.y, bv.z, bv.w};
#pragma unroll
            for (int u = 0; u < 4; ++u)
#pragma unroll
                for (int v = 0; v < 4; ++v)
                    acc[u][v] = fmaf(a_[u], b_[v], acc[u][v]);
        }
        __syncthreads();
    }
    if (!storeBf16) {
        float* Bf = (float*)Bq;
#pragma unroll
        for (int u = 0; u < 4; ++u) {
            float4 pk = {acc[u][0], acc[u][1], acc[u][2], acc[u][3]};
            *(float4*)&Bf[(size_t)(m0 + ty * 4 + u) * ldB + bo * 64 + tx * 4] = pk;
        }
    } else {
        unsigned short* Bh = (unsigned short*)Bq;
#pragma unroll
        for (int u = 0; u < 4; ++u) {
            ushort4 pk;
            pk.x = f2u(acc[u][0]); pk.y = f2u(acc[u][1]);
            pk.z = f2u(acc[u][2]); pk.w = f2u(acc[u][3]);
            *(ushort4*)&Bh[(size_t)(m0 + ty * 4 + u) * ldB + bo * 64 + tx * 4] = pk;
        }
    }
}

// ---------------------------------------------------------------------------
// K5: epilogue. Unchanged.
// ---------------------------------------------------------------------------
__global__ __launch_bounds__(256) void k_outA(
    const float* __restrict__ x, const float* __restrict__ cw,
    const float* __restrict__ e0, const float* __restrict__ cb,
    const float* __restrict__ gam, const float* __restrict__ bet,
    float* __restrict__ out, const void* __restrict__ Bq,
    int b, int o0base, int bcol0, int ldB, int readBf16)
{
    __shared__ float Xi[16][68];
    __shared__ float Wd[16][68];
    __shared__ int jidx[64 * KNN];
    int r  = blockIdx.x;
    int nt = r % 49, ot = r / 49;
    int n0 = nt * 64, o0 = o0base + ot * 64;
    int tid = threadIdx.x;
    int tx = tid & 15, ty = tid >> 4;
    const float* xb = x + (size_t)b * C_ * NPT;

    for (int e = tid; e < 64 * KNN; e += 256)
        jidx[e] = (int)e0[((size_t)b * NPT + n0 + e / KNN) * KNN + e % KNN];

    float zA[4][4];
#pragma unroll
    for (int u = 0; u < 4; ++u)
#pragma unroll
        for (int v = 0; v < 4; ++v) zA[u][v] = 0.f;

    for (int ct = 0; ct < 12; ++ct) {
        int c0 = ct * 16;
        {
            int cc = tid >> 4, n4 = (tid & 15) * 4;
            *(float4*)&Xi[cc][n4] =
                *(const float4*)&xb[(size_t)(c0 + cc) * NPT + n0 + n4];
        }
        {
            int oo = tid >> 2, c4 = (tid & 3) * 4;
            int o = o0 + oo;
            float4 w1 = *(const float4*)&cw[(size_t)o * 384 + c0 + c4];
            float4 w2 = *(const float4*)&cw[(size_t)o * 384 + C_ + c0 + c4];
            Wd[c4 + 0][oo] = w1.x - w2.x; Wd[c4 + 1][oo] = w1.y - w2.y;
            Wd[c4 + 2][oo] = w1.z - w2.z; Wd[c4 + 3][oo] = w1.w - w2.w;
        }
        __syncthreads();
#pragma unroll
        for (int cc = 0; cc < 16; ++cc) {
            float4 av = *(const float4*)&Xi[cc][ty * 4];
            float4 bv = *(const float4*)&Wd[cc][tx * 4];
            float a_[4] = {av.x, av.y, av.z, av.w};
            float b_[4] = {bv.x, bv.y, bv.z, bv.w};
#pragma unroll
            for (int u = 0; u < 4; ++u)
#pragma unroll
                for (int v = 0; v < 4; ++v)
                    zA[u][v] = fmaf(a_[u], b_[v], zA[u][v]);
        }
        __syncthreads();
    }

    const float inv_s = 0.9999950000374997f;  // 1/sqrt(1+1e-5)
    float gs[4], bts[4], cbs[4];
#pragma unroll
    for (int v = 0; v < 4; ++v) {
        int o = o0 + tx * 4 + v;
        gs[v]  = gam[o] * inv_s;
        bts[v] = bet[o];
        cbs[v] = cb[o];
    }

    float best[4][4];
#pragma unroll
    for (int u = 0; u < 4; ++u)
#pragma unroll
        for (int v = 0; v < 4; ++v) best[u][v] = -1e30f;

    int obB = o0 - bcol0;
    for (int k = 0; k < KNN; ++k) {
#pragma unroll
        for (int u = 0; u < 4; ++u) {
            int j = jidx[(ty * 4 + u) * KNN + k];
            float bvv[4];
            if (!readBf16) {
                float4 g = *(const float4*)
                    ((const float*)Bq + (size_t)j * ldB + obB + tx * 4);
                bvv[0] = g.x; bvv[1] = g.y; bvv[2] = g.z; bvv[3] = g.w;
            } else {
                ushort4 g = *(const ushort4*)
                    ((const unsigned short*)Bq + (size_t)j * ldB + obB + tx * 4);
                bvv[0] = u2f(g.x); bvv[1] = u2f(g.y);
                bvv[2] = u2f(g.z); bvv[3] = u2f(g.w);
            }
#pragma unroll
            for (int v = 0; v < 4; ++v) {
                float z = zA[u][v] + bvv[v] + cbs[v];
                float y = fmaf(z, gs[v], bts[v]);
                float ge = 0.5f * y * (1.0f + erff(y * 0.70710678118654752f));
                best[u][v] = fmaxf(best[u][v], ge);
            }
        }
    }

#pragma unroll
    for (int v = 0; v < 4; ++v) {
        int o = o0 + tx * 4 + v;
        float4 pk = {best[0][v], best[1][v], best[2][v], best[3][v]};
        *(float4*)(out + ((size_t)(b * CO_ + o)) * NPT + n0 + ty * 4) = pk;
    }
}

// ---------------------------------------------------------------------------
// K6: generate edge plane1 (center indices) last.
// ---------------------------------------------------------------------------
__global__ __launch_bounds__(256) void k_center(float* __restrict__ e1)
{
    int p = blockIdx.x * 256 + threadIdx.x;
    if (p >= NROWS * KNN) return;
    e1[p] = (float)((p / KNN) % NPT);
}

// ---------------------------------------------------------------------------
extern "C" void kernel_launch(void* const* d_in, const int* in_sizes, int n_in,
                              void* d_out, int out_size, void* d_ws, size_t ws_size,
                              hipStream_t stream)
{
    const float* x   = (const float*)d_in[0];
    const float* cw  = (const float*)d_in[1];
    const float* cb  = (const float*)d_in[2];
    const float* gam = (const float*)d_in[3];
    const float* bet = (const float*)d_in[4];

    // d_out: FLOAT32. out0 = floats [0, 4,816,896); e0 = [4,816,896,
    // 4,929,792); e1 = [4,929,792, 5,042,688).
    // Scratch liveness (all dead before their region's output write):
    //   head:   invn64/sqd/invn32/cand       bytes [0, 1,856,512)
    //   packed: fp16 MFMA fragments          bytes [1,856,512, 6,673,408)
    //           (dead after k_screen_mfma)
    //   xT:     floats [2,408,448, 4,816,896) = bytes [9,633,792, 19,267,584)
    //           (dead after k_refine)
    float* ou   = (float*)d_out;
    float* out0 = ou;
    double* invn64 = (double*)d_out;
    double* sqd    = (double*)((char*)d_out + 100352);
    float*  invn32 = (float*)((char*)d_out + 200704);
    unsigned short* cand =
        (unsigned short*)((char*)d_out + 250880);          // 1,605,632 B
    _Float16* packed = (_Float16*)(ou + 464128);           // 4,816,896 B
    float* xT = ou + 2408448;                              // 9.63 MB
    float* e0 = ou + 4816896;
    float* e1 = ou + 4929792;

    k_norm       <<<NROWS / 256, 256, 0, stream>>>(x, invn32, invn64, sqd);
    k_xpose      <<<B_ * 6 * 98, 256, 0, stream>>>(x, xT);
    k_pack       <<<1176, 256, 0, stream>>>(xT, invn32, packed);
    k_screen_mfma<<<B_ * 49 * 4, 256, 0, stream>>>(packed, cand);
    k_refine     <<<NROWS / 4, 256, 0, stream>>>(xT, invn64, sqd, cand, e0);

    // Batches 3,2,1: full B (3136x384 fp32 = 4.8 MB) in Q0 (free until b0).
    for (int b = 3; b >= 1; --b) {
        k_gemmB<<<49 * 6, 256, 0, stream>>>(x, cw, (void*)ou, b, 0, 384, 0);
        k_outA <<<49 * 6, 256, 0, stream>>>(x, cw, e0, cb, gam, bet, out0,
                                            (const void*)ou, b, 0, 0, 384, 0);
    }
    // Batch 0 in 3 bf16 col-chunks; B buffers in provably-dead space:
    //  1: cols [192,384) B bf16 @ Q0 bytes [0,1,204,224) out->[2,408,448,4,816,896)
    //  2: cols [ 64,192) B bf16 @ Q0 bytes [0,  802,816) out->[  802,816,2,408,448)
    //  3: cols [  0, 64) B bf16 @ e1      (401,408 B)    out->[        0,  802,816)
    k_gemmB<<<49 * 3, 256, 0, stream>>>(x, cw, (void*)ou, 0, 192, 192, 1);
    k_outA <<<49 * 3, 256, 0, stream>>>(x, cw, e0, cb, gam, bet, out0,
                                        (const void*)ou, 0, 192, 192, 192, 1);
    k_gemmB<<<49 * 2, 256, 0, stream>>>(x, cw, (void*)ou, 0, 64, 128, 1);
    k_outA <<<49 * 2, 256, 0, stream>>>(x, cw, e0, cb, gam, bet, out0,
                                        (const void*)ou, 0, 64, 64, 128, 1);
    k_gemmB<<<49 * 1, 256, 0, stream>>>(x, cw, (void*)e1, 0, 0, 64, 1);
    k_outA <<<49 * 1, 256, 0, stream>>>(x, cw, e0, cb, gam, bet, out0,
                                        (const void*)e1, 0, 0, 0, 64, 1);
    // Generate e1 (center plane) last.
    k_center<<<(NROWS * KNN + 255) / 256, 256, 0, stream>>>(e1);
}

// Round 4
// 315.212 us; speedup vs baseline: 2.9115x; 1.6351x over previous
//
#include <hip/hip_runtime.h>
#include <hip/hip_bf16.h>
#include <math.h>

#define B_    4
#define C_    192
#define NPT   3136          // H*W points per batch
#define CO_   384           // Cout
#define KNN   9
#define CAND  64            // 4 j-chunks * merged top-16 per row
#define NROWS (B_*NPT)      // 12544 total points
#define SD    10            // per-lane screening stream depth

typedef _Float16 half8 __attribute__((ext_vector_type(8)));
typedef float    f32x4 __attribute__((ext_vector_type(4)));

__device__ __forceinline__ float u2f(unsigned short u) {
    unsigned int t = ((unsigned int)u) << 16;
    float f; __builtin_memcpy(&f, &t, 4); return f;
}
__device__ __forceinline__ unsigned short f2u(float f) {
    __hip_bfloat16 h = __float2bfloat16(f);
    unsigned short u; __builtin_memcpy(&u, &h, 2); return u;
}

// ---------------------------------------------------------------------------
// K1: per-point f64 norm stats from fp32 x.
// ---------------------------------------------------------------------------
__global__ __launch_bounds__(256) void k_norm(
    const float* __restrict__ x,
    float* __restrict__ invn32, double* __restrict__ invn64,
    double* __restrict__ sqd)
{
    int p = blockIdx.x * 256 + threadIdx.x;
    if (p >= NROWS) return;
    int b = p / NPT, n = p % NPT;
    const float* xb = x + (size_t)b * C_ * NPT + n;
    double S = 0.0;
    for (int c = 0; c < C_; ++c) {
        double v = (double)xb[(size_t)c * NPT];
        S = fma(v, v, S);
    }
    double nrm = sqrt(S);
    if (nrm < 1e-12) nrm = 1e-12;
    double iv = 1.0 / nrm;
    invn64[p] = iv;
    invn32[p] = (float)iv;
    sqd[p] = iv * iv * S;
}

// ---------------------------------------------------------------------------
// K1b: LDS-tiled transpose x [b][c][n] -> xT [b*NPT+n][c] (fp32, exact).
// ---------------------------------------------------------------------------
__global__ __launch_bounds__(256) void k_xpose(
    const float* __restrict__ x, float* __restrict__ xT)
{
    __shared__ float t[32][33];
    int blk = blockIdx.x;
    int b  = blk / 588;
    int r  = blk % 588;
    int ct = r / 98, nt = r % 98;
    int c0 = ct * 32, n0 = nt * 32;
    int tid = threadIdx.x;
    int tx = tid & 31, ty8 = tid >> 5;          // 8 rows per pass
    const float* xb = x + (size_t)b * C_ * NPT;
#pragma unroll
    for (int e = 0; e < 4; ++e) {
        int cc = ty8 + e * 8;
        t[cc][tx] = xb[(size_t)(c0 + cc) * NPT + n0 + tx];
    }
    __syncthreads();
#pragma unroll
    for (int e = 0; e < 4; ++e) {
        int nn = ty8 + e * 8;
        xT[(size_t)(b * NPT + n0 + nn) * C_ + c0 + tx] = t[tx][nn];
    }
}

// ---------------------------------------------------------------------------
// K1c: pack normalized fp16 fragments for MFMA screening.
// ---------------------------------------------------------------------------
__global__ __launch_bounds__(256) void k_pack(
    const float* __restrict__ xT, const float* __restrict__ invn32,
    _Float16* __restrict__ packed)
{
    int t = blockIdx.x * 256 + threadIdx.x;    // 0 .. 301055
    if (t >= B_ * 196 * 6 * 64) return;
    int l  = t & 63;
    int tk = t >> 6;            // (b*196 + t16)*6 + kk
    int kk = tk % 6;
    int bt = tk / 6;            // b*196 + t16
    int row = bt * 16 + (l & 15);
    int kbase = kk * 32 + (l >> 4) * 8;
    const float* src = xT + (size_t)row * C_ + kbase;
    float iv = invn32[row];
    float4 v0 = *(const float4*)src;
    float4 v1 = *(const float4*)(src + 4);
    half8 h;
    h[0] = (_Float16)(v0.x * iv); h[1] = (_Float16)(v0.y * iv);
    h[2] = (_Float16)(v0.z * iv); h[3] = (_Float16)(v0.w * iv);
    h[4] = (_Float16)(v1.x * iv); h[5] = (_Float16)(v1.y * iv);
    h[6] = (_Float16)(v1.z * iv); h[7] = (_Float16)(v1.w * iv);
    *(half8*)(packed + (size_t)t * 8) = h;
}

// ---------------------------------------------------------------------------
// K2 (MFMA v2): fp16 matrix-core screening, branchless u32-key selection.
//   key = (bits(score+2.0f) & 0xFFFFF000) | jj; branchless max/min bubble.
//   A-fragments software-prefetched one j-tile ahead.
// ---------------------------------------------------------------------------
__global__ __launch_bounds__(256) void k_screen_mfma(
    const _Float16* __restrict__ packed, unsigned short* __restrict__ cand)
{
    __shared__ unsigned md[64][4 * SD + 1];   // stride 41
    int blk   = blockIdx.x;
    int chunk = blk & 3;
    int t2    = blk >> 2;
    int b     = t2 / 49;
    int itile = t2 % 49;                 // 64-row i tile
    int tid   = threadIdx.x;
    int wave  = tid >> 6, lane = tid & 63;
    int it    = itile * 4 + wave;        // global 16-row tile within batch

    const _Float16* pb = packed + ((size_t)(b * 196 + it) * 6) * 512 + lane * 8;
    half8 bf[6];
#pragma unroll
    for (int kk = 0; kk < 6; ++kk)
        bf[kk] = *(const half8*)(pb + kk * 512);

    int jt0 = chunk * 48;                 // chunks: 768,768,768,832 cols
    int ntj = (chunk == 3) ? 52 : 48;

    unsigned bd[SD];
#pragma unroll
    for (int q = 0; q < SD; ++q) bd[q] = 0u;

    const _Float16* pa_base =
        packed + ((size_t)(b * 196 + jt0) * 6) * 512 + lane * 8;

    half8 af[6];
#pragma unroll
    for (int kk = 0; kk < 6; ++kk)
        af[kk] = *(const half8*)(pa_base + kk * 512);

    for (int jt = 0; jt < ntj; ++jt) {
        f32x4 acc = {0.f, 0.f, 0.f, 0.f};
#pragma unroll
        for (int kk = 0; kk < 6; ++kk)
            acc = __builtin_amdgcn_mfma_f32_16x16x32_f16(af[kk], bf[kk], acc, 0, 0, 0);

        if (jt + 1 < ntj) {
            const _Float16* pn = pa_base + (size_t)(jt + 1) * 6 * 512;
#pragma unroll
            for (int kk = 0; kk < 6; ++kk)
                af[kk] = *(const half8*)(pn + kk * 512);
        }

        unsigned jb = (unsigned)((jt0 + jt) * 16 + (lane >> 4) * 4);
#pragma unroll
        for (int q = 0; q < 4; ++q) {
            float s = acc[q] + 2.0f;
            unsigned fb = __float_as_uint(s);
            unsigned c = (fb & 0xFFFFF000u) | (jb + (unsigned)q);
#pragma unroll
            for (int t = 0; t < SD; ++t) {
                unsigned old = bd[t];
                unsigned mx = old > c ? old : c;    // v_max_u32
                c           = old > c ? c : old;    // v_min_u32
                bd[t] = mx;
            }
        }
    }

    int ir = wave * 16 + (lane & 15);    // i-row within block (0..63)
    int g  = lane >> 4;                  // stream id
#pragma unroll
    for (int q = 0; q < SD; ++q) md[ir][g * SD + q] = bd[q];
    __syncthreads();

    if (tid < 64) {
        int h[4] = {0, 0, 0, 0};
        unsigned short* cp =
            cand + ((size_t)b * NPT + itile * 64 + tid) * CAND + chunk * 16;
        const unsigned* rd = &md[tid][0];
        for (int s = 0; s < 16; ++s) {
            unsigned best = 0u; int bg = 0;
#pragma unroll
            for (int g2 = 0; g2 < 4; ++g2) {
                unsigned v = (h[g2] < SD) ? rd[g2 * SD + h[g2]] : 0u;
                if (v > best) { best = v; bg = g2; }
            }
            cp[s] = (unsigned short)(best & 0xFFFu);
            h[bg]++;
        }
    }
}

// ---------------------------------------------------------------------------
// K3 v2: f64 refine from xT. Unchanged.
// ---------------------------------------------------------------------------
__global__ __launch_bounds__(256) void k_refine(
    const float* __restrict__ xT, const double* __restrict__ invn64,
    const double* __restrict__ sqd, const unsigned short* __restrict__ cand,
    float* __restrict__ e0)
{
    __shared__ double dbuf[4][CAND];
    __shared__ int    icand[4][CAND];
    int wave = threadIdx.x >> 6;
    int lane = threadIdx.x & 63;
    int row  = blockIdx.x * 4 + wave;
    int b    = row / NPT;

    icand[wave][lane] = (int)cand[(size_t)row * CAND + lane];
    __syncthreads();

    int sub = lane & 7, cg = lane >> 3;
    const float* xiRow = xT + (size_t)row * C_;
    float4 xif[6];
#pragma unroll
    for (int q = 0; q < 6; ++q)
        xif[q] = *(const float4*)&xiRow[q * 32 + sub * 4];
    double ivi = invn64[row], sqi = sqd[row];

    for (int cc = 0; cc < CAND / 8; ++cc) {
        int cidx = cc * 8 + cg;
        int j = icand[wave][cidx];
        const float* xjRow = xT + (size_t)(b * NPT + j) * C_;
        float4 v[6];
#pragma unroll
        for (int q = 0; q < 6; ++q)
            v[q] = *(const float4*)&xjRow[q * 32 + sub * 4];
        double d0 = 0.0, d1 = 0.0, d2 = 0.0, d3 = 0.0;
#pragma unroll
        for (int q = 0; q < 6; ++q) {
            d0 = fma((double)xif[q].x, (double)v[q].x, d0);
            d1 = fma((double)xif[q].y, (double)v[q].y, d1);
            d2 = fma((double)xif[q].z, (double)v[q].z, d2);
            d3 = fma((double)xif[q].w, (double)v[q].w, d3);
        }
        double dot = (d0 + d1) + (d2 + d3);
        dot += __shfl_xor(dot, 1);
        dot += __shfl_xor(dot, 2);
        dot += __shfl_xor(dot, 4);
        if (sub == 0)
            dbuf[wave][cidx] = sqi + sqd[(size_t)b * NPT + j]
                             - 2.0 * (ivi * invn64[(size_t)b * NPT + j] * dot);
    }
    __syncthreads();

    double d = dbuf[wave][lane];
    int    j = icand[wave][lane];
    float* p0 = e0 + (size_t)row * KNN;
    for (int q = 0; q < KNN; ++q) {
        double bdv = d; int bjv = j;
#pragma unroll
        for (int off = 32; off > 0; off >>= 1) {
            double od = __shfl_xor(bdv, off);
            int    oj = __shfl_xor(bjv, off);
            if (od < bdv || (od == bdv && oj < bjv)) { bdv = od; bjv = oj; }
        }
        if (lane == 0) p0[q] = (float)bjv;
        if (j == bjv) d = 1e301;
    }
}

// ---------------------------------------------------------------------------
// K4: B = W2 * x. Multi-batch: grid = nb * 49 * botiles;
//   b = bbase + blk/per, B base advanced by bstrideBytes per batch-in-launch.
// ---------------------------------------------------------------------------
__global__ __launch_bounds__(256) void k_gemmB(
    const float* __restrict__ x, const float* __restrict__ cw,
    void* __restrict__ Bq, int bbase, int bcol0, int ldB, int storeBf16,
    int botiles, int bstrideBytes)
{
    int per = 49 * botiles;
    int blk = blockIdx.x;
    int bi  = blk / per;
    int r   = blk % per;
    int b   = bbase + bi;
    int bm = r % 49;
    int bo = r / 49;
    int m0 = bm * 64;
    char* Bp = (char*)Bq + (size_t)bi * (size_t)bstrideBytes;

    __shared__ float Xt[16][68];
    __shared__ float Wt[16][68];
    int tid = threadIdx.x;
    int tx = tid & 15, ty = tid >> 4;
    const float* xb = x + (size_t)b * C_ * NPT;
    float acc[4][4];
#pragma unroll
    for (int u = 0; u < 4; ++u)
#pragma unroll
        for (int v = 0; v < 4; ++v) acc[u][v] = 0.f;

    for (int ct = 0; ct < 12; ++ct) {
        int c0 = ct * 16;
        {
            int cc = tid >> 4, n4 = (tid & 15) * 4;
            *(float4*)&Xt[cc][n4] =
                *(const float4*)&xb[(size_t)(c0 + cc) * NPT + m0 + n4];
        }
        {
            int oo = tid >> 2, c4 = (tid & 3) * 4;
            int o = bcol0 + bo * 64 + oo;
            float4 w = *(const float4*)&cw[(size_t)o * 384 + C_ + c0 + c4];
            Wt[c4 + 0][oo] = w.x; Wt[c4 + 1][oo] = w.y;
            Wt[c4 + 2][oo] = w.z; Wt[c4 + 3][oo] = w.w;
        }
        __syncthreads();
#pragma unroll
        for (int cc = 0; cc < 16; ++cc) {
            float4 av = *(const float4*)&Xt[cc][ty * 4];
            float4 bv = *(const float4*)&Wt[cc][tx * 4];
            float a_[4] = {av.x, av.y, av.z, av.w};
            float b_[4] = {bv.x, bv.y, bv.z, bv.w};
#pragma unroll
            for (int u = 0; u < 4; ++u)
#pragma unroll
                for (int v = 0; v < 4; ++v)
                    acc[u][v] = fmaf(a_[u], b_[v], acc[u][v]);
        }
        __syncthreads();
    }
    if (!storeBf16) {
        float* Bf = (float*)Bp;
#pragma unroll
        for (int u = 0; u < 4; ++u) {
            float4 pk = {acc[u][0], acc[u][1], acc[u][2], acc[u][3]};
            *(float4*)&Bf[(size_t)(m0 + ty * 4 + u) * ldB + bo * 64 + tx * 4] = pk;
        }
    } else {
        unsigned short* Bh = (unsigned short*)Bp;
#pragma unroll
        for (int u = 0; u < 4; ++u) {
            ushort4 pk;
            pk.x = f2u(acc[u][0]); pk.y = f2u(acc[u][1]);
            pk.z = f2u(acc[u][2]); pk.w = f2u(acc[u][3]);
            *(ushort4*)&Bh[(size_t)(m0 + ty * 4 + u) * ldB + bo * 64 + tx * 4] = pk;
        }
    }
}

// ---------------------------------------------------------------------------
// K5: epilogue. Multi-batch like K4.
// ---------------------------------------------------------------------------
__global__ __launch_bounds__(256) void k_outA(
    const float* __restrict__ x, const float* __restrict__ cw,
    const float* __restrict__ e0, const float* __restrict__ cb,
    const float* __restrict__ gam, const float* __restrict__ bet,
    float* __restrict__ out, const void* __restrict__ Bq,
    int bbase, int o0base, int bcol0, int ldB, int readBf16,
    int botiles, int bstrideBytes)
{
    int per = 49 * botiles;
    int blk = blockIdx.x;
    int bi  = blk / per;
    int r   = blk % per;
    int b   = bbase + bi;
    int nt = r % 49, ot = r / 49;
    int n0 = nt * 64, o0 = o0base + ot * 64;
    const char* Bp = (const char*)Bq + (size_t)bi * (size_t)bstrideBytes;

    __shared__ float Xi[16][68];
    __shared__ float Wd[16][68];
    __shared__ int jidx[64 * KNN];
    int tid = threadIdx.x;
    int tx = tid & 15, ty = tid >> 4;
    const float* xb = x + (size_t)b * C_ * NPT;

    for (int e = tid; e < 64 * KNN; e += 256)
        jidx[e] = (int)e0[((size_t)b * NPT + n0 + e / KNN) * KNN + e % KNN];

    float zA[4][4];
#pragma unroll
    for (int u = 0; u < 4; ++u)
#pragma unroll
        for (int v = 0; v < 4; ++v) zA[u][v] = 0.f;

    for (int ct = 0; ct < 12; ++ct) {
        int c0 = ct * 16;
        {
            int cc = tid >> 4, n4 = (tid & 15) * 4;
            *(float4*)&Xi[cc][n4] =
                *(const float4*)&xb[(size_t)(c0 + cc) * NPT + n0 + n4];
        }
        {
            int oo = tid >> 2, c4 = (tid & 3) * 4;
            int o = o0 + oo;
            float4 w1 = *(const float4*)&cw[(size_t)o * 384 + c0 + c4];
            float4 w2 = *(const float4*)&cw[(size_t)o * 384 + C_ + c0 + c4];
            Wd[c4 + 0][oo] = w1.x - w2.x; Wd[c4 + 1][oo] = w1.y - w2.y;
            Wd[c4 + 2][oo] = w1.z - w2.z; Wd[c4 + 3][oo] = w1.w - w2.w;
        }
        __syncthreads();
#pragma unroll
        for (int cc = 0; cc < 16; ++cc) {
            float4 av = *(const float4*)&Xi[cc][ty * 4];
            float4 bv = *(const float4*)&Wd[cc][tx * 4];
            float a_[4] = {av.x, av.y, av.z, av.w};
            float b_[4] = {bv.x, bv.y, bv.z, bv.w};
#pragma unroll
            for (int u = 0; u < 4; ++u)
#pragma unroll
                for (int v = 0; v < 4; ++v)
                    zA[u][v] = fmaf(a_[u], b_[v], zA[u][v]);
        }
        __syncthreads();
    }

    const float inv_s = 0.9999950000374997f;  // 1/sqrt(1+1e-5)
    float gs[4], bts[4], cbs[4];
#pragma unroll
    for (int v = 0; v < 4; ++v) {
        int o = o0 + tx * 4 + v;
        gs[v]  = gam[o] * inv_s;
        bts[v] = bet[o];
        cbs[v] = cb[o];
    }

    float best[4][4];
#pragma unroll
    for (int u = 0; u < 4; ++u)
#pragma unroll
        for (int v = 0; v < 4; ++v) best[u][v] = -1e30f;

    int obB = o0 - bcol0;
    for (int k = 0; k < KNN; ++k) {
#pragma unroll
        for (int u = 0; u < 4; ++u) {
            int j = jidx[(ty * 4 + u) * KNN + k];
            float bvv[4];
            if (!readBf16) {
                float4 g = *(const float4*)
                    ((const float*)Bp + (size_t)j * ldB + obB + tx * 4);
                bvv[0] = g.x; bvv[1] = g.y; bvv[2] = g.z; bvv[3] = g.w;
            } else {
                ushort4 g = *(const ushort4*)
                    ((const unsigned short*)Bp + (size_t)j * ldB + obB + tx * 4);
                bvv[0] = u2f(g.x); bvv[1] = u2f(g.y);
                bvv[2] = u2f(g.z); bvv[3] = u2f(g.w);
            }
#pragma unroll
            for (int v = 0; v < 4; ++v) {
                float z = zA[u][v] + bvv[v] + cbs[v];
                float y = fmaf(z, gs[v], bts[v]);
                float ge = 0.5f * y * (1.0f + erff(y * 0.70710678118654752f));
                best[u][v] = fmaxf(best[u][v], ge);
            }
        }
    }

#pragma unroll
    for (int v = 0; v < 4; ++v) {
        int o = o0 + tx * 4 + v;
        float4 pk = {best[0][v], best[1][v], best[2][v], best[3][v]};
        *(float4*)(out + ((size_t)(b * CO_ + o)) * NPT + n0 + ty * 4) = pk;
    }
}

// ---------------------------------------------------------------------------
// K6: generate edge plane1 (center indices) last.
// ---------------------------------------------------------------------------
__global__ __launch_bounds__(256) void k_center(float* __restrict__ e1)
{
    int p = blockIdx.x * 256 + threadIdx.x;
    if (p >= NROWS * KNN) return;
    e1[p] = (float)((p / KNN) % NPT);
}

// ---------------------------------------------------------------------------
extern "C" void kernel_launch(void* const* d_in, const int* in_sizes, int n_in,
                              void* d_out, int out_size, void* d_ws, size_t ws_size,
                              hipStream_t stream)
{
    const float* x   = (const float*)d_in[0];
    const float* cw  = (const float*)d_in[1];
    const float* cb  = (const float*)d_in[2];
    const float* gam = (const float*)d_in[3];
    const float* bet = (const float*)d_in[4];

    // d_out: FLOAT32. out0 = floats [0, 4,816,896); e0 = [4,816,896,
    // 4,929,792); e1 = [4,929,792, 5,042,688).
    // Scratch liveness:
    //   head:   invn64/sqd/invn32/cand       bytes [0, 1,856,512)  dead@refine
    //   packed: fp16 MFMA fragments          bytes [1,856,512, 6,673,408)
    //           dead@screen
    //   xT:     bytes [9,633,792, 19,267,584) dead@refine
    float* ou   = (float*)d_out;
    float* out0 = ou;
    double* invn64 = (double*)d_out;
    double* sqd    = (double*)((char*)d_out + 100352);
    float*  invn32 = (float*)((char*)d_out + 200704);
    unsigned short* cand =
        (unsigned short*)((char*)d_out + 250880);          // 1,605,632 B
    _Float16* packed = (_Float16*)(ou + 464128);           // 4,816,896 B
    float* xT = ou + 2408448;                              // 9.63 MB
    float* e0 = ou + 4816896;
    float* e1 = ou + 4929792;

    k_norm       <<<NROWS / 256, 256, 0, stream>>>(x, invn32, invn64, sqd);
    k_xpose      <<<B_ * 6 * 98, 256, 0, stream>>>(x, xT);
    k_pack       <<<1176, 256, 0, stream>>>(xT, invn32, packed);
    k_screen_mfma<<<B_ * 49 * 4, 256, 0, stream>>>(packed, cand);
    k_refine     <<<NROWS / 4, 256, 0, stream>>>(xT, invn64, sqd, cand, e0);

    const int BSTRIDE = NPT * CO_ * 4;   // 4,816,896 B per fp32 batch-B
    if (ws_size >= (size_t)B_ * BSTRIDE) {
        // FAST PATH: all-batch fp32 B in d_ws. 2 big launches (1176 blocks).
        k_gemmB<<<B_ * 49 * 6, 256, 0, stream>>>(
            x, cw, d_ws, 0, 0, 384, 0, 6, BSTRIDE);
        k_outA <<<B_ * 49 * 6, 256, 0, stream>>>(
            x, cw, e0, cb, gam, bet, out0, (const void*)d_ws,
            0, 0, 0, 384, 0, 6, BSTRIDE);
    } else {
        // FALLBACK: d_out aliasing discipline (numerics identical to R3 run).
        // P1/P2: batches {2,3} fp32 B23 @ bytes [0, 9,633,792)
        //        (b0+b1 out-region, still scratch); out writes b2/b3 region.
        k_gemmB<<<2 * 49 * 6, 256, 0, stream>>>(
            x, cw, (void*)ou, 2, 0, 384, 0, 6, BSTRIDE);
        k_outA <<<2 * 49 * 6, 256, 0, stream>>>(
            x, cw, e0, cb, gam, bet, out0, (const void*)ou,
            2, 0, 0, 384, 0, 6, BSTRIDE);
        // P3/P4: batch 1 fp32 B1 @ bytes [0, 4,816,896); out -> b1 region.
        k_gemmB<<<49 * 6, 256, 0, stream>>>(
            x, cw, (void*)ou, 1, 0, 384, 0, 6, 0);
        k_outA <<<49 * 6, 256, 0, stream>>>(
            x, cw, e0, cb, gam, bet, out0, (const void*)ou,
            1, 0, 0, 384, 0, 6, 0);
        // Batch 0 in 3 bf16 col-chunks in provably-dead space:
        //  1: cols [192,384) B bf16 @ bytes [0,1,204,224)  out->[2.41M,4.82M)
        //  2: cols [ 64,192) B bf16 @ bytes [0,  802,816)  out->[0.80M,2.41M)
        //  3: cols [  0, 64) B bf16 @ e1     (401,408 B)   out->[0,     0.80M)
        k_gemmB<<<49 * 3, 256, 0, stream>>>(
            x, cw, (void*)ou, 0, 192, 192, 1, 3, 0);
        k_outA <<<49 * 3, 256, 0, stream>>>(
            x, cw, e0, cb, gam, bet, out0, (const void*)ou,
            0, 192, 192, 192, 1, 3, 0);
        k_gemmB<<<49 * 2, 256, 0, stream>>>(
            x, cw, (void*)ou, 0, 64, 128, 1, 2, 0);
        k_outA <<<49 * 2, 256, 0, stream>>>(
            x, cw, e0, cb, gam, bet, out0, (const void*)ou,
            0, 64, 64, 128, 1, 2, 0);
        k_gemmB<<<49 * 1, 256, 0, stream>>>(
            x, cw, (void*)e1, 0, 0, 64, 1, 1, 0);
        k_outA <<<49 * 1, 256, 0, stream>>>(
            x, cw, e0, cb, gam, bet, out0, (const void*)e1,
            0, 0, 0, 64, 1, 1, 0);
    }
    // Generate e1 (center plane) last.
    k_center<<<(NROWS * KNN + 255) / 256, 256, 0, stream>>>(e1);
}

// Round 5
// 305.563 us; speedup vs baseline: 3.0034x; 1.0316x over previous
//
#include <hip/hip_runtime.h>
#include <hip/hip_bf16.h>
#include <math.h>

#define B_    4
#define C_    192
#define NPT   3136          // H*W points per batch
#define CO_   384           // Cout
#define KNN   9
#define CAND  64            // 4 j-chunks * merged top-16 per row
#define NROWS (B_*NPT)      // 12544 total points
#define SD    10            // per-lane screening stream depth

typedef _Float16 half8 __attribute__((ext_vector_type(8)));
typedef float    f32x4 __attribute__((ext_vector_type(4)));

__device__ __forceinline__ float u2f(unsigned short u) {
    unsigned int t = ((unsigned int)u) << 16;
    float f; __builtin_memcpy(&f, &t, 4); return f;
}
__device__ __forceinline__ unsigned short f2u(float f) {
    __hip_bfloat16 h = __float2bfloat16(f);
    unsigned short u; __builtin_memcpy(&u, &h, 2); return u;
}

// ---------------------------------------------------------------------------
// K1: per-point f64 norm stats from fp32 x.
// ---------------------------------------------------------------------------
__global__ __launch_bounds__(256) void k_norm(
    const float* __restrict__ x,
    float* __restrict__ invn32, double* __restrict__ invn64,
    double* __restrict__ sqd)
{
    int p = blockIdx.x * 256 + threadIdx.x;
    if (p >= NROWS) return;
    int b = p / NPT, n = p % NPT;
    const float* xb = x + (size_t)b * C_ * NPT + n;
    double S = 0.0;
    for (int c = 0; c < C_; ++c) {
        double v = (double)xb[(size_t)c * NPT];
        S = fma(v, v, S);
    }
    double nrm = sqrt(S);
    if (nrm < 1e-12) nrm = 1e-12;
    double iv = 1.0 / nrm;
    invn64[p] = iv;
    invn32[p] = (float)iv;
    sqd[p] = iv * iv * S;
}

// ---------------------------------------------------------------------------
// K1b: LDS-tiled transpose x [b][c][n] -> xT [b*NPT+n][c] (fp32, exact).
// ---------------------------------------------------------------------------
__global__ __launch_bounds__(256) void k_xpose(
    const float* __restrict__ x, float* __restrict__ xT)
{
    __shared__ float t[32][33];
    int blk = blockIdx.x;
    int b  = blk / 588;
    int r  = blk % 588;
    int ct = r / 98, nt = r % 98;
    int c0 = ct * 32, n0 = nt * 32;
    int tid = threadIdx.x;
    int tx = tid & 31, ty8 = tid >> 5;          // 8 rows per pass
    const float* xb = x + (size_t)b * C_ * NPT;
#pragma unroll
    for (int e = 0; e < 4; ++e) {
        int cc = ty8 + e * 8;
        t[cc][tx] = xb[(size_t)(c0 + cc) * NPT + n0 + tx];
    }
    __syncthreads();
#pragma unroll
    for (int e = 0; e < 4; ++e) {
        int nn = ty8 + e * 8;
        xT[(size_t)(b * NPT + n0 + nn) * C_ + c0 + tx] = t[tx][nn];
    }
}

// ---------------------------------------------------------------------------
// K1c: pack normalized fp16 fragments for MFMA screening.
// ---------------------------------------------------------------------------
__global__ __launch_bounds__(256) void k_pack(
    const float* __restrict__ xT, const float* __restrict__ invn32,
    _Float16* __restrict__ packed)
{
    int t = blockIdx.x * 256 + threadIdx.x;    // 0 .. 301055
    if (t >= B_ * 196 * 6 * 64) return;
    int l  = t & 63;
    int tk = t >> 6;            // (b*196 + t16)*6 + kk
    int kk = tk % 6;
    int bt = tk / 6;            // b*196 + t16
    int row = bt * 16 + (l & 15);
    int kbase = kk * 32 + (l >> 4) * 8;
    const float* src = xT + (size_t)row * C_ + kbase;
    float iv = invn32[row];
    float4 v0 = *(const float4*)src;
    float4 v1 = *(const float4*)(src + 4);
    half8 h;
    h[0] = (_Float16)(v0.x * iv); h[1] = (_Float16)(v0.y * iv);
    h[2] = (_Float16)(v0.z * iv); h[3] = (_Float16)(v0.w * iv);
    h[4] = (_Float16)(v1.x * iv); h[5] = (_Float16)(v1.y * iv);
    h[6] = (_Float16)(v1.z * iv); h[7] = (_Float16)(v1.w * iv);
    *(half8*)(packed + (size_t)t * 8) = h;
}

// ---------------------------------------------------------------------------
// K2 (MFMA v2): fp16 matrix-core screening, branchless u32-key selection.
// ---------------------------------------------------------------------------
__global__ __launch_bounds__(256) void k_screen_mfma(
    const _Float16* __restrict__ packed, unsigned short* __restrict__ cand)
{
    __shared__ unsigned md[64][4 * SD + 1];   // stride 41
    int blk   = blockIdx.x;
    int chunk = blk & 3;
    int t2    = blk >> 2;
    int b     = t2 / 49;
    int itile = t2 % 49;                 // 64-row i tile
    int tid   = threadIdx.x;
    int wave  = tid >> 6, lane = tid & 63;
    int it    = itile * 4 + wave;        // global 16-row tile within batch

    const _Float16* pb = packed + ((size_t)(b * 196 + it) * 6) * 512 + lane * 8;
    half8 bf[6];
#pragma unroll
    for (int kk = 0; kk < 6; ++kk)
        bf[kk] = *(const half8*)(pb + kk * 512);

    int jt0 = chunk * 48;                 // chunks: 768,768,768,832 cols
    int ntj = (chunk == 3) ? 52 : 48;

    unsigned bd[SD];
#pragma unroll
    for (int q = 0; q < SD; ++q) bd[q] = 0u;

    const _Float16* pa_base =
        packed + ((size_t)(b * 196 + jt0) * 6) * 512 + lane * 8;

    half8 af[6];
#pragma unroll
    for (int kk = 0; kk < 6; ++kk)
        af[kk] = *(const half8*)(pa_base + kk * 512);

    for (int jt = 0; jt < ntj; ++jt) {
        f32x4 acc = {0.f, 0.f, 0.f, 0.f};
#pragma unroll
        for (int kk = 0; kk < 6; ++kk)
            acc = __builtin_amdgcn_mfma_f32_16x16x32_f16(af[kk], bf[kk], acc, 0, 0, 0);

        if (jt + 1 < ntj) {
            const _Float16* pn = pa_base + (size_t)(jt + 1) * 6 * 512;
#pragma unroll
            for (int kk = 0; kk < 6; ++kk)
                af[kk] = *(const half8*)(pn + kk * 512);
        }

        unsigned jb = (unsigned)((jt0 + jt) * 16 + (lane >> 4) * 4);
#pragma unroll
        for (int q = 0; q < 4; ++q) {
            float s = acc[q] + 2.0f;
            unsigned fb = __float_as_uint(s);
            unsigned c = (fb & 0xFFFFF000u) | (jb + (unsigned)q);
#pragma unroll
            for (int t = 0; t < SD; ++t) {
                unsigned old = bd[t];
                unsigned mx = old > c ? old : c;    // v_max_u32
                c           = old > c ? c : old;    // v_min_u32
                bd[t] = mx;
            }
        }
    }

    int ir = wave * 16 + (lane & 15);    // i-row within block (0..63)
    int g  = lane >> 4;                  // stream id
#pragma unroll
    for (int q = 0; q < SD; ++q) md[ir][g * SD + q] = bd[q];
    __syncthreads();

    if (tid < 64) {
        int h[4] = {0, 0, 0, 0};
        unsigned short* cp =
            cand + ((size_t)b * NPT + itile * 64 + tid) * CAND + chunk * 16;
        const unsigned* rd = &md[tid][0];
        for (int s = 0; s < 16; ++s) {
            unsigned best = 0u; int bg = 0;
#pragma unroll
            for (int g2 = 0; g2 < 4; ++g2) {
                unsigned v = (h[g2] < SD) ? rd[g2 * SD + h[g2]] : 0u;
                if (v > best) { best = v; bg = g2; }
            }
            cp[s] = (unsigned short)(best & 0xFFFu);
            h[bg]++;
        }
    }
}

// ---------------------------------------------------------------------------
// K3 v2: f64 refine from xT. Unchanged.
// ---------------------------------------------------------------------------
__global__ __launch_bounds__(256) void k_refine(
    const float* __restrict__ xT, const double* __restrict__ invn64,
    const double* __restrict__ sqd, const unsigned short* __restrict__ cand,
    float* __restrict__ e0)
{
    __shared__ double dbuf[4][CAND];
    __shared__ int    icand[4][CAND];
    int wave = threadIdx.x >> 6;
    int lane = threadIdx.x & 63;
    int row  = blockIdx.x * 4 + wave;
    int b    = row / NPT;

    icand[wave][lane] = (int)cand[(size_t)row * CAND + lane];
    __syncthreads();

    int sub = lane & 7, cg = lane >> 3;
    const float* xiRow = xT + (size_t)row * C_;
    float4 xif[6];
#pragma unroll
    for (int q = 0; q < 6; ++q)
        xif[q] = *(const float4*)&xiRow[q * 32 + sub * 4];
    double ivi = invn64[row], sqi = sqd[row];

    for (int cc = 0; cc < CAND / 8; ++cc) {
        int cidx = cc * 8 + cg;
        int j = icand[wave][cidx];
        const float* xjRow = xT + (size_t)(b * NPT + j) * C_;
        float4 v[6];
#pragma unroll
        for (int q = 0; q < 6; ++q)
            v[q] = *(const float4*)&xjRow[q * 32 + sub * 4];
        double d0 = 0.0, d1 = 0.0, d2 = 0.0, d3 = 0.0;
#pragma unroll
        for (int q = 0; q < 6; ++q) {
            d0 = fma((double)xif[q].x, (double)v[q].x, d0);
            d1 = fma((double)xif[q].y, (double)v[q].y, d1);
            d2 = fma((double)xif[q].z, (double)v[q].z, d2);
            d3 = fma((double)xif[q].w, (double)v[q].w, d3);
        }
        double dot = (d0 + d1) + (d2 + d3);
        dot += __shfl_xor(dot, 1);
        dot += __shfl_xor(dot, 2);
        dot += __shfl_xor(dot, 4);
        if (sub == 0)
            dbuf[wave][cidx] = sqi + sqd[(size_t)b * NPT + j]
                             - 2.0 * (ivi * invn64[(size_t)b * NPT + j] * dot);
    }
    __syncthreads();

    double d = dbuf[wave][lane];
    int    j = icand[wave][lane];
    float* p0 = e0 + (size_t)row * KNN;
    for (int q = 0; q < KNN; ++q) {
        double bdv = d; int bjv = j;
#pragma unroll
        for (int off = 32; off > 0; off >>= 1) {
            double od = __shfl_xor(bdv, off);
            int    oj = __shfl_xor(bjv, off);
            if (od < bdv || (od == bdv && oj < bjv)) { bdv = od; bjv = oj; }
        }
        if (lane == 0) p0[q] = (float)bjv;
        if (j == bjv) d = 1e301;
    }
}

// ---------------------------------------------------------------------------
// K4b: fused dual GEMM (fast path).  For all 4 batches:
//   B  = x . W2          -> bf16, ldB=384   (gather operand, halves BW)
//   zA = x . (W1-W2)+cb  -> fp32, 384      (center term, exact)
//   grid = 4*49*6 blocks, 64x64 tile, 4x4/thread, 3 LDS reads / 32 FMA.
// ---------------------------------------------------------------------------
__global__ __launch_bounds__(256) void k_gemmBoth(
    const float* __restrict__ x, const float* __restrict__ cw,
    const float* __restrict__ cb,
    unsigned short* __restrict__ Bh, float* __restrict__ Zf)
{
    __shared__ float Xt[16][68];
    __shared__ float Wd[16][68];
    __shared__ float W2[16][68];
    int blk = blockIdx.x;
    int b   = blk / 294;
    int r   = blk % 294;
    int bm  = r % 49;
    int bo  = r / 49;
    int m0  = bm * 64;
    int tid = threadIdx.x;
    int tx = tid & 15, ty = tid >> 4;
    const float* xb = x + (size_t)b * C_ * NPT;

    float acc1[4][4], acc2[4][4];
#pragma unroll
    for (int u = 0; u < 4; ++u)
#pragma unroll
        for (int v = 0; v < 4; ++v) { acc1[u][v] = 0.f; acc2[u][v] = 0.f; }

    for (int ct = 0; ct < 12; ++ct) {
        int c0 = ct * 16;
        {
            int cc = tid >> 4, n4 = (tid & 15) * 4;
            *(float4*)&Xt[cc][n4] =
                *(const float4*)&xb[(size_t)(c0 + cc) * NPT + m0 + n4];
        }
        {
            int oo = tid >> 2, c4 = (tid & 3) * 4;
            int o = bo * 64 + oo;
            float4 w1 = *(const float4*)&cw[(size_t)o * 384 + c0 + c4];
            float4 w2 = *(const float4*)&cw[(size_t)o * 384 + C_ + c0 + c4];
            Wd[c4 + 0][oo] = w1.x - w2.x; Wd[c4 + 1][oo] = w1.y - w2.y;
            Wd[c4 + 2][oo] = w1.z - w2.z; Wd[c4 + 3][oo] = w1.w - w2.w;
            W2[c4 + 0][oo] = w2.x; W2[c4 + 1][oo] = w2.y;
            W2[c4 + 2][oo] = w2.z; W2[c4 + 3][oo] = w2.w;
        }
        __syncthreads();
#pragma unroll
        for (int cc = 0; cc < 16; ++cc) {
            float4 av = *(const float4*)&Xt[cc][ty * 4];
            float4 dv = *(const float4*)&Wd[cc][tx * 4];
            float4 wv = *(const float4*)&W2[cc][tx * 4];
            float a_[4] = {av.x, av.y, av.z, av.w};
            float d_[4] = {dv.x, dv.y, dv.z, dv.w};
            float w_[4] = {wv.x, wv.y, wv.z, wv.w};
#pragma unroll
            for (int u = 0; u < 4; ++u)
#pragma unroll
                for (int v = 0; v < 4; ++v) {
                    acc1[u][v] = fmaf(a_[u], d_[v], acc1[u][v]);
                    acc2[u][v] = fmaf(a_[u], w_[v], acc2[u][v]);
                }
        }
        __syncthreads();
    }

    float cbs[4];
#pragma unroll
    for (int v = 0; v < 4; ++v) cbs[v] = cb[bo * 64 + tx * 4 + v];

#pragma unroll
    for (int u = 0; u < 4; ++u) {
        size_t rowb = (size_t)(b * NPT + m0 + ty * 4 + u) * 384 + bo * 64 + tx * 4;
        ushort4 pk;
        pk.x = f2u(acc2[u][0]); pk.y = f2u(acc2[u][1]);
        pk.z = f2u(acc2[u][2]); pk.w = f2u(acc2[u][3]);
        *(ushort4*)&Bh[rowb] = pk;
        float4 za = {acc1[u][0] + cbs[0], acc1[u][1] + cbs[1],
                     acc1[u][2] + cbs[2], acc1[u][3] + cbs[3]};
        *(float4*)&Zf[rowb] = za;
    }
}

// ---------------------------------------------------------------------------
// K5b: gather-only epilogue (fast path). No GEMM, tiny LDS, low VGPR ->
//   high occupancy to hide the scattered bf16 B-row gathers.
// ---------------------------------------------------------------------------
__global__ __launch_bounds__(256) void k_out2(
    const float* __restrict__ e0, const float* __restrict__ gam,
    const float* __restrict__ bet, float* __restrict__ out,
    const unsigned short* __restrict__ Bh, const float* __restrict__ Zf)
{
    __shared__ int jidx[64 * KNN];
    int blk = blockIdx.x;
    int b   = blk / 294;
    int r   = blk % 294;
    int nt  = r % 49, ot = r / 49;
    int n0 = nt * 64, o0 = ot * 64;
    int tid = threadIdx.x;
    int tx = tid & 15, ty = tid >> 4;

    for (int e = tid; e < 64 * KNN; e += 256)
        jidx[e] = (int)e0[((size_t)b * NPT + n0 + e / KNN) * KNN + e % KNN];

    const float inv_s = 0.9999950000374997f;  // 1/sqrt(1+1e-5)
    float gs[4], bts[4];
#pragma unroll
    for (int v = 0; v < 4; ++v) {
        int o = o0 + tx * 4 + v;
        gs[v]  = gam[o] * inv_s;
        bts[v] = bet[o];
    }

    float zA[4][4];
    __syncthreads();
#pragma unroll
    for (int u = 0; u < 4; ++u) {
        float4 z = *(const float4*)
            &Zf[(size_t)(b * NPT + n0 + ty * 4 + u) * 384 + o0 + tx * 4];
        zA[u][0] = z.x; zA[u][1] = z.y; zA[u][2] = z.z; zA[u][3] = z.w;
    }

    float best[4][4];
#pragma unroll
    for (int u = 0; u < 4; ++u)
#pragma unroll
        for (int v = 0; v < 4; ++v) best[u][v] = -1e30f;

    for (int k = 0; k < KNN; ++k) {
#pragma unroll
        for (int u = 0; u < 4; ++u) {
            int j = jidx[(ty * 4 + u) * KNN + k];
            ushort4 g = *(const ushort4*)
                &Bh[(size_t)(b * NPT + j) * 384 + o0 + tx * 4];
            float bvv[4] = {u2f(g.x), u2f(g.y), u2f(g.z), u2f(g.w)};
#pragma unroll
            for (int v = 0; v < 4; ++v) {
                float z = zA[u][v] + bvv[v];
                float y = fmaf(z, gs[v], bts[v]);
                float ge = 0.5f * y * (1.0f + erff(y * 0.70710678118654752f));
                best[u][v] = fmaxf(best[u][v], ge);
            }
        }
    }

#pragma unroll
    for (int v = 0; v < 4; ++v) {
        int o = o0 + tx * 4 + v;
        float4 pk = {best[0][v], best[1][v], best[2][v], best[3][v]};
        *(float4*)(out + ((size_t)(b * CO_ + o)) * NPT + n0 + ty * 4) = pk;
    }
}

// ---------------------------------------------------------------------------
// K4: B = W2 * x (fallback path, multi-batch).
// ---------------------------------------------------------------------------
__global__ __launch_bounds__(256) void k_gemmB(
    const float* __restrict__ x, const float* __restrict__ cw,
    void* __restrict__ Bq, int bbase, int bcol0, int ldB, int storeBf16,
    int botiles, int bstrideBytes)
{
    int per = 49 * botiles;
    int blk = blockIdx.x;
    int bi  = blk / per;
    int r   = blk % per;
    int b   = bbase + bi;
    int bm = r % 49;
    int bo = r / 49;
    int m0 = bm * 64;
    char* Bp = (char*)Bq + (size_t)bi * (size_t)bstrideBytes;

    __shared__ float Xt[16][68];
    __shared__ float Wt[16][68];
    int tid = threadIdx.x;
    int tx = tid & 15, ty = tid >> 4;
    const float* xb = x + (size_t)b * C_ * NPT;
    float acc[4][4];
#pragma unroll
    for (int u = 0; u < 4; ++u)
#pragma unroll
        for (int v = 0; v < 4; ++v) acc[u][v] = 0.f;

    for (int ct = 0; ct < 12; ++ct) {
        int c0 = ct * 16;
        {
            int cc = tid >> 4, n4 = (tid & 15) * 4;
            *(float4*)&Xt[cc][n4] =
                *(const float4*)&xb[(size_t)(c0 + cc) * NPT + m0 + n4];
        }
        {
            int oo = tid >> 2, c4 = (tid & 3) * 4;
            int o = bcol0 + bo * 64 + oo;
            float4 w = *(const float4*)&cw[(size_t)o * 384 + C_ + c0 + c4];
            Wt[c4 + 0][oo] = w.x; Wt[c4 + 1][oo] = w.y;
            Wt[c4 + 2][oo] = w.z; Wt[c4 + 3][oo] = w.w;
        }
        __syncthreads();
#pragma unroll
        for (int cc = 0; cc < 16; ++cc) {
            float4 av = *(const float4*)&Xt[cc][ty * 4];
            float4 bv = *(const float4*)&Wt[cc][tx * 4];
            float a_[4] = {av.x, av.y, av.z, av.w};
            float b_[4] = {bv.x, bv.y, bv.z, bv.w};
#pragma unroll
            for (int u = 0; u < 4; ++u)
#pragma unroll
                for (int v = 0; v < 4; ++v)
                    acc[u][v] = fmaf(a_[u], b_[v], acc[u][v]);
        }
        __syncthreads();
    }
    if (!storeBf16) {
        float* Bf = (float*)Bp;
#pragma unroll
        for (int u = 0; u < 4; ++u) {
            float4 pk = {acc[u][0], acc[u][1], acc[u][2], acc[u][3]};
            *(float4*)&Bf[(size_t)(m0 + ty * 4 + u) * ldB + bo * 64 + tx * 4] = pk;
        }
    } else {
        unsigned short* Bh = (unsigned short*)Bp;
#pragma unroll
        for (int u = 0; u < 4; ++u) {
            ushort4 pk;
            pk.x = f2u(acc[u][0]); pk.y = f2u(acc[u][1]);
            pk.z = f2u(acc[u][2]); pk.w = f2u(acc[u][3]);
            *(ushort4*)&Bh[(size_t)(m0 + ty * 4 + u) * ldB + bo * 64 + tx * 4] = pk;
        }
    }
}

// ---------------------------------------------------------------------------
// K5: fused epilogue (fallback path, multi-batch).
// ---------------------------------------------------------------------------
__global__ __launch_bounds__(256) void k_outA(
    const float* __restrict__ x, const float* __restrict__ cw,
    const float* __restrict__ e0, const float* __restrict__ cb,
    const float* __restrict__ gam, const float* __restrict__ bet,
    float* __restrict__ out, const void* __restrict__ Bq,
    int bbase, int o0base, int bcol0, int ldB, int readBf16,
    int botiles, int bstrideBytes)
{
    int per = 49 * botiles;
    int blk = blockIdx.x;
    int bi  = blk / per;
    int r   = blk % per;
    int b   = bbase + bi;
    int nt = r % 49, ot = r / 49;
    int n0 = nt * 64, o0 = o0base + ot * 64;
    const char* Bp = (const char*)Bq + (size_t)bi * (size_t)bstrideBytes;

    __shared__ float Xi[16][68];
    __shared__ float Wd[16][68];
    __shared__ int jidx[64 * KNN];
    int tid = threadIdx.x;
    int tx = tid & 15, ty = tid >> 4;
    const float* xb = x + (size_t)b * C_ * NPT;

    for (int e = tid; e < 64 * KNN; e += 256)
        jidx[e] = (int)e0[((size_t)b * NPT + n0 + e / KNN) * KNN + e % KNN];

    float zA[4][4];
#pragma unroll
    for (int u = 0; u < 4; ++u)
#pragma unroll
        for (int v = 0; v < 4; ++v) zA[u][v] = 0.f;

    for (int ct = 0; ct < 12; ++ct) {
        int c0 = ct * 16;
        {
            int cc = tid >> 4, n4 = (tid & 15) * 4;
            *(float4*)&Xi[cc][n4] =
                *(const float4*)&xb[(size_t)(c0 + cc) * NPT + n0 + n4];
        }
        {
            int oo = tid >> 2, c4 = (tid & 3) * 4;
            int o = o0 + oo;
            float4 w1 = *(const float4*)&cw[(size_t)o * 384 + c0 + c4];
            float4 w2 = *(const float4*)&cw[(size_t)o * 384 + C_ + c0 + c4];
            Wd[c4 + 0][oo] = w1.x - w2.x; Wd[c4 + 1][oo] = w1.y - w2.y;
            Wd[c4 + 2][oo] = w1.z - w2.z; Wd[c4 + 3][oo] = w1.w - w2.w;
        }
        __syncthreads();
#pragma unroll
        for (int cc = 0; cc < 16; ++cc) {
            float4 av = *(const float4*)&Xi[cc][ty * 4];
            float4 bv = *(const float4*)&Wd[cc][tx * 4];
            float a_[4] = {av.x, av.y, av.z, av.w};
            float b_[4] = {bv.x, bv.y, bv.z, bv.w};
#pragma unroll
            for (int u = 0; u < 4; ++u)
#pragma unroll
                for (int v = 0; v < 4; ++v)
                    zA[u][v] = fmaf(a_[u], b_[v], zA[u][v]);
        }
        __syncthreads();
    }

    const float inv_s = 0.9999950000374997f;  // 1/sqrt(1+1e-5)
    float gs[4], bts[4], cbs[4];
#pragma unroll
    for (int v = 0; v < 4; ++v) {
        int o = o0 + tx * 4 + v;
        gs[v]  = gam[o] * inv_s;
        bts[v] = bet[o];
        cbs[v] = cb[o];
    }

    float best[4][4];
#pragma unroll
    for (int u = 0; u < 4; ++u)
#pragma unroll
        for (int v = 0; v < 4; ++v) best[u][v] = -1e30f;

    int obB = o0 - bcol0;
    for (int k = 0; k < KNN; ++k) {
#pragma unroll
        for (int u = 0; u < 4; ++u) {
            int j = jidx[(ty * 4 + u) * KNN + k];
            float bvv[4];
            if (!readBf16) {
                float4 g = *(const float4*)
                    ((const float*)Bp + (size_t)j * ldB + obB + tx * 4);
                bvv[0] = g.x; bvv[1] = g.y; bvv[2] = g.z; bvv[3] = g.w;
            } else {
                ushort4 g = *(const ushort4*)
                    ((const unsigned short*)Bp + (size_t)j * ldB + obB + tx * 4);
                bvv[0] = u2f(g.x); bvv[1] = u2f(g.y);
                bvv[2] = u2f(g.z); bvv[3] = u2f(g.w);
            }
#pragma unroll
            for (int v = 0; v < 4; ++v) {
                float z = zA[u][v] + bvv[v] + cbs[v];
                float y = fmaf(z, gs[v], bts[v]);
                float ge = 0.5f * y * (1.0f + erff(y * 0.70710678118654752f));
                best[u][v] = fmaxf(best[u][v], ge);
            }
        }
    }

#pragma unroll
    for (int v = 0; v < 4; ++v) {
        int o = o0 + tx * 4 + v;
        float4 pk = {best[0][v], best[1][v], best[2][v], best[3][v]};
        *(float4*)(out + ((size_t)(b * CO_ + o)) * NPT + n0 + ty * 4) = pk;
    }
}

// ---------------------------------------------------------------------------
// K6: generate edge plane1 (center indices) last.
// ---------------------------------------------------------------------------
__global__ __launch_bounds__(256) void k_center(float* __restrict__ e1)
{
    int p = blockIdx.x * 256 + threadIdx.x;
    if (p >= NROWS * KNN) return;
    e1[p] = (float)((p / KNN) % NPT);
}

// ---------------------------------------------------------------------------
extern "C" void kernel_launch(void* const* d_in, const int* in_sizes, int n_in,
                              void* d_out, int out_size, void* d_ws, size_t ws_size,
                              hipStream_t stream)
{
    const float* x   = (const float*)d_in[0];
    const float* cw  = (const float*)d_in[1];
    const float* cb  = (const float*)d_in[2];
    const float* gam = (const float*)d_in[3];
    const float* bet = (const float*)d_in[4];

    // d_out: FLOAT32. out0 = floats [0, 4,816,896); e0 = [4,816,896,
    // 4,929,792); e1 = [4,929,792, 5,042,688).
    // Scratch liveness:
    //   head:   invn64/sqd/invn32/cand       bytes [0, 1,856,512)  dead@refine
    //   packed: fp16 MFMA fragments          bytes [1,856,512, 6,673,408)
    //           dead@screen
    //   xT:     bytes [9,633,792, 19,267,584) dead@refine
    float* ou   = (float*)d_out;
    float* out0 = ou;
    double* invn64 = (double*)d_out;
    double* sqd    = (double*)((char*)d_out + 100352);
    float*  invn32 = (float*)((char*)d_out + 200704);
    unsigned short* cand =
        (unsigned short*)((char*)d_out + 250880);          // 1,605,632 B
    _Float16* packed = (_Float16*)(ou + 464128);           // 4,816,896 B
    float* xT = ou + 2408448;                              // 9.63 MB
    float* e0 = ou + 4816896;
    float* e1 = ou + 4929792;

    k_norm       <<<NROWS / 256, 256, 0, stream>>>(x, invn32, invn64, sqd);
    k_xpose      <<<B_ * 6 * 98, 256, 0, stream>>>(x, xT);
    k_pack       <<<1176, 256, 0, stream>>>(xT, invn32, packed);
    k_screen_mfma<<<B_ * 49 * 4, 256, 0, stream>>>(packed, cand);
    k_refine     <<<NROWS / 4, 256, 0, stream>>>(xT, invn64, sqd, cand, e0);

    const size_t BH_BYTES = (size_t)NROWS * 384 * 2;   //  9,633,792 bf16 B
    const size_t ZF_BYTES = (size_t)NROWS * 384 * 4;   // 19,267,584 fp32 zA
    const int    BSTRIDE  = NPT * CO_ * 4;             // fp32 batch-B stride

    if (ws_size >= BH_BYTES + ZF_BYTES) {
        // FAST PATH: split GEMM / gather. B bf16 + zA fp32 in d_ws.
        unsigned short* wsB = (unsigned short*)d_ws;
        float* wsZ = (float*)((char*)d_ws + BH_BYTES);
        k_gemmBoth<<<B_ * 49 * 6, 256, 0, stream>>>(x, cw, cb, wsB, wsZ);
        k_out2    <<<B_ * 49 * 6, 256, 0, stream>>>(e0, gam, bet, out0,
                                                    wsB, wsZ);
    } else if (ws_size >= ZF_BYTES) {
        // MEDIUM: R4 fast path — all-batch fp32 B in d_ws, fused epilogue.
        k_gemmB<<<B_ * 49 * 6, 256, 0, stream>>>(
            x, cw, d_ws, 0, 0, 384, 0, 6, BSTRIDE);
        k_outA <<<B_ * 49 * 6, 256, 0, stream>>>(
            x, cw, e0, cb, gam, bet, out0, (const void*)d_ws,
            0, 0, 0, 384, 0, 6, BSTRIDE);
    } else {
        // FALLBACK: d_out aliasing discipline (R3-proven numerics).
        k_gemmB<<<2 * 49 * 6, 256, 0, stream>>>(
            x, cw, (void*)ou, 2, 0, 384, 0, 6, BSTRIDE);
        k_outA <<<2 * 49 * 6, 256, 0, stream>>>(
            x, cw, e0, cb, gam, bet, out0, (const void*)ou,
            2, 0, 0, 384, 0, 6, BSTRIDE);
        k_gemmB<<<49 * 6, 256, 0, stream>>>(
            x, cw, (void*)ou, 1, 0, 384, 0, 6, 0);
        k_outA <<<49 * 6, 256, 0, stream>>>(
            x, cw, e0, cb, gam, bet, out0, (const void*)ou,
            1, 0, 0, 384, 0, 6, 0);
        k_gemmB<<<49 * 3, 256, 0, stream>>>(
            x, cw, (void*)ou, 0, 192, 192, 1, 3, 0);
        k_outA <<<49 * 3, 256, 0, stream>>>(
            x, cw, e0, cb, gam, bet, out0, (const void*)ou,
            0, 192, 192, 192, 1, 3, 0);
        k_gemmB<<<49 * 2, 256, 0, stream>>>(
            x, cw, (void*)ou, 0, 64, 128, 1, 2, 0);
        k_outA <<<49 * 2, 256, 0, stream>>>(
            x, cw, e0, cb, gam, bet, out0, (const void*)ou,
            0, 64, 64, 128, 1, 2, 0);
        k_gemmB<<<49 * 1, 256, 0, stream>>>(
            x, cw, (void*)e1, 0, 0, 64, 1, 1, 0);
        k_outA <<<49 * 1, 256, 0, stream>>>(
            x, cw, e0, cb, gam, bet, out0, (const void*)e1,
            0, 0, 0, 64, 1, 1, 0);
    }
    // Generate e1 (center plane) last.
    k_center<<<(NROWS * KNN + 255) / 256, 256, 0, stream>>>(e1);
}

// Round 6
// 263.650 us; speedup vs baseline: 3.4809x; 1.1590x over previous
//
#include <hip/hip_runtime.h>
#include <hip/hip_bf16.h>
#include <math.h>

#define B_    4
#define C_    192
#define NPT   3136          // H*W points per batch
#define CO_   384           // Cout
#define KNN   9
#define CAND  64            // 4 j-chunks * merged top-16 per row
#define NROWS (B_*NPT)      // 12544 total points
#define SD    10            // per-lane screening stream depth

typedef _Float16 half8 __attribute__((ext_vector_type(8)));
typedef float    f32x4 __attribute__((ext_vector_type(4)));

__device__ __forceinline__ float u2f(unsigned short u) {
    unsigned int t = ((unsigned int)u) << 16;
    float f; __builtin_memcpy(&f, &t, 4); return f;
}
__device__ __forceinline__ unsigned short f2u(float f) {
    __hip_bfloat16 h = __float2bfloat16(f);
    unsigned short u; __builtin_memcpy(&u, &h, 2); return u;
}
__device__ __forceinline__ float gelu_exact(float y) {
    return 0.5f * y * (1.0f + erff(y * 0.70710678118654752f));
}

// ---------------------------------------------------------------------------
// K1: per-point f64 norm stats from fp32 x.
// ---------------------------------------------------------------------------
__global__ __launch_bounds__(256) void k_norm(
    const float* __restrict__ x,
    float* __restrict__ invn32, double* __restrict__ invn64,
    double* __restrict__ sqd)
{
    int p = blockIdx.x * 256 + threadIdx.x;
    if (p >= NROWS) return;
    int b = p / NPT, n = p % NPT;
    const float* xb = x + (size_t)b * C_ * NPT + n;
    double S = 0.0;
    for (int c = 0; c < C_; ++c) {
        double v = (double)xb[(size_t)c * NPT];
        S = fma(v, v, S);
    }
    double nrm = sqrt(S);
    if (nrm < 1e-12) nrm = 1e-12;
    double iv = 1.0 / nrm;
    invn64[p] = iv;
    invn32[p] = (float)iv;
    sqd[p] = iv * iv * S;
}

// ---------------------------------------------------------------------------
// K1b: LDS-tiled transpose x [b][c][n] -> xT [b*NPT+n][c] (fp32, exact).
// ---------------------------------------------------------------------------
__global__ __launch_bounds__(256) void k_xpose(
    const float* __restrict__ x, float* __restrict__ xT)
{
    __shared__ float t[32][33];
    int blk = blockIdx.x;
    int b  = blk / 588;
    int r  = blk % 588;
    int ct = r / 98, nt = r % 98;
    int c0 = ct * 32, n0 = nt * 32;
    int tid = threadIdx.x;
    int tx = tid & 31, ty8 = tid >> 5;          // 8 rows per pass
    const float* xb = x + (size_t)b * C_ * NPT;
#pragma unroll
    for (int e = 0; e < 4; ++e) {
        int cc = ty8 + e * 8;
        t[cc][tx] = xb[(size_t)(c0 + cc) * NPT + n0 + tx];
    }
    __syncthreads();
#pragma unroll
    for (int e = 0; e < 4; ++e) {
        int nn = ty8 + e * 8;
        xT[(size_t)(b * NPT + n0 + nn) * C_ + c0 + tx] = t[tx][nn];
    }
}

// ---------------------------------------------------------------------------
// K1c: pack normalized fp16 fragments for MFMA screening.
// ---------------------------------------------------------------------------
__global__ __launch_bounds__(256) void k_pack(
    const float* __restrict__ xT, const float* __restrict__ invn32,
    _Float16* __restrict__ packed)
{
    int t = blockIdx.x * 256 + threadIdx.x;    // 0 .. 301055
    if (t >= B_ * 196 * 6 * 64) return;
    int l  = t & 63;
    int tk = t >> 6;            // (b*196 + t16)*6 + kk
    int kk = tk % 6;
    int bt = tk / 6;            // b*196 + t16
    int row = bt * 16 + (l & 15);
    int kbase = kk * 32 + (l >> 4) * 8;
    const float* src = xT + (size_t)row * C_ + kbase;
    float iv = invn32[row];
    float4 v0 = *(const float4*)src;
    float4 v1 = *(const float4*)(src + 4);
    half8 h;
    h[0] = (_Float16)(v0.x * iv); h[1] = (_Float16)(v0.y * iv);
    h[2] = (_Float16)(v0.z * iv); h[3] = (_Float16)(v0.w * iv);
    h[4] = (_Float16)(v1.x * iv); h[5] = (_Float16)(v1.y * iv);
    h[6] = (_Float16)(v1.z * iv); h[7] = (_Float16)(v1.w * iv);
    *(half8*)(packed + (size_t)t * 8) = h;
}

// ---------------------------------------------------------------------------
// K2 (MFMA v2): fp16 matrix-core screening, branchless u32-key selection.
// ---------------------------------------------------------------------------
__global__ __launch_bounds__(256) void k_screen_mfma(
    const _Float16* __restrict__ packed, unsigned short* __restrict__ cand)
{
    __shared__ unsigned md[64][4 * SD + 1];   // stride 41
    int blk   = blockIdx.x;
    int chunk = blk & 3;
    int t2    = blk >> 2;
    int b     = t2 / 49;
    int itile = t2 % 49;                 // 64-row i tile
    int tid   = threadIdx.x;
    int wave  = tid >> 6, lane = tid & 63;
    int it    = itile * 4 + wave;        // global 16-row tile within batch

    const _Float16* pb = packed + ((size_t)(b * 196 + it) * 6) * 512 + lane * 8;
    half8 bf[6];
#pragma unroll
    for (int kk = 0; kk < 6; ++kk)
        bf[kk] = *(const half8*)(pb + kk * 512);

    int jt0 = chunk * 48;                 // chunks: 768,768,768,832 cols
    int ntj = (chunk == 3) ? 52 : 48;

    unsigned bd[SD];
#pragma unroll
    for (int q = 0; q < SD; ++q) bd[q] = 0u;

    const _Float16* pa_base =
        packed + ((size_t)(b * 196 + jt0) * 6) * 512 + lane * 8;

    half8 af[6];
#pragma unroll
    for (int kk = 0; kk < 6; ++kk)
        af[kk] = *(const half8*)(pa_base + kk * 512);

    for (int jt = 0; jt < ntj; ++jt) {
        f32x4 acc = {0.f, 0.f, 0.f, 0.f};
#pragma unroll
        for (int kk = 0; kk < 6; ++kk)
            acc = __builtin_amdgcn_mfma_f32_16x16x32_f16(af[kk], bf[kk], acc, 0, 0, 0);

        if (jt + 1 < ntj) {
            const _Float16* pn = pa_base + (size_t)(jt + 1) * 6 * 512;
#pragma unroll
            for (int kk = 0; kk < 6; ++kk)
                af[kk] = *(const half8*)(pn + kk * 512);
        }

        unsigned jb = (unsigned)((jt0 + jt) * 16 + (lane >> 4) * 4);
#pragma unroll
        for (int q = 0; q < 4; ++q) {
            float s = acc[q] + 2.0f;
            unsigned fb = __float_as_uint(s);
            unsigned c = (fb & 0xFFFFF000u) | (jb + (unsigned)q);
#pragma unroll
            for (int t = 0; t < SD; ++t) {
                unsigned old = bd[t];
                unsigned mx = old > c ? old : c;    // v_max_u32
                c           = old > c ? c : old;    // v_min_u32
                bd[t] = mx;
            }
        }
    }

    int ir = wave * 16 + (lane & 15);    // i-row within block (0..63)
    int g  = lane >> 4;                  // stream id
#pragma unroll
    for (int q = 0; q < SD; ++q) md[ir][g * SD + q] = bd[q];
    __syncthreads();

    if (tid < 64) {
        int h[4] = {0, 0, 0, 0};
        unsigned short* cp =
            cand + ((size_t)b * NPT + itile * 64 + tid) * CAND + chunk * 16;
        const unsigned* rd = &md[tid][0];
        for (int s = 0; s < 16; ++s) {
            unsigned best = 0u; int bg = 0;
#pragma unroll
            for (int g2 = 0; g2 < 4; ++g2) {
                unsigned v = (h[g2] < SD) ? rd[g2 * SD + h[g2]] : 0u;
                if (v > best) { best = v; bg = g2; }
            }
            cp[s] = (unsigned short)(best & 0xFFFu);
            h[bg]++;
        }
    }
}

// ---------------------------------------------------------------------------
// K3 v2: f64 refine from xT. Unchanged.
// ---------------------------------------------------------------------------
__global__ __launch_bounds__(256) void k_refine(
    const float* __restrict__ xT, const double* __restrict__ invn64,
    const double* __restrict__ sqd, const unsigned short* __restrict__ cand,
    float* __restrict__ e0)
{
    __shared__ double dbuf[4][CAND];
    __shared__ int    icand[4][CAND];
    int wave = threadIdx.x >> 6;
    int lane = threadIdx.x & 63;
    int row  = blockIdx.x * 4 + wave;
    int b    = row / NPT;

    icand[wave][lane] = (int)cand[(size_t)row * CAND + lane];
    __syncthreads();

    int sub = lane & 7, cg = lane >> 3;
    const float* xiRow = xT + (size_t)row * C_;
    float4 xif[6];
#pragma unroll
    for (int q = 0; q < 6; ++q)
        xif[q] = *(const float4*)&xiRow[q * 32 + sub * 4];
    double ivi = invn64[row], sqi = sqd[row];

    for (int cc = 0; cc < CAND / 8; ++cc) {
        int cidx = cc * 8 + cg;
        int j = icand[wave][cidx];
        const float* xjRow = xT + (size_t)(b * NPT + j) * C_;
        float4 v[6];
#pragma unroll
        for (int q = 0; q < 6; ++q)
            v[q] = *(const float4*)&xjRow[q * 32 + sub * 4];
        double d0 = 0.0, d1 = 0.0, d2 = 0.0, d3 = 0.0;
#pragma unroll
        for (int q = 0; q < 6; ++q) {
            d0 = fma((double)xif[q].x, (double)v[q].x, d0);
            d1 = fma((double)xif[q].y, (double)v[q].y, d1);
            d2 = fma((double)xif[q].z, (double)v[q].z, d2);
            d3 = fma((double)xif[q].w, (double)v[q].w, d3);
        }
        double dot = (d0 + d1) + (d2 + d3);
        dot += __shfl_xor(dot, 1);
        dot += __shfl_xor(dot, 2);
        dot += __shfl_xor(dot, 4);
        if (sub == 0)
            dbuf[wave][cidx] = sqi + sqd[(size_t)b * NPT + j]
                             - 2.0 * (ivi * invn64[(size_t)b * NPT + j] * dot);
    }
    __syncthreads();

    double d = dbuf[wave][lane];
    int    j = icand[wave][lane];
    float* p0 = e0 + (size_t)row * KNN;
    for (int q = 0; q < KNN; ++q) {
        double bdv = d; int bjv = j;
#pragma unroll
        for (int off = 32; off > 0; off >>= 1) {
            double od = __shfl_xor(bdv, off);
            int    oj = __shfl_xor(bjv, off);
            if (od < bdv || (od == bdv && oj < bjv)) { bdv = od; bjv = oj; }
        }
        if (lane == 0) p0[q] = (float)bjv;
        if (j == bjv) d = 1e301;
    }
}

// ---------------------------------------------------------------------------
// K4b: fused dual GEMM (fast path).  For all 4 batches:
//   B  = x . W2          -> bf16, ldB=384   (gather operand, halves BW)
//   zA = x . (W1-W2)+cb  -> fp32, 384      (center term, exact)
// ---------------------------------------------------------------------------
__global__ __launch_bounds__(256) void k_gemmBoth(
    const float* __restrict__ x, const float* __restrict__ cw,
    const float* __restrict__ cb,
    unsigned short* __restrict__ Bh, float* __restrict__ Zf)
{
    __shared__ float Xt[16][68];
    __shared__ float Wd[16][68];
    __shared__ float W2[16][68];
    int blk = blockIdx.x;
    int b   = blk / 294;
    int r   = blk % 294;
    int bm  = r % 49;
    int bo  = r / 49;
    int m0  = bm * 64;
    int tid = threadIdx.x;
    int tx = tid & 15, ty = tid >> 4;
    const float* xb = x + (size_t)b * C_ * NPT;

    float acc1[4][4], acc2[4][4];
#pragma unroll
    for (int u = 0; u < 4; ++u)
#pragma unroll
        for (int v = 0; v < 4; ++v) { acc1[u][v] = 0.f; acc2[u][v] = 0.f; }

    for (int ct = 0; ct < 12; ++ct) {
        int c0 = ct * 16;
        {
            int cc = tid >> 4, n4 = (tid & 15) * 4;
            *(float4*)&Xt[cc][n4] =
                *(const float4*)&xb[(size_t)(c0 + cc) * NPT + m0 + n4];
        }
        {
            int oo = tid >> 2, c4 = (tid & 3) * 4;
            int o = bo * 64 + oo;
            float4 w1 = *(const float4*)&cw[(size_t)o * 384 + c0 + c4];
            float4 w2 = *(const float4*)&cw[(size_t)o * 384 + C_ + c0 + c4];
            Wd[c4 + 0][oo] = w1.x - w2.x; Wd[c4 + 1][oo] = w1.y - w2.y;
            Wd[c4 + 2][oo] = w1.z - w2.z; Wd[c4 + 3][oo] = w1.w - w2.w;
            W2[c4 + 0][oo] = w2.x; W2[c4 + 1][oo] = w2.y;
            W2[c4 + 2][oo] = w2.z; W2[c4 + 3][oo] = w2.w;
        }
        __syncthreads();
#pragma unroll
        for (int cc = 0; cc < 16; ++cc) {
            float4 av = *(const float4*)&Xt[cc][ty * 4];
            float4 dv = *(const float4*)&Wd[cc][tx * 4];
            float4 wv = *(const float4*)&W2[cc][tx * 4];
            float a_[4] = {av.x, av.y, av.z, av.w};
            float d_[4] = {dv.x, dv.y, dv.z, dv.w};
            float w_[4] = {wv.x, wv.y, wv.z, wv.w};
#pragma unroll
            for (int u = 0; u < 4; ++u)
#pragma unroll
                for (int v = 0; v < 4; ++v) {
                    acc1[u][v] = fmaf(a_[u], d_[v], acc1[u][v]);
                    acc2[u][v] = fmaf(a_[u], w_[v], acc2[u][v]);
                }
        }
        __syncthreads();
    }

    float cbs[4];
#pragma unroll
    for (int v = 0; v < 4; ++v) cbs[v] = cb[bo * 64 + tx * 4 + v];

#pragma unroll
    for (int u = 0; u < 4; ++u) {
        size_t rowb = (size_t)(b * NPT + m0 + ty * 4 + u) * 384 + bo * 64 + tx * 4;
        ushort4 pk;
        pk.x = f2u(acc2[u][0]); pk.y = f2u(acc2[u][1]);
        pk.z = f2u(acc2[u][2]); pk.w = f2u(acc2[u][3]);
        *(ushort4*)&Bh[rowb] = pk;
        float4 za = {acc1[u][0] + cbs[0], acc1[u][1] + cbs[1],
                     acc1[u][2] + cbs[2], acc1[u][3] + cbs[3]};
        *(float4*)&Zf[rowb] = za;
    }
}

// ---------------------------------------------------------------------------
// K5b v2: gather epilogue with quasiconvex-GELU reduction.
//   GELU (exact) is unimodal (min at y0 ~ -0.752): max over the 9 neighbor
//   y-values = max(GELU(ymin), GELU(ymax)).  Track ymin/ymax with cheap
//   fmin/fmax, evaluate erff only 2x per output element (was 9x).
//   u-outer loop keeps only 8 extrema registers live -> VGPR stays low.
// ---------------------------------------------------------------------------
__global__ __launch_bounds__(256) void k_out2(
    const float* __restrict__ e0, const float* __restrict__ gam,
    const float* __restrict__ bet, float* __restrict__ out,
    const unsigned short* __restrict__ Bh, const float* __restrict__ Zf)
{
    __shared__ int jidx[64 * KNN];
    int blk = blockIdx.x;
    int b   = blk / 294;
    int r   = blk % 294;
    int nt  = r % 49, ot = r / 49;
    int n0 = nt * 64, o0 = ot * 64;
    int tid = threadIdx.x;
    int tx = tid & 15, ty = tid >> 4;

    for (int e = tid; e < 64 * KNN; e += 256)
        jidx[e] = (int)e0[((size_t)b * NPT + n0 + e / KNN) * KNN + e % KNN];

    const float inv_s = 0.9999950000374997f;  // 1/sqrt(1+1e-5)
    float gs[4], bts[4];
#pragma unroll
    for (int v = 0; v < 4; ++v) {
        int o = o0 + tx * 4 + v;
        gs[v]  = gam[o] * inv_s;
        bts[v] = bet[o];
    }
    __syncthreads();

    float best[4][4];
#pragma unroll
    for (int u = 0; u < 4; ++u) {
        float4 z = *(const float4*)
            &Zf[(size_t)(b * NPT + n0 + ty * 4 + u) * 384 + o0 + tx * 4];
        float zA[4] = {z.x, z.y, z.z, z.w};

        float ymin[4], ymax[4];
#pragma unroll
        for (int v = 0; v < 4; ++v) { ymin[v] = 1e30f; ymax[v] = -1e30f; }

        const int* jr = &jidx[(ty * 4 + u) * KNN];
#pragma unroll
        for (int k = 0; k < KNN; ++k) {
            int j = jr[k];
            ushort4 g = *(const ushort4*)
                &Bh[(size_t)(b * NPT + j) * 384 + o0 + tx * 4];
            float bvv[4] = {u2f(g.x), u2f(g.y), u2f(g.z), u2f(g.w)};
#pragma unroll
            for (int v = 0; v < 4; ++v) {
                float y = fmaf(zA[v] + bvv[v], gs[v], bts[v]);
                ymin[v] = fminf(ymin[v], y);
                ymax[v] = fmaxf(ymax[v], y);
            }
        }
#pragma unroll
        for (int v = 0; v < 4; ++v)
            best[u][v] = fmaxf(gelu_exact(ymin[v]), gelu_exact(ymax[v]));
    }

#pragma unroll
    for (int v = 0; v < 4; ++v) {
        int o = o0 + tx * 4 + v;
        float4 pk = {best[0][v], best[1][v], best[2][v], best[3][v]};
        *(float4*)(out + ((size_t)(b * CO_ + o)) * NPT + n0 + ty * 4) = pk;
    }
}

// ---------------------------------------------------------------------------
// K4: B = W2 * x (fallback path, multi-batch).
// ---------------------------------------------------------------------------
__global__ __launch_bounds__(256) void k_gemmB(
    const float* __restrict__ x, const float* __restrict__ cw,
    void* __restrict__ Bq, int bbase, int bcol0, int ldB, int storeBf16,
    int botiles, int bstrideBytes)
{
    int per = 49 * botiles;
    int blk = blockIdx.x;
    int bi  = blk / per;
    int r   = blk % per;
    int b   = bbase + bi;
    int bm = r % 49;
    int bo = r / 49;
    int m0 = bm * 64;
    char* Bp = (char*)Bq + (size_t)bi * (size_t)bstrideBytes;

    __shared__ float Xt[16][68];
    __shared__ float Wt[16][68];
    int tid = threadIdx.x;
    int tx = tid & 15, ty = tid >> 4;
    const float* xb = x + (size_t)b * C_ * NPT;
    float acc[4][4];
#pragma unroll
    for (int u = 0; u < 4; ++u)
#pragma unroll
        for (int v = 0; v < 4; ++v) acc[u][v] = 0.f;

    for (int ct = 0; ct < 12; ++ct) {
        int c0 = ct * 16;
        {
            int cc = tid >> 4, n4 = (tid & 15) * 4;
            *(float4*)&Xt[cc][n4] =
                *(const float4*)&xb[(size_t)(c0 + cc) * NPT + m0 + n4];
        }
        {
            int oo = tid >> 2, c4 = (tid & 3) * 4;
            int o = bcol0 + bo * 64 + oo;
            float4 w = *(const float4*)&cw[(size_t)o * 384 + C_ + c0 + c4];
            Wt[c4 + 0][oo] = w.x; Wt[c4 + 1][oo] = w.y;
            Wt[c4 + 2][oo] = w.z; Wt[c4 + 3][oo] = w.w;
        }
        __syncthreads();
#pragma unroll
        for (int cc = 0; cc < 16; ++cc) {
            float4 av = *(const float4*)&Xt[cc][ty * 4];
            float4 bv = *(const float4*)&Wt[cc][tx * 4];
            float a_[4] = {av.x, av.y, av.z, av.w};
            float b_[4] = {bv.x, bv.y, bv.z, bv.w};
#pragma unroll
            for (int u = 0; u < 4; ++u)
#pragma unroll
                for (int v = 0; v < 4; ++v)
                    acc[u][v] = fmaf(a_[u], b_[v], acc[u][v]);
        }
        __syncthreads();
    }
    if (!storeBf16) {
        float* Bf = (float*)Bp;
#pragma unroll
        for (int u = 0; u < 4; ++u) {
            float4 pk = {acc[u][0], acc[u][1], acc[u][2], acc[u][3]};
            *(float4*)&Bf[(size_t)(m0 + ty * 4 + u) * ldB + bo * 64 + tx * 4] = pk;
        }
    } else {
        unsigned short* Bh = (unsigned short*)Bp;
#pragma unroll
        for (int u = 0; u < 4; ++u) {
            ushort4 pk;
            pk.x = f2u(acc[u][0]); pk.y = f2u(acc[u][1]);
            pk.z = f2u(acc[u][2]); pk.w = f2u(acc[u][3]);
            *(ushort4*)&Bh[(size_t)(m0 + ty * 4 + u) * ldB + bo * 64 + tx * 4] = pk;
        }
    }
}

// ---------------------------------------------------------------------------
// K5: fused epilogue (fallback path, multi-batch). Unchanged (proven).
// ---------------------------------------------------------------------------
__global__ __launch_bounds__(256) void k_outA(
    const float* __restrict__ x, const float* __restrict__ cw,
    const float* __restrict__ e0, const float* __restrict__ cb,
    const float* __restrict__ gam, const float* __restrict__ bet,
    float* __restrict__ out, const void* __restrict__ Bq,
    int bbase, int o0base, int bcol0, int ldB, int readBf16,
    int botiles, int bstrideBytes)
{
    int per = 49 * botiles;
    int blk = blockIdx.x;
    int bi  = blk / per;
    int r   = blk % per;
    int b   = bbase + bi;
    int nt = r % 49, ot = r / 49;
    int n0 = nt * 64, o0 = o0base + ot * 64;
    const char* Bp = (const char*)Bq + (size_t)bi * (size_t)bstrideBytes;

    __shared__ float Xi[16][68];
    __shared__ float Wd[16][68];
    __shared__ int jidx[64 * KNN];
    int tid = threadIdx.x;
    int tx = tid & 15, ty = tid >> 4;
    const float* xb = x + (size_t)b * C_ * NPT;

    for (int e = tid; e < 64 * KNN; e += 256)
        jidx[e] = (int)e0[((size_t)b * NPT + n0 + e / KNN) * KNN + e % KNN];

    float zA[4][4];
#pragma unroll
    for (int u = 0; u < 4; ++u)
#pragma unroll
        for (int v = 0; v < 4; ++v) zA[u][v] = 0.f;

    for (int ct = 0; ct < 12; ++ct) {
        int c0 = ct * 16;
        {
            int cc = tid >> 4, n4 = (tid & 15) * 4;
            *(float4*)&Xi[cc][n4] =
                *(const float4*)&xb[(size_t)(c0 + cc) * NPT + n0 + n4];
        }
        {
            int oo = tid >> 2, c4 = (tid & 3) * 4;
            int o = o0 + oo;
            float4 w1 = *(const float4*)&cw[(size_t)o * 384 + c0 + c4];
            float4 w2 = *(const float4*)&cw[(size_t)o * 384 + C_ + c0 + c4];
            Wd[c4 + 0][oo] = w1.x - w2.x; Wd[c4 + 1][oo] = w1.y - w2.y;
            Wd[c4 + 2][oo] = w1.z - w2.z; Wd[c4 + 3][oo] = w1.w - w2.w;
        }
        __syncthreads();
#pragma unroll
        for (int cc = 0; cc < 16; ++cc) {
            float4 av = *(const float4*)&Xi[cc][ty * 4];
            float4 bv = *(const float4*)&Wd[cc][tx * 4];
            float a_[4] = {av.x, av.y, av.z, av.w};
            float b_[4] = {bv.x, bv.y, bv.z, bv.w};
#pragma unroll
            for (int u = 0; u < 4; ++u)
#pragma unroll
                for (int v = 0; v < 4; ++v)
                    zA[u][v] = fmaf(a_[u], b_[v], zA[u][v]);
        }
        __syncthreads();
    }

    const float inv_s = 0.9999950000374997f;  // 1/sqrt(1+1e-5)
    float gs[4], bts[4], cbs[4];
#pragma unroll
    for (int v = 0; v < 4; ++v) {
        int o = o0 + tx * 4 + v;
        gs[v]  = gam[o] * inv_s;
        bts[v] = bet[o];
        cbs[v] = cb[o];
    }

    float best[4][4];
#pragma unroll
    for (int u = 0; u < 4; ++u)
#pragma unroll
        for (int v = 0; v < 4; ++v) best[u][v] = -1e30f;

    int obB = o0 - bcol0;
    for (int k = 0; k < KNN; ++k) {
#pragma unroll
        for (int u = 0; u < 4; ++u) {
            int j = jidx[(ty * 4 + u) * KNN + k];
            float bvv[4];
            if (!readBf16) {
                float4 g = *(const float4*)
                    ((const float*)Bp + (size_t)j * ldB + obB + tx * 4);
                bvv[0] = g.x; bvv[1] = g.y; bvv[2] = g.z; bvv[3] = g.w;
            } else {
                ushort4 g = *(const ushort4*)
                    ((const unsigned short*)Bp + (size_t)j * ldB + obB + tx * 4);
                bvv[0] = u2f(g.x); bvv[1] = u2f(g.y);
                bvv[2] = u2f(g.z); bvv[3] = u2f(g.w);
            }
#pragma unroll
            for (int v = 0; v < 4; ++v) {
                float z = zA[u][v] + bvv[v] + cbs[v];
                float y = fmaf(z, gs[v], bts[v]);
                float ge = 0.5f * y * (1.0f + erff(y * 0.70710678118654752f));
                best[u][v] = fmaxf(best[u][v], ge);
            }
        }
    }

#pragma unroll
    for (int v = 0; v < 4; ++v) {
        int o = o0 + tx * 4 + v;
        float4 pk = {best[0][v], best[1][v], best[2][v], best[3][v]};
        *(float4*)(out + ((size_t)(b * CO_ + o)) * NPT + n0 + ty * 4) = pk;
    }
}

// ---------------------------------------------------------------------------
// K6: generate edge plane1 (center indices) last.
// ---------------------------------------------------------------------------
__global__ __launch_bounds__(256) void k_center(float* __restrict__ e1)
{
    int p = blockIdx.x * 256 + threadIdx.x;
    if (p >= NROWS * KNN) return;
    e1[p] = (float)((p / KNN) % NPT);
}

// ---------------------------------------------------------------------------
extern "C" void kernel_launch(void* const* d_in, const int* in_sizes, int n_in,
                              void* d_out, int out_size, void* d_ws, size_t ws_size,
                              hipStream_t stream)
{
    const float* x   = (const float*)d_in[0];
    const float* cw  = (const float*)d_in[1];
    const float* cb  = (const float*)d_in[2];
    const float* gam = (const float*)d_in[3];
    const float* bet = (const float*)d_in[4];

    // d_out: FLOAT32. out0 = floats [0, 4,816,896); e0 = [4,816,896,
    // 4,929,792); e1 = [4,929,792, 5,042,688).
    // Scratch liveness:
    //   head:   invn64/sqd/invn32/cand       bytes [0, 1,856,512)  dead@refine
    //   packed: fp16 MFMA fragments          bytes [1,856,512, 6,673,408)
    //           dead@screen
    //   xT:     bytes [9,633,792, 19,267,584) dead@refine
    float* ou   = (float*)d_out;
    float* out0 = ou;
    double* invn64 = (double*)d_out;
    double* sqd    = (double*)((char*)d_out + 100352);
    float*  invn32 = (float*)((char*)d_out + 200704);
    unsigned short* cand =
        (unsigned short*)((char*)d_out + 250880);          // 1,605,632 B
    _Float16* packed = (_Float16*)(ou + 464128);           // 4,816,896 B
    float* xT = ou + 2408448;                              // 9.63 MB
    float* e0 = ou + 4816896;
    float* e1 = ou + 4929792;

    k_norm       <<<NROWS / 256, 256, 0, stream>>>(x, invn32, invn64, sqd);
    k_xpose      <<<B_ * 6 * 98, 256, 0, stream>>>(x, xT);
    k_pack       <<<1176, 256, 0, stream>>>(xT, invn32, packed);
    k_screen_mfma<<<B_ * 49 * 4, 256, 0, stream>>>(packed, cand);
    k_refine     <<<NROWS / 4, 256, 0, stream>>>(xT, invn64, sqd, cand, e0);

    const size_t BH_BYTES = (size_t)NROWS * 384 * 2;   //  9,633,792 bf16 B
    const size_t ZF_BYTES = (size_t)NROWS * 384 * 4;   // 19,267,584 fp32 zA
    const int    BSTRIDE  = NPT * CO_ * 4;             // fp32 batch-B stride

    if (ws_size >= BH_BYTES + ZF_BYTES) {
        // FAST PATH: split GEMM / gather. B bf16 + zA fp32 in d_ws.
        unsigned short* wsB = (unsigned short*)d_ws;
        float* wsZ = (float*)((char*)d_ws + BH_BYTES);
        k_gemmBoth<<<B_ * 49 * 6, 256, 0, stream>>>(x, cw, cb, wsB, wsZ);
        k_out2    <<<B_ * 49 * 6, 256, 0, stream>>>(e0, gam, bet, out0,
                                                    wsB, wsZ);
    } else if (ws_size >= ZF_BYTES) {
        // MEDIUM: R4 fast path — all-batch fp32 B in d_ws, fused epilogue.
        k_gemmB<<<B_ * 49 * 6, 256, 0, stream>>>(
            x, cw, d_ws, 0, 0, 384, 0, 6, BSTRIDE);
        k_outA <<<B_ * 49 * 6, 256, 0, stream>>>(
            x, cw, e0, cb, gam, bet, out0, (const void*)d_ws,
            0, 0, 0, 384, 0, 6, BSTRIDE);
    } else {
        // FALLBACK: d_out aliasing discipline (R3-proven numerics).
        k_gemmB<<<2 * 49 * 6, 256, 0, stream>>>(
            x, cw, (void*)ou, 2, 0, 384, 0, 6, BSTRIDE);
        k_outA <<<2 * 49 * 6, 256, 0, stream>>>(
            x, cw, e0, cb, gam, bet, out0, (const void*)ou,
            2, 0, 0, 384, 0, 6, BSTRIDE);
        k_gemmB<<<49 * 6, 256, 0, stream>>>(
            x, cw, (void*)ou, 1, 0, 384, 0, 6, 0);
        k_outA <<<49 * 6, 256, 0, stream>>>(
            x, cw, e0, cb, gam, bet, out0, (const void*)ou,
            1, 0, 0, 384, 0, 6, 0);
        k_gemmB<<<49 * 3, 256, 0, stream>>>(
            x, cw, (void*)ou, 0, 192, 192, 1, 3, 0);
        k_outA <<<49 * 3, 256, 0, stream>>>(
            x, cw, e0, cb, gam, bet, out0, (const void*)ou,
            0, 192, 192, 192, 1, 3, 0);
        k_gemmB<<<49 * 2, 256, 0, stream>>>(
            x, cw, (void*)ou, 0, 64, 128, 1, 2, 0);
        k_outA <<<49 * 2, 256, 0, stream>>>(
            x, cw, e0, cb, gam, bet, out0, (const void*)ou,
            0, 64, 64, 128, 1, 2, 0);
        k_gemmB<<<49 * 1, 256, 0, stream>>>(
            x, cw, (void*)e1, 0, 0, 64, 1, 1, 0);
        k_outA <<<49 * 1, 256, 0, stream>>>(
            x, cw, e0, cb, gam, bet, out0, (const void*)e1,
            0, 0, 0, 64, 1, 1, 0);
    }
    // Generate e1 (center plane) last.
    k_center<<<(NROWS * KNN + 255) / 256, 256, 0, stream>>>(e1);
}

// Round 7
// 248.889 us; speedup vs baseline: 3.6873x; 1.0593x over previous
//
#include <hip/hip_runtime.h>
#include <hip/hip_bf16.h>
#include <math.h>

#define B_    4
#define C_    192
#define NPT   3136          // H*W points per batch
#define CO_   384           // Cout
#define KNN   9
#define CAND  64            // 4 j-chunks * merged top-16 per row
#define NROWS (B_*NPT)      // 12544 total points
#define SD    10            // per-lane screening stream depth

typedef _Float16 half8 __attribute__((ext_vector_type(8)));
typedef float    f32x4 __attribute__((ext_vector_type(4)));

__device__ __forceinline__ float u2f(unsigned short u) {
    unsigned int t = ((unsigned int)u) << 16;
    float f; __builtin_memcpy(&f, &t, 4); return f;
}
__device__ __forceinline__ unsigned short f2u(float f) {
    __hip_bfloat16 h = __float2bfloat16(f);
    unsigned short u; __builtin_memcpy(&u, &h, 2); return u;
}
__device__ __forceinline__ float gelu_exact(float y) {
    return 0.5f * y * (1.0f + erff(y * 0.70710678118654752f));
}
// sortable u64 key for an f64 (ascending double order == ascending u64 order)
__device__ __forceinline__ unsigned long long dkey(double d) {
    long long sb = __double_as_longlong(d);
    unsigned long long u = (unsigned long long)sb;
    return (sb < 0) ? ~u : (u | 0x8000000000000000ULL);
}

// ---------------------------------------------------------------------------
// K1 v2: per-point f64 norm stats. 196 blocks; 4 waves split the channel
//   range (48 each), fixed-order LDS combine -> deterministic f64 sum.
// ---------------------------------------------------------------------------
__global__ __launch_bounds__(256) void k_norm(
    const float* __restrict__ x,
    float* __restrict__ invn32, double* __restrict__ invn64,
    double* __restrict__ sqd)
{
    __shared__ double part[4][64];
    int wave = threadIdx.x >> 6, lane = threadIdx.x & 63;
    int p0 = blockIdx.x * 64;          // 64 points per block, 196 blocks
    int row = p0 + lane;
    int b = row / NPT, n = row % NPT;
    const float* xb = x + (size_t)b * C_ * NPT + n;
    double S = 0.0;
    int c0 = wave * 48;
    for (int c = c0; c < c0 + 48; ++c) {
        double v = (double)xb[(size_t)c * NPT];
        S = fma(v, v, S);
    }
    part[wave][lane] = S;
    __syncthreads();
    if (threadIdx.x < 64) {
        double T = ((part[0][lane] + part[1][lane]) + part[2][lane])
                 + part[3][lane];
        double nrm = sqrt(T);
        if (nrm < 1e-12) nrm = 1e-12;
        double iv = 1.0 / nrm;
        int prow = p0 + lane;
        invn64[prow] = iv;
        invn32[prow] = (float)iv;
        sqd[prow] = iv * iv * T;
    }
}

// ---------------------------------------------------------------------------
// K1b: LDS-tiled transpose x [b][c][n] -> xT [b*NPT+n][c] (fp32, exact).
// ---------------------------------------------------------------------------
__global__ __launch_bounds__(256) void k_xpose(
    const float* __restrict__ x, float* __restrict__ xT)
{
    __shared__ float t[32][33];
    int blk = blockIdx.x;
    int b  = blk / 588;
    int r  = blk % 588;
    int ct = r / 98, nt = r % 98;
    int c0 = ct * 32, n0 = nt * 32;
    int tid = threadIdx.x;
    int tx = tid & 31, ty8 = tid >> 5;          // 8 rows per pass
    const float* xb = x + (size_t)b * C_ * NPT;
#pragma unroll
    for (int e = 0; e < 4; ++e) {
        int cc = ty8 + e * 8;
        t[cc][tx] = xb[(size_t)(c0 + cc) * NPT + n0 + tx];
    }
    __syncthreads();
#pragma unroll
    for (int e = 0; e < 4; ++e) {
        int nn = ty8 + e * 8;
        xT[(size_t)(b * NPT + n0 + nn) * C_ + c0 + tx] = t[tx][nn];
    }
}

// ---------------------------------------------------------------------------
// K1c: pack normalized fp16 fragments for MFMA screening.
// ---------------------------------------------------------------------------
__global__ __launch_bounds__(256) void k_pack(
    const float* __restrict__ xT, const float* __restrict__ invn32,
    _Float16* __restrict__ packed)
{
    int t = blockIdx.x * 256 + threadIdx.x;    // 0 .. 301055
    if (t >= B_ * 196 * 6 * 64) return;
    int l  = t & 63;
    int tk = t >> 6;            // (b*196 + t16)*6 + kk
    int kk = tk % 6;
    int bt = tk / 6;            // b*196 + t16
    int row = bt * 16 + (l & 15);
    int kbase = kk * 32 + (l >> 4) * 8;
    const float* src = xT + (size_t)row * C_ + kbase;
    float iv = invn32[row];
    float4 v0 = *(const float4*)src;
    float4 v1 = *(const float4*)(src + 4);
    half8 h;
    h[0] = (_Float16)(v0.x * iv); h[1] = (_Float16)(v0.y * iv);
    h[2] = (_Float16)(v0.z * iv); h[3] = (_Float16)(v0.w * iv);
    h[4] = (_Float16)(v1.x * iv); h[5] = (_Float16)(v1.y * iv);
    h[6] = (_Float16)(v1.z * iv); h[7] = (_Float16)(v1.w * iv);
    *(half8*)(packed + (size_t)t * 8) = h;
}

// ---------------------------------------------------------------------------
// K2 (MFMA v2): fp16 matrix-core screening, branchless u32-key selection.
// ---------------------------------------------------------------------------
__global__ __launch_bounds__(256) void k_screen_mfma(
    const _Float16* __restrict__ packed, unsigned short* __restrict__ cand)
{
    __shared__ unsigned md[64][4 * SD + 1];   // stride 41
    int blk   = blockIdx.x;
    int chunk = blk & 3;
    int t2    = blk >> 2;
    int b     = t2 / 49;
    int itile = t2 % 49;                 // 64-row i tile
    int tid   = threadIdx.x;
    int wave  = tid >> 6, lane = tid & 63;
    int it    = itile * 4 + wave;        // global 16-row tile within batch

    const _Float16* pb = packed + ((size_t)(b * 196 + it) * 6) * 512 + lane * 8;
    half8 bf[6];
#pragma unroll
    for (int kk = 0; kk < 6; ++kk)
        bf[kk] = *(const half8*)(pb + kk * 512);

    int jt0 = chunk * 48;                 // chunks: 768,768,768,832 cols
    int ntj = (chunk == 3) ? 52 : 48;

    unsigned bd[SD];
#pragma unroll
    for (int q = 0; q < SD; ++q) bd[q] = 0u;

    const _Float16* pa_base =
        packed + ((size_t)(b * 196 + jt0) * 6) * 512 + lane * 8;

    half8 af[6];
#pragma unroll
    for (int kk = 0; kk < 6; ++kk)
        af[kk] = *(const half8*)(pa_base + kk * 512);

    for (int jt = 0; jt < ntj; ++jt) {
        f32x4 acc = {0.f, 0.f, 0.f, 0.f};
#pragma unroll
        for (int kk = 0; kk < 6; ++kk)
            acc = __builtin_amdgcn_mfma_f32_16x16x32_f16(af[kk], bf[kk], acc, 0, 0, 0);

        if (jt + 1 < ntj) {
            const _Float16* pn = pa_base + (size_t)(jt + 1) * 6 * 512;
#pragma unroll
            for (int kk = 0; kk < 6; ++kk)
                af[kk] = *(const half8*)(pn + kk * 512);
        }

        unsigned jb = (unsigned)((jt0 + jt) * 16 + (lane >> 4) * 4);
#pragma unroll
        for (int q = 0; q < 4; ++q) {
            float s = acc[q] + 2.0f;
            unsigned fb = __float_as_uint(s);
            unsigned c = (fb & 0xFFFFF000u) | (jb + (unsigned)q);
#pragma unroll
            for (int t = 0; t < SD; ++t) {
                unsigned old = bd[t];
                unsigned mx = old > c ? old : c;    // v_max_u32
                c           = old > c ? c : old;    // v_min_u32
                bd[t] = mx;
            }
        }
    }

    int ir = wave * 16 + (lane & 15);    // i-row within block (0..63)
    int g  = lane >> 4;                  // stream id
#pragma unroll
    for (int q = 0; q < SD; ++q) md[ir][g * SD + q] = bd[q];
    __syncthreads();

    if (tid < 64) {
        int h[4] = {0, 0, 0, 0};
        unsigned short* cp =
            cand + ((size_t)b * NPT + itile * 64 + tid) * CAND + chunk * 16;
        const unsigned* rd = &md[tid][0];
        for (int s = 0; s < 16; ++s) {
            unsigned best = 0u; int bg = 0;
#pragma unroll
            for (int g2 = 0; g2 < 4; ++g2) {
                unsigned v = (h[g2] < SD) ? rd[g2 * SD + h[g2]] : 0u;
                if (v > best) { best = v; bg = g2; }
            }
            cp[s] = (unsigned short)(best & 0xFFFu);
            h[bg]++;
        }
    }
}

// ---------------------------------------------------------------------------
// K3 v3: f64 refine, pipelined loads + rank-based top-9.
//   Dot phase: ping-pong prefetch of candidate fragments (A/B) so scattered
//   L2 reads overlap the f64 FMA chain. At sub==0, the distance is packed
//   into a sortable u64 key in LDS.
//   Selection: lane m ranks its candidate with 64 broadcast LDS reads and
//   branchless compares (tie: idx asc) — comparator identical to the old
//   9-round butterfly, output bit-identical; no serial shuffle chain.
// ---------------------------------------------------------------------------
__global__ __launch_bounds__(256) void k_refine(
    const float* __restrict__ xT, const double* __restrict__ invn64,
    const double* __restrict__ sqd, const unsigned short* __restrict__ cand,
    float* __restrict__ e0)
{
    __shared__ unsigned long long kbuf[4][CAND];
    __shared__ int icand[4][CAND];
    int wave = threadIdx.x >> 6;
    int lane = threadIdx.x & 63;
    int row  = blockIdx.x * 4 + wave;
    int b    = row / NPT;
    size_t bN = (size_t)b * NPT;

    icand[wave][lane] = (int)cand[(size_t)row * CAND + lane];
    __syncthreads();

    int sub = lane & 7, cg = lane >> 3;
    const float* xiRow = xT + (size_t)row * C_ + sub * 4;
    float4 xif[6];
#pragma unroll
    for (int q = 0; q < 6; ++q)
        xif[q] = *(const float4*)&xiRow[q * 32];
    double ivi = invn64[row], sqi = sqd[row];

    // prologue: load candidate cg (round 0) into A
    int jA = icand[wave][cg];
    const float* pA = xT + (bN + jA) * C_ + sub * 4;
    float4 vA[6];
#pragma unroll
    for (int q = 0; q < 6; ++q) vA[q] = *(const float4*)&pA[q * 32];
    double ivA = invn64[bN + jA], sqA = sqd[bN + jA];

#pragma unroll
    for (int cc = 0; cc < 8; cc += 2) {
        // prefetch B = candidate (cc+1)*8+cg
        int jB = icand[wave][(cc + 1) * 8 + cg];
        const float* pB = xT + (bN + jB) * C_ + sub * 4;
        float4 vB[6];
#pragma unroll
        for (int q = 0; q < 6; ++q) vB[q] = *(const float4*)&pB[q * 32];
        double ivB = invn64[bN + jB], sqB = sqd[bN + jB];

        // compute A
        {
            double d0 = 0.0, d1 = 0.0, d2 = 0.0, d3 = 0.0;
#pragma unroll
            for (int q = 0; q < 6; ++q) {
                d0 = fma((double)xif[q].x, (double)vA[q].x, d0);
                d1 = fma((double)xif[q].y, (double)vA[q].y, d1);
                d2 = fma((double)xif[q].z, (double)vA[q].z, d2);
                d3 = fma((double)xif[q].w, (double)vA[q].w, d3);
            }
            double dot = (d0 + d1) + (d2 + d3);
            dot += __shfl_xor(dot, 1);
            dot += __shfl_xor(dot, 2);
            dot += __shfl_xor(dot, 4);
            if (sub == 0) {
                double dist = sqi + sqA - 2.0 * (ivi * ivA * dot);
                kbuf[wave][cc * 8 + cg] = dkey(dist);
            }
        }
        // prefetch next A = candidate (cc+2)*8+cg
        if (cc + 2 < 8) {
            int jn = icand[wave][(cc + 2) * 8 + cg];
            const float* pn = xT + (bN + jn) * C_ + sub * 4;
#pragma unroll
            for (int q = 0; q < 6; ++q) vA[q] = *(const float4*)&pn[q * 32];
            ivA = invn64[bN + jn]; sqA = sqd[bN + jn];
        }
        // compute B
        {
            double d0 = 0.0, d1 = 0.0, d2 = 0.0, d3 = 0.0;
#pragma unroll
            for (int q = 0; q < 6; ++q) {
                d0 = fma((double)xif[q].x, (double)vB[q].x, d0);
                d1 = fma((double)xif[q].y, (double)vB[q].y, d1);
                d2 = fma((double)xif[q].z, (double)vB[q].z, d2);
                d3 = fma((double)xif[q].w, (double)vB[q].w, d3);
            }
            double dot = (d0 + d1) + (d2 + d3);
            dot += __shfl_xor(dot, 1);
            dot += __shfl_xor(dot, 2);
            dot += __shfl_xor(dot, 4);
            if (sub == 0) {
                double dist = sqi + sqB - 2.0 * (ivi * ivB * dot);
                kbuf[wave][(cc + 1) * 8 + cg] = dkey(dist);
            }
        }
    }
    __syncthreads();

    // rank-based top-9: all 64 candidates distinct (disjoint chunk ranges),
    // so (key, idx) ranks form a permutation; ranks 0..8 written.
    unsigned long long kd = kbuf[wave][lane];
    int jme = icand[wave][lane];
    int rank = 0;
#pragma unroll
    for (int m = 0; m < CAND; ++m) {
        unsigned long long km = kbuf[wave][m];
        int jm = icand[wave][m];
        rank += ((km < kd) || (km == kd && jm < jme)) ? 1 : 0;
    }
    if (rank < KNN)
        e0[(size_t)row * KNN + rank] = (float)jme;
}

// ---------------------------------------------------------------------------
// K4b: fused dual GEMM (fast path).  For all 4 batches:
//   B  = x . W2          -> bf16, ldB=384   (gather operand, halves BW)
//   zA = x . (W1-W2)+cb  -> fp32, 384      (center term, exact)
// ---------------------------------------------------------------------------
__global__ __launch_bounds__(256) void k_gemmBoth(
    const float* __restrict__ x, const float* __restrict__ cw,
    const float* __restrict__ cb,
    unsigned short* __restrict__ Bh, float* __restrict__ Zf)
{
    __shared__ float Xt[16][68];
    __shared__ float Wd[16][68];
    __shared__ float W2[16][68];
    int blk = blockIdx.x;
    int b   = blk / 294;
    int r   = blk % 294;
    int bm  = r % 49;
    int bo  = r / 49;
    int m0  = bm * 64;
    int tid = threadIdx.x;
    int tx = tid & 15, ty = tid >> 4;
    const float* xb = x + (size_t)b * C_ * NPT;

    float acc1[4][4], acc2[4][4];
#pragma unroll
    for (int u = 0; u < 4; ++u)
#pragma unroll
        for (int v = 0; v < 4; ++v) { acc1[u][v] = 0.f; acc2[u][v] = 0.f; }

    for (int ct = 0; ct < 12; ++ct) {
        int c0 = ct * 16;
        {
            int cc = tid >> 4, n4 = (tid & 15) * 4;
            *(float4*)&Xt[cc][n4] =
                *(const float4*)&xb[(size_t)(c0 + cc) * NPT + m0 + n4];
        }
        {
            int oo = tid >> 2, c4 = (tid & 3) * 4;
            int o = bo * 64 + oo;
            float4 w1 = *(const float4*)&cw[(size_t)o * 384 + c0 + c4];
            float4 w2 = *(const float4*)&cw[(size_t)o * 384 + C_ + c0 + c4];
            Wd[c4 + 0][oo] = w1.x - w2.x; Wd[c4 + 1][oo] = w1.y - w2.y;
            Wd[c4 + 2][oo] = w1.z - w2.z; Wd[c4 + 3][oo] = w1.w - w2.w;
            W2[c4 + 0][oo] = w2.x; W2[c4 + 1][oo] = w2.y;
            W2[c4 + 2][oo] = w2.z; W2[c4 + 3][oo] = w2.w;
        }
        __syncthreads();
#pragma unroll
        for (int cc = 0; cc < 16; ++cc) {
            float4 av = *(const float4*)&Xt[cc][ty * 4];
            float4 dv = *(const float4*)&Wd[cc][tx * 4];
            float4 wv = *(const float4*)&W2[cc][tx * 4];
            float a_[4] = {av.x, av.y, av.z, av.w};
            float d_[4] = {dv.x, dv.y, dv.z, dv.w};
            float w_[4] = {wv.x, wv.y, wv.z, wv.w};
#pragma unroll
            for (int u = 0; u < 4; ++u)
#pragma unroll
                for (int v = 0; v < 4; ++v) {
                    acc1[u][v] = fmaf(a_[u], d_[v], acc1[u][v]);
                    acc2[u][v] = fmaf(a_[u], w_[v], acc2[u][v]);
                }
        }
        __syncthreads();
    }

    float cbs[4];
#pragma unroll
    for (int v = 0; v < 4; ++v) cbs[v] = cb[bo * 64 + tx * 4 + v];

#pragma unroll
    for (int u = 0; u < 4; ++u) {
        size_t rowb = (size_t)(b * NPT + m0 + ty * 4 + u) * 384 + bo * 64 + tx * 4;
        ushort4 pk;
        pk.x = f2u(acc2[u][0]); pk.y = f2u(acc2[u][1]);
        pk.z = f2u(acc2[u][2]); pk.w = f2u(acc2[u][3]);
        *(ushort4*)&Bh[rowb] = pk;
        float4 za = {acc1[u][0] + cbs[0], acc1[u][1] + cbs[1],
                     acc1[u][2] + cbs[2], acc1[u][3] + cbs[3]};
        *(float4*)&Zf[rowb] = za;
    }
}

// ---------------------------------------------------------------------------
// K5b v2: gather epilogue with quasiconvex-GELU reduction.
// ---------------------------------------------------------------------------
__global__ __launch_bounds__(256) void k_out2(
    const float* __restrict__ e0, const float* __restrict__ gam,
    const float* __restrict__ bet, float* __restrict__ out,
    const unsigned short* __restrict__ Bh, const float* __restrict__ Zf)
{
    __shared__ int jidx[64 * KNN];
    int blk = blockIdx.x;
    int b   = blk / 294;
    int r   = blk % 294;
    int nt  = r % 49, ot = r / 49;
    int n0 = nt * 64, o0 = ot * 64;
    int tid = threadIdx.x;
    int tx = tid & 15, ty = tid >> 4;

    for (int e = tid; e < 64 * KNN; e += 256)
        jidx[e] = (int)e0[((size_t)b * NPT + n0 + e / KNN) * KNN + e % KNN];

    const float inv_s = 0.9999950000374997f;  // 1/sqrt(1+1e-5)
    float gs[4], bts[4];
#pragma unroll
    for (int v = 0; v < 4; ++v) {
        int o = o0 + tx * 4 + v;
        gs[v]  = gam[o] * inv_s;
        bts[v] = bet[o];
    }
    __syncthreads();

    float best[4][4];
#pragma unroll
    for (int u = 0; u < 4; ++u) {
        float4 z = *(const float4*)
            &Zf[(size_t)(b * NPT + n0 + ty * 4 + u) * 384 + o0 + tx * 4];
        float zA[4] = {z.x, z.y, z.z, z.w};

        float ymin[4], ymax[4];
#pragma unroll
        for (int v = 0; v < 4; ++v) { ymin[v] = 1e30f; ymax[v] = -1e30f; }

        const int* jr = &jidx[(ty * 4 + u) * KNN];
#pragma unroll
        for (int k = 0; k < KNN; ++k) {
            int j = jr[k];
            ushort4 g = *(const ushort4*)
                &Bh[(size_t)(b * NPT + j) * 384 + o0 + tx * 4];
            float bvv[4] = {u2f(g.x), u2f(g.y), u2f(g.z), u2f(g.w)};
#pragma unroll
            for (int v = 0; v < 4; ++v) {
                float y = fmaf(zA[v] + bvv[v], gs[v], bts[v]);
                ymin[v] = fminf(ymin[v], y);
                ymax[v] = fmaxf(ymax[v], y);
            }
        }
#pragma unroll
        for (int v = 0; v < 4; ++v)
            best[u][v] = fmaxf(gelu_exact(ymin[v]), gelu_exact(ymax[v]));
    }

#pragma unroll
    for (int v = 0; v < 4; ++v) {
        int o = o0 + tx * 4 + v;
        float4 pk = {best[0][v], best[1][v], best[2][v], best[3][v]};
        *(float4*)(out + ((size_t)(b * CO_ + o)) * NPT + n0 + ty * 4) = pk;
    }
}

// ---------------------------------------------------------------------------
// K4: B = W2 * x (fallback path, multi-batch).
// ---------------------------------------------------------------------------
__global__ __launch_bounds__(256) void k_gemmB(
    const float* __restrict__ x, const float* __restrict__ cw,
    void* __restrict__ Bq, int bbase, int bcol0, int ldB, int storeBf16,
    int botiles, int bstrideBytes)
{
    int per = 49 * botiles;
    int blk = blockIdx.x;
    int bi  = blk / per;
    int r   = blk % per;
    int b   = bbase + bi;
    int bm = r % 49;
    int bo = r / 49;
    int m0 = bm * 64;
    char* Bp = (char*)Bq + (size_t)bi * (size_t)bstrideBytes;

    __shared__ float Xt[16][68];
    __shared__ float Wt[16][68];
    int tid = threadIdx.x;
    int tx = tid & 15, ty = tid >> 4;
    const float* xb = x + (size_t)b * C_ * NPT;
    float acc[4][4];
#pragma unroll
    for (int u = 0; u < 4; ++u)
#pragma unroll
        for (int v = 0; v < 4; ++v) acc[u][v] = 0.f;

    for (int ct = 0; ct < 12; ++ct) {
        int c0 = ct * 16;
        {
            int cc = tid >> 4, n4 = (tid & 15) * 4;
            *(float4*)&Xt[cc][n4] =
                *(const float4*)&xb[(size_t)(c0 + cc) * NPT + m0 + n4];
        }
        {
            int oo = tid >> 2, c4 = (tid & 3) * 4;
            int o = bcol0 + bo * 64 + oo;
            float4 w = *(const float4*)&cw[(size_t)o * 384 + C_ + c0 + c4];
            Wt[c4 + 0][oo] = w.x; Wt[c4 + 1][oo] = w.y;
            Wt[c4 + 2][oo] = w.z; Wt[c4 + 3][oo] = w.w;
        }
        __syncthreads();
#pragma unroll
        for (int cc = 0; cc < 16; ++cc) {
            float4 av = *(const float4*)&Xt[cc][ty * 4];
            float4 bv = *(const float4*)&Wt[cc][tx * 4];
            float a_[4] = {av.x, av.y, av.z, av.w};
            float b_[4] = {bv.x, bv.y, bv.z, bv.w};
#pragma unroll
            for (int u = 0; u < 4; ++u)
#pragma unroll
                for (int v = 0; v < 4; ++v)
                    acc[u][v] = fmaf(a_[u], b_[v], acc[u][v]);
        }
        __syncthreads();
    }
    if (!storeBf16) {
        float* Bf = (float*)Bp;
#pragma unroll
        for (int u = 0; u < 4; ++u) {
            float4 pk = {acc[u][0], acc[u][1], acc[u][2], acc[u][3]};
            *(float4*)&Bf[(size_t)(m0 + ty * 4 + u) * ldB + bo * 64 + tx * 4] = pk;
        }
    } else {
        unsigned short* Bh = (unsigned short*)Bp;
#pragma unroll
        for (int u = 0; u < 4; ++u) {
            ushort4 pk;
            pk.x = f2u(acc[u][0]); pk.y = f2u(acc[u][1]);
            pk.z = f2u(acc[u][2]); pk.w = f2u(acc[u][3]);
            *(ushort4*)&Bh[(size_t)(m0 + ty * 4 + u) * ldB + bo * 64 + tx * 4] = pk;
        }
    }
}

// ---------------------------------------------------------------------------
// K5: fused epilogue (fallback path, multi-batch). Unchanged (proven).
// ---------------------------------------------------------------------------
__global__ __launch_bounds__(256) void k_outA(
    const float* __restrict__ x, const float* __restrict__ cw,
    const float* __restrict__ e0, const float* __restrict__ cb,
    const float* __restrict__ gam, const float* __restrict__ bet,
    float* __restrict__ out, const void* __restrict__ Bq,
    int bbase, int o0base, int bcol0, int ldB, int readBf16,
    int botiles, int bstrideBytes)
{
    int per = 49 * botiles;
    int blk = blockIdx.x;
    int bi  = blk / per;
    int r   = blk % per;
    int b   = bbase + bi;
    int nt = r % 49, ot = r / 49;
    int n0 = nt * 64, o0 = o0base + ot * 64;
    const char* Bp = (const char*)Bq + (size_t)bi * (size_t)bstrideBytes;

    __shared__ float Xi[16][68];
    __shared__ float Wd[16][68];
    __shared__ int jidx[64 * KNN];
    int tid = threadIdx.x;
    int tx = tid & 15, ty = tid >> 4;
    const float* xb = x + (size_t)b * C_ * NPT;

    for (int e = tid; e < 64 * KNN; e += 256)
        jidx[e] = (int)e0[((size_t)b * NPT + n0 + e / KNN) * KNN + e % KNN];

    float zA[4][4];
#pragma unroll
    for (int u = 0; u < 4; ++u)
#pragma unroll
        for (int v = 0; v < 4; ++v) zA[u][v] = 0.f;

    for (int ct = 0; ct < 12; ++ct) {
        int c0 = ct * 16;
        {
            int cc = tid >> 4, n4 = (tid & 15) * 4;
            *(float4*)&Xi[cc][n4] =
                *(const float4*)&xb[(size_t)(c0 + cc) * NPT + n0 + n4];
        }
        {
            int oo = tid >> 2, c4 = (tid & 3) * 4;
            int o = o0 + oo;
            float4 w1 = *(const float4*)&cw[(size_t)o * 384 + c0 + c4];
            float4 w2 = *(const float4*)&cw[(size_t)o * 384 + C_ + c0 + c4];
            Wd[c4 + 0][oo] = w1.x - w2.x; Wd[c4 + 1][oo] = w1.y - w2.y;
            Wd[c4 + 2][oo] = w1.z - w2.z; Wd[c4 + 3][oo] = w1.w - w2.w;
        }
        __syncthreads();
#pragma unroll
        for (int cc = 0; cc < 16; ++cc) {
            float4 av = *(const float4*)&Xi[cc][ty * 4];
            float4 bv = *(const float4*)&Wd[cc][tx * 4];
            float a_[4] = {av.x, av.y, av.z, av.w};
            float b_[4] = {bv.x, bv.y, bv.z, bv.w};
#pragma unroll
            for (int u = 0; u < 4; ++u)
#pragma unroll
                for (int v = 0; v < 4; ++v)
                    zA[u][v] = fmaf(a_[u], b_[v], zA[u][v]);
        }
        __syncthreads();
    }

    const float inv_s = 0.9999950000374997f;  // 1/sqrt(1+1e-5)
    float gs[4], bts[4], cbs[4];
#pragma unroll
    for (int v = 0; v < 4; ++v) {
        int o = o0 + tx * 4 + v;
        gs[v]  = gam[o] * inv_s;
        bts[v] = bet[o];
        cbs[v] = cb[o];
    }

    float best[4][4];
#pragma unroll
    for (int u = 0; u < 4; ++u)
#pragma unroll
        for (int v = 0; v < 4; ++v) best[u][v] = -1e30f;

    int obB = o0 - bcol0;
    for (int k = 0; k < KNN; ++k) {
#pragma unroll
        for (int u = 0; u < 4; ++u) {
            int j = jidx[(ty * 4 + u) * KNN + k];
            float bvv[4];
            if (!readBf16) {
                float4 g = *(const float4*)
                    ((const float*)Bp + (size_t)j * ldB + obB + tx * 4);
                bvv[0] = g.x; bvv[1] = g.y; bvv[2] = g.z; bvv[3] = g.w;
            } else {
                ushort4 g = *(const ushort4*)
                    ((const unsigned short*)Bp + (size_t)j * ldB + obB + tx * 4);
                bvv[0] = u2f(g.x); bvv[1] = u2f(g.y);
                bvv[2] = u2f(g.z); bvv[3] = u2f(g.w);
            }
#pragma unroll
            for (int v = 0; v < 4; ++v) {
                float z = zA[u][v] + bvv[v] + cbs[v];
                float y = fmaf(z, gs[v], bts[v]);
                float ge = 0.5f * y * (1.0f + erff(y * 0.70710678118654752f));
                best[u][v] = fmaxf(best[u][v], ge);
            }
        }
    }

#pragma unroll
    for (int v = 0; v < 4; ++v) {
        int o = o0 + tx * 4 + v;
        float4 pk = {best[0][v], best[1][v], best[2][v], best[3][v]};
        *(float4*)(out + ((size_t)(b * CO_ + o)) * NPT + n0 + ty * 4) = pk;
    }
}

// ---------------------------------------------------------------------------
// K6: generate edge plane1 (center indices) last.
// ---------------------------------------------------------------------------
__global__ __launch_bounds__(256) void k_center(float* __restrict__ e1)
{
    int p = blockIdx.x * 256 + threadIdx.x;
    if (p >= NROWS * KNN) return;
    e1[p] = (float)((p / KNN) % NPT);
}

// ---------------------------------------------------------------------------
extern "C" void kernel_launch(void* const* d_in, const int* in_sizes, int n_in,
                              void* d_out, int out_size, void* d_ws, size_t ws_size,
                              hipStream_t stream)
{
    const float* x   = (const float*)d_in[0];
    const float* cw  = (const float*)d_in[1];
    const float* cb  = (const float*)d_in[2];
    const float* gam = (const float*)d_in[3];
    const float* bet = (const float*)d_in[4];

    // d_out: FLOAT32. out0 = floats [0, 4,816,896); e0 = [4,816,896,
    // 4,929,792); e1 = [4,929,792, 5,042,688).
    // Scratch liveness:
    //   head:   invn64/sqd/invn32/cand       bytes [0, 1,856,512)  dead@refine
    //   packed: fp16 MFMA fragments          bytes [1,856,512, 6,673,408)
    //           dead@screen
    //   xT:     bytes [9,633,792, 19,267,584) dead@refine
    float* ou   = (float*)d_out;
    float* out0 = ou;
    double* invn64 = (double*)d_out;
    double* sqd    = (double*)((char*)d_out + 100352);
    float*  invn32 = (float*)((char*)d_out + 200704);
    unsigned short* cand =
        (unsigned short*)((char*)d_out + 250880);          // 1,605,632 B
    _Float16* packed = (_Float16*)(ou + 464128);           // 4,816,896 B
    float* xT = ou + 2408448;                              // 9.63 MB
    float* e0 = ou + 4816896;
    float* e1 = ou + 4929792;

    k_norm       <<<NROWS / 64, 256, 0, stream>>>(x, invn32, invn64, sqd);
    k_xpose      <<<B_ * 6 * 98, 256, 0, stream>>>(x, xT);
    k_pack       <<<1176, 256, 0, stream>>>(xT, invn32, packed);
    k_screen_mfma<<<B_ * 49 * 4, 256, 0, stream>>>(packed, cand);
    k_refine     <<<NROWS / 4, 256, 0, stream>>>(xT, invn64, sqd, cand, e0);

    const size_t BH_BYTES = (size_t)NROWS * 384 * 2;   //  9,633,792 bf16 B
    const size_t ZF_BYTES = (size_t)NROWS * 384 * 4;   // 19,267,584 fp32 zA
    const int    BSTRIDE  = NPT * CO_ * 4;             // fp32 batch-B stride

    if (ws_size >= BH_BYTES + ZF_BYTES) {
        // FAST PATH: split GEMM / gather. B bf16 + zA fp32 in d_ws.
        unsigned short* wsB = (unsigned short*)d_ws;
        float* wsZ = (float*)((char*)d_ws + BH_BYTES);
        k_gemmBoth<<<B_ * 49 * 6, 256, 0, stream>>>(x, cw, cb, wsB, wsZ);
        k_out2    <<<B_ * 49 * 6, 256, 0, stream>>>(e0, gam, bet, out0,
                                                    wsB, wsZ);
    } else if (ws_size >= ZF_BYTES) {
        // MEDIUM: R4 fast path — all-batch fp32 B in d_ws, fused epilogue.
        k_gemmB<<<B_ * 49 * 6, 256, 0, stream>>>(
            x, cw, d_ws, 0, 0, 384, 0, 6, BSTRIDE);
        k_outA <<<B_ * 49 * 6, 256, 0, stream>>>(
            x, cw, e0, cb, gam, bet, out0, (const void*)d_ws,
            0, 0, 0, 384, 0, 6, BSTRIDE);
    } else {
        // FALLBACK: d_out aliasing discipline (R3-proven numerics).
        k_gemmB<<<2 * 49 * 6, 256, 0, stream>>>(
            x, cw, (void*)ou, 2, 0, 384, 0, 6, BSTRIDE);
        k_outA <<<2 * 49 * 6, 256, 0, stream>>>(
            x, cw, e0, cb, gam, bet, out0, (const void*)ou,
            2, 0, 0, 384, 0, 6, BSTRIDE);
        k_gemmB<<<49 * 6, 256, 0, stream>>>(
            x, cw, (void*)ou, 1, 0, 384, 0, 6, 0);
        k_outA <<<49 * 6, 256, 0, stream>>>(
            x, cw, e0, cb, gam, bet, out0, (const void*)ou,
            1, 0, 0, 384, 0, 6, 0);
        k_gemmB<<<49 * 3, 256, 0, stream>>>(
            x, cw, (void*)ou, 0, 192, 192, 1, 3, 0);
        k_outA <<<49 * 3, 256, 0, stream>>>(
            x, cw, e0, cb, gam, bet, out0, (const void*)ou,
            0, 192, 192, 192, 1, 3, 0);
        k_gemmB<<<49 * 2, 256, 0, stream>>>(
            x, cw, (void*)ou, 0, 64, 128, 1, 2, 0);
        k_outA <<<49 * 2, 256, 0, stream>>>(
            x, cw, e0, cb, gam, bet, out0, (const void*)ou,
            0, 64, 64, 128, 1, 2, 0);
        k_gemmB<<<49 * 1, 256, 0, stream>>>(
            x, cw, (void*)e1, 0, 0, 64, 1, 1, 0);
        k_outA <<<49 * 1, 256, 0, stream>>>(
            x, cw, e0, cb, gam, bet, out0, (const void*)e1,
            0, 0, 0, 64, 1, 1, 0);
    }
    // Generate e1 (center plane) last.
    k_center<<<(NROWS * KNN + 255) / 256, 256, 0, stream>>>(e1);
}

// Round 8
// 246.693 us; speedup vs baseline: 3.7201x; 1.0089x over previous
//
#include <hip/hip_runtime.h>
#include <hip/hip_bf16.h>
#include <math.h>

#define B_    4
#define C_    192
#define NPT   3136          // H*W points per batch
#define CO_   384           // Cout
#define KNN   9
#define CAND  64            // 4 j-chunks * merged top-16 per row
#define NROWS (B_*NPT)      // 12544 total points
#define SD    10            // per-lane screening stream depth

typedef _Float16 half8 __attribute__((ext_vector_type(8)));
typedef float    f32x4 __attribute__((ext_vector_type(4)));

__device__ __forceinline__ float u2f(unsigned short u) {
    unsigned int t = ((unsigned int)u) << 16;
    float f; __builtin_memcpy(&f, &t, 4); return f;
}
__device__ __forceinline__ unsigned short f2u(float f) {
    __hip_bfloat16 h = __float2bfloat16(f);
    unsigned short u; __builtin_memcpy(&u, &h, 2); return u;
}
__device__ __forceinline__ float gelu_exact(float y) {
    return 0.5f * y * (1.0f + erff(y * 0.70710678118654752f));
}
// sortable u64 key for an f64 (ascending double order == ascending u64 order)
__device__ __forceinline__ unsigned long long dkey(double d) {
    long long sb = __double_as_longlong(d);
    unsigned long long u = (unsigned long long)sb;
    return (sb < 0) ? ~u : (u | 0x8000000000000000ULL);
}

// ---------------------------------------------------------------------------
// K1 v2: per-point f64 norm stats. 196 blocks; 4 waves split the channel
//   range (48 each), fixed-order LDS combine -> deterministic f64 sum.
// ---------------------------------------------------------------------------
__global__ __launch_bounds__(256) void k_norm(
    const float* __restrict__ x,
    float* __restrict__ invn32, double* __restrict__ invn64,
    double* __restrict__ sqd)
{
    __shared__ double part[4][64];
    int wave = threadIdx.x >> 6, lane = threadIdx.x & 63;
    int p0 = blockIdx.x * 64;          // 64 points per block, 196 blocks
    int row = p0 + lane;
    int b = row / NPT, n = row % NPT;
    const float* xb = x + (size_t)b * C_ * NPT + n;
    double S = 0.0;
    int c0 = wave * 48;
    for (int c = c0; c < c0 + 48; ++c) {
        double v = (double)xb[(size_t)c * NPT];
        S = fma(v, v, S);
    }
    part[wave][lane] = S;
    __syncthreads();
    if (threadIdx.x < 64) {
        double T = ((part[0][lane] + part[1][lane]) + part[2][lane])
                 + part[3][lane];
        double nrm = sqrt(T);
        if (nrm < 1e-12) nrm = 1e-12;
        double iv = 1.0 / nrm;
        int prow = p0 + lane;
        invn64[prow] = iv;
        invn32[prow] = (float)iv;
        sqd[prow] = iv * iv * T;
    }
}

// ---------------------------------------------------------------------------
// K1b v2: LDS-tiled transpose x [b][c][n] -> xT [b*NPT+n][c] (fp32, exact)
//   + FUSED fp16 fragment pack (was k_pack): the 32x32 tile is exactly one
//   (kk=ct) channel-group for two 16-point fragments. Threads 0..127 emit
//   packed[(b*196 + nt*2 + f)*6 + ct][l][e] = t[(l>>4)*8+e][f*16+(l&15)]*iv.
// ---------------------------------------------------------------------------
__global__ __launch_bounds__(256) void k_xpose(
    const float* __restrict__ x, float* __restrict__ xT,
    const float* __restrict__ invn32, _Float16* __restrict__ packed)
{
    __shared__ float t[32][33];
    int blk = blockIdx.x;
    int b  = blk / 588;
    int r  = blk % 588;
    int ct = r / 98, nt = r % 98;
    int c0 = ct * 32, n0 = nt * 32;
    int tid = threadIdx.x;
    int tx = tid & 31, ty8 = tid >> 5;          // 8 rows per pass
    const float* xb = x + (size_t)b * C_ * NPT;
#pragma unroll
    for (int e = 0; e < 4; ++e) {
        int cc = ty8 + e * 8;
        t[cc][tx] = xb[(size_t)(c0 + cc) * NPT + n0 + tx];
    }
    __syncthreads();
#pragma unroll
    for (int e = 0; e < 4; ++e) {
        int nn = ty8 + e * 8;
        xT[(size_t)(b * NPT + n0 + nn) * C_ + c0 + tx] = t[tx][nn];
    }
    if (tid < 128) {
        int f = tid >> 6, l = tid & 63;
        int pt = f * 16 + (l & 15);            // tile-local point
        float iv = invn32[(size_t)b * NPT + n0 + pt];
        int cb = (l >> 4) * 8;                 // tile-local channel base
        half8 h;
#pragma unroll
        for (int e = 0; e < 8; ++e)
            h[e] = (_Float16)(t[cb + e][pt] * iv);
        size_t idx = ((((size_t)(b * 196 + nt * 2 + f)) * 6 + ct) * 64 + l) * 8;
        *(half8*)(packed + idx) = h;
    }
}

// ---------------------------------------------------------------------------
// K2 (MFMA v2): fp16 matrix-core screening, branchless u32-key selection.
// ---------------------------------------------------------------------------
__global__ __launch_bounds__(256) void k_screen_mfma(
    const _Float16* __restrict__ packed, unsigned short* __restrict__ cand)
{
    __shared__ unsigned md[64][4 * SD + 1];   // stride 41
    int blk   = blockIdx.x;
    int chunk = blk & 3;
    int t2    = blk >> 2;
    int b     = t2 / 49;
    int itile = t2 % 49;                 // 64-row i tile
    int tid   = threadIdx.x;
    int wave  = tid >> 6, lane = tid & 63;
    int it    = itile * 4 + wave;        // global 16-row tile within batch

    const _Float16* pb = packed + ((size_t)(b * 196 + it) * 6) * 512 + lane * 8;
    half8 bf[6];
#pragma unroll
    for (int kk = 0; kk < 6; ++kk)
        bf[kk] = *(const half8*)(pb + kk * 512);

    int jt0 = chunk * 48;                 // chunks: 768,768,768,832 cols
    int ntj = (chunk == 3) ? 52 : 48;

    unsigned bd[SD];
#pragma unroll
    for (int q = 0; q < SD; ++q) bd[q] = 0u;

    const _Float16* pa_base =
        packed + ((size_t)(b * 196 + jt0) * 6) * 512 + lane * 8;

    half8 af[6];
#pragma unroll
    for (int kk = 0; kk < 6; ++kk)
        af[kk] = *(const half8*)(pa_base + kk * 512);

    for (int jt = 0; jt < ntj; ++jt) {
        f32x4 acc = {0.f, 0.f, 0.f, 0.f};
#pragma unroll
        for (int kk = 0; kk < 6; ++kk)
            acc = __builtin_amdgcn_mfma_f32_16x16x32_f16(af[kk], bf[kk], acc, 0, 0, 0);

        if (jt + 1 < ntj) {
            const _Float16* pn = pa_base + (size_t)(jt + 1) * 6 * 512;
#pragma unroll
            for (int kk = 0; kk < 6; ++kk)
                af[kk] = *(const half8*)(pn + kk * 512);
        }

        unsigned jb = (unsigned)((jt0 + jt) * 16 + (lane >> 4) * 4);
#pragma unroll
        for (int q = 0; q < 4; ++q) {
            float s = acc[q] + 2.0f;
            unsigned fb = __float_as_uint(s);
            unsigned c = (fb & 0xFFFFF000u) | (jb + (unsigned)q);
#pragma unroll
            for (int t = 0; t < SD; ++t) {
                unsigned old = bd[t];
                unsigned mx = old > c ? old : c;    // v_max_u32
                c           = old > c ? c : old;    // v_min_u32
                bd[t] = mx;
            }
        }
    }

    int ir = wave * 16 + (lane & 15);    // i-row within block (0..63)
    int g  = lane >> 4;                  // stream id
#pragma unroll
    for (int q = 0; q < SD; ++q) md[ir][g * SD + q] = bd[q];
    __syncthreads();

    if (tid < 64) {
        int h[4] = {0, 0, 0, 0};
        unsigned short* cp =
            cand + ((size_t)b * NPT + itile * 64 + tid) * CAND + chunk * 16;
        const unsigned* rd = &md[tid][0];
        for (int s = 0; s < 16; ++s) {
            unsigned best = 0u; int bg = 0;
#pragma unroll
            for (int g2 = 0; g2 < 4; ++g2) {
                unsigned v = (h[g2] < SD) ? rd[g2 * SD + h[g2]] : 0u;
                if (v > best) { best = v; bg = g2; }
            }
            cp[s] = (unsigned short)(best & 0xFFFu);
            h[bg]++;
        }
    }
}

// ---------------------------------------------------------------------------
// K3 v4: f64 refine — LDS xi row + LDS candidate stats + half-candidate
//   prefetch pipeline (6 live float4 instead of 12 -> low VGPR, high
//   occupancy). Accumulation order q0..q5 into d0..d3 chains, shuffle tree,
//   and dist formula identical to v3 -> bit-identical e0.
// ---------------------------------------------------------------------------
__global__ __launch_bounds__(256) void k_refine(
    const float* __restrict__ xT, const double* __restrict__ invn64,
    const double* __restrict__ sqd, const unsigned short* __restrict__ cand,
    float* __restrict__ e0)
{
    __shared__ unsigned long long kbuf[4][CAND];
    __shared__ int    icand[4][CAND];
    __shared__ double civ[4][CAND];
    __shared__ double csq[4][CAND];
    __shared__ float  xi[4][C_];
    int wave = threadIdx.x >> 6;
    int lane = threadIdx.x & 63;
    int row  = blockIdx.x * 4 + wave;
    int b    = row / NPT;
    size_t bN = (size_t)b * NPT;

    int jc = (int)cand[(size_t)row * CAND + lane];
    icand[wave][lane] = jc;
    civ[wave][lane] = invn64[bN + jc];
    csq[wave][lane] = sqd[bN + jc];
    const float* xiRow = xT + (size_t)row * C_;
    xi[wave][lane]       = xiRow[lane];
    xi[wave][lane + 64]  = xiRow[lane + 64];
    xi[wave][lane + 128] = xiRow[lane + 128];
    __syncthreads();

    int sub = lane & 7, cg = lane >> 3;
    double ivi = invn64[row], sqi = sqd[row];
    const float* xw = &xi[wave][sub * 4];

    // prologue: first half of candidate cg
    float4 h0a, h0b, h0c;
    {
        int j0 = icand[wave][cg];
        const float* p = xT + (bN + j0) * C_ + sub * 4;
        h0a = *(const float4*)&p[0];
        h0b = *(const float4*)&p[32];
        h0c = *(const float4*)&p[64];
    }

#pragma unroll
    for (int cc = 0; cc < 8; ++cc) {
        int cidx = cc * 8 + cg;
        int jcur = icand[wave][cidx];
        const float* pc = xT + (bN + jcur) * C_ + sub * 4;
        // issue second-half loads of current candidate
        float4 h1a = *(const float4*)&pc[96];
        float4 h1b = *(const float4*)&pc[128];
        float4 h1c = *(const float4*)&pc[160];

        double d0 = 0.0, d1 = 0.0, d2 = 0.0, d3 = 0.0;
        {
            float4 xq;
            xq = *(const float4*)&xw[0];
            d0 = fma((double)xq.x, (double)h0a.x, d0);
            d1 = fma((double)xq.y, (double)h0a.y, d1);
            d2 = fma((double)xq.z, (double)h0a.z, d2);
            d3 = fma((double)xq.w, (double)h0a.w, d3);
            xq = *(const float4*)&xw[32];
            d0 = fma((double)xq.x, (double)h0b.x, d0);
            d1 = fma((double)xq.y, (double)h0b.y, d1);
            d2 = fma((double)xq.z, (double)h0b.z, d2);
            d3 = fma((double)xq.w, (double)h0b.w, d3);
            xq = *(const float4*)&xw[64];
            d0 = fma((double)xq.x, (double)h0c.x, d0);
            d1 = fma((double)xq.y, (double)h0c.y, d1);
            d2 = fma((double)xq.z, (double)h0c.z, d2);
            d3 = fma((double)xq.w, (double)h0c.w, d3);
        }
        // prefetch first half of NEXT candidate into the freed h0 regs
        if (cc < 7) {
            int jn = icand[wave][cidx + 8];
            const float* pn = xT + (bN + jn) * C_ + sub * 4;
            h0a = *(const float4*)&pn[0];
            h0b = *(const float4*)&pn[32];
            h0c = *(const float4*)&pn[64];
        }
        {
            float4 xq;
            xq = *(const float4*)&xw[96];
            d0 = fma((double)xq.x, (double)h1a.x, d0);
            d1 = fma((double)xq.y, (double)h1a.y, d1);
            d2 = fma((double)xq.z, (double)h1a.z, d2);
            d3 = fma((double)xq.w, (double)h1a.w, d3);
            xq = *(const float4*)&xw[128];
            d0 = fma((double)xq.x, (double)h1b.x, d0);
            d1 = fma((double)xq.y, (double)h1b.y, d1);
            d2 = fma((double)xq.z, (double)h1b.z, d2);
            d3 = fma((double)xq.w, (double)h1b.w, d3);
            xq = *(const float4*)&xw[160];
            d0 = fma((double)xq.x, (double)h1c.x, d0);
            d1 = fma((double)xq.y, (double)h1c.y, d1);
            d2 = fma((double)xq.z, (double)h1c.z, d2);
            d3 = fma((double)xq.w, (double)h1c.w, d3);
        }
        double dot = (d0 + d1) + (d2 + d3);
        dot += __shfl_xor(dot, 1);
        dot += __shfl_xor(dot, 2);
        dot += __shfl_xor(dot, 4);
        if (sub == 0) {
            double dist = sqi + csq[wave][cidx]
                        - 2.0 * (ivi * civ[wave][cidx] * dot);
            kbuf[wave][cidx] = dkey(dist);
        }
    }
    __syncthreads();

    // rank-based top-9: all 64 candidates distinct (disjoint chunk ranges),
    // so (key, idx) ranks form a permutation; ranks 0..8 written.
    unsigned long long kd = kbuf[wave][lane];
    int jme = icand[wave][lane];
    int rank = 0;
#pragma unroll
    for (int m = 0; m < CAND; ++m) {
        unsigned long long km = kbuf[wave][m];
        int jm = icand[wave][m];
        rank += ((km < kd) || (km == kd && jm < jme)) ? 1 : 0;
    }
    if (rank < KNN)
        e0[(size_t)row * KNN + rank] = (float)jme;
}

// ---------------------------------------------------------------------------
// K4b: fused dual GEMM (fast path).  For all 4 batches:
//   B  = x . W2          -> bf16, ldB=384   (gather operand, halves BW)
//   zA = x . (W1-W2)+cb  -> fp32, 384      (center term, exact)
// ---------------------------------------------------------------------------
__global__ __launch_bounds__(256) void k_gemmBoth(
    const float* __restrict__ x, const float* __restrict__ cw,
    const float* __restrict__ cb,
    unsigned short* __restrict__ Bh, float* __restrict__ Zf)
{
    __shared__ float Xt[16][68];
    __shared__ float Wd[16][68];
    __shared__ float W2[16][68];
    int blk = blockIdx.x;
    int b   = blk / 294;
    int r   = blk % 294;
    int bm  = r % 49;
    int bo  = r / 49;
    int m0  = bm * 64;
    int tid = threadIdx.x;
    int tx = tid & 15, ty = tid >> 4;
    const float* xb = x + (size_t)b * C_ * NPT;

    float acc1[4][4], acc2[4][4];
#pragma unroll
    for (int u = 0; u < 4; ++u)
#pragma unroll
        for (int v = 0; v < 4; ++v) { acc1[u][v] = 0.f; acc2[u][v] = 0.f; }

    for (int ct = 0; ct < 12; ++ct) {
        int c0 = ct * 16;
        {
            int cc = tid >> 4, n4 = (tid & 15) * 4;
            *(float4*)&Xt[cc][n4] =
                *(const float4*)&xb[(size_t)(c0 + cc) * NPT + m0 + n4];
        }
        {
            int oo = tid >> 2, c4 = (tid & 3) * 4;
            int o = bo * 64 + oo;
            float4 w1 = *(const float4*)&cw[(size_t)o * 384 + c0 + c4];
            float4 w2 = *(const float4*)&cw[(size_t)o * 384 + C_ + c0 + c4];
            Wd[c4 + 0][oo] = w1.x - w2.x; Wd[c4 + 1][oo] = w1.y - w2.y;
            Wd[c4 + 2][oo] = w1.z - w2.z; Wd[c4 + 3][oo] = w1.w - w2.w;
            W2[c4 + 0][oo] = w2.x; W2[c4 + 1][oo] = w2.y;
            W2[c4 + 2][oo] = w2.z; W2[c4 + 3][oo] = w2.w;
        }
        __syncthreads();
#pragma unroll
        for (int cc = 0; cc < 16; ++cc) {
            float4 av = *(const float4*)&Xt[cc][ty * 4];
            float4 dv = *(const float4*)&Wd[cc][tx * 4];
            float4 wv = *(const float4*)&W2[cc][tx * 4];
            float a_[4] = {av.x, av.y, av.z, av.w};
            float d_[4] = {dv.x, dv.y, dv.z, dv.w};
            float w_[4] = {wv.x, wv.y, wv.z, wv.w};
#pragma unroll
            for (int u = 0; u < 4; ++u)
#pragma unroll
                for (int v = 0; v < 4; ++v) {
                    acc1[u][v] = fmaf(a_[u], d_[v], acc1[u][v]);
                    acc2[u][v] = fmaf(a_[u], w_[v], acc2[u][v]);
                }
        }
        __syncthreads();
    }

    float cbs[4];
#pragma unroll
    for (int v = 0; v < 4; ++v) cbs[v] = cb[bo * 64 + tx * 4 + v];

#pragma unroll
    for (int u = 0; u < 4; ++u) {
        size_t rowb = (size_t)(b * NPT + m0 + ty * 4 + u) * 384 + bo * 64 + tx * 4;
        ushort4 pk;
        pk.x = f2u(acc2[u][0]); pk.y = f2u(acc2[u][1]);
        pk.z = f2u(acc2[u][2]); pk.w = f2u(acc2[u][3]);
        *(ushort4*)&Bh[rowb] = pk;
        float4 za = {acc1[u][0] + cbs[0], acc1[u][1] + cbs[1],
                     acc1[u][2] + cbs[2], acc1[u][3] + cbs[3]};
        *(float4*)&Zf[rowb] = za;
    }
}

// ---------------------------------------------------------------------------
// K5b v2: gather epilogue with quasiconvex-GELU reduction.
// ---------------------------------------------------------------------------
__global__ __launch_bounds__(256) void k_out2(
    const float* __restrict__ e0, const float* __restrict__ gam,
    const float* __restrict__ bet, float* __restrict__ out,
    const unsigned short* __restrict__ Bh, const float* __restrict__ Zf)
{
    __shared__ int jidx[64 * KNN];
    int blk = blockIdx.x;
    int b   = blk / 294;
    int r   = blk % 294;
    int nt  = r % 49, ot = r / 49;
    int n0 = nt * 64, o0 = ot * 64;
    int tid = threadIdx.x;
    int tx = tid & 15, ty = tid >> 4;

    for (int e = tid; e < 64 * KNN; e += 256)
        jidx[e] = (int)e0[((size_t)b * NPT + n0 + e / KNN) * KNN + e % KNN];

    const float inv_s = 0.9999950000374997f;  // 1/sqrt(1+1e-5)
    float gs[4], bts[4];
#pragma unroll
    for (int v = 0; v < 4; ++v) {
        int o = o0 + tx * 4 + v;
        gs[v]  = gam[o] * inv_s;
        bts[v] = bet[o];
    }
    __syncthreads();

    float best[4][4];
#pragma unroll
    for (int u = 0; u < 4; ++u) {
        float4 z = *(const float4*)
            &Zf[(size_t)(b * NPT + n0 + ty * 4 + u) * 384 + o0 + tx * 4];
        float zA[4] = {z.x, z.y, z.z, z.w};

        float ymin[4], ymax[4];
#pragma unroll
        for (int v = 0; v < 4; ++v) { ymin[v] = 1e30f; ymax[v] = -1e30f; }

        const int* jr = &jidx[(ty * 4 + u) * KNN];
#pragma unroll
        for (int k = 0; k < KNN; ++k) {
            int j = jr[k];
            ushort4 g = *(const ushort4*)
                &Bh[(size_t)(b * NPT + j) * 384 + o0 + tx * 4];
            float bvv[4] = {u2f(g.x), u2f(g.y), u2f(g.z), u2f(g.w)};
#pragma unroll
            for (int v = 0; v < 4; ++v) {
                float y = fmaf(zA[v] + bvv[v], gs[v], bts[v]);
                ymin[v] = fminf(ymin[v], y);
                ymax[v] = fmaxf(ymax[v], y);
            }
        }
#pragma unroll
        for (int v = 0; v < 4; ++v)
            best[u][v] = fmaxf(gelu_exact(ymin[v]), gelu_exact(ymax[v]));
    }

#pragma unroll
    for (int v = 0; v < 4; ++v) {
        int o = o0 + tx * 4 + v;
        float4 pk = {best[0][v], best[1][v], best[2][v], best[3][v]};
        *(float4*)(out + ((size_t)(b * CO_ + o)) * NPT + n0 + ty * 4) = pk;
    }
}

// ---------------------------------------------------------------------------
// K4: B = W2 * x (fallback path, multi-batch).
// ---------------------------------------------------------------------------
__global__ __launch_bounds__(256) void k_gemmB(
    const float* __restrict__ x, const float* __restrict__ cw,
    void* __restrict__ Bq, int bbase, int bcol0, int ldB, int storeBf16,
    int botiles, int bstrideBytes)
{
    int per = 49 * botiles;
    int blk = blockIdx.x;
    int bi  = blk / per;
    int r   = blk % per;
    int b   = bbase + bi;
    int bm = r % 49;
    int bo = r / 49;
    int m0 = bm * 64;
    char* Bp = (char*)Bq + (size_t)bi * (size_t)bstrideBytes;

    __shared__ float Xt[16][68];
    __shared__ float Wt[16][68];
    int tid = threadIdx.x;
    int tx = tid & 15, ty = tid >> 4;
    const float* xb = x + (size_t)b * C_ * NPT;
    float acc[4][4];
#pragma unroll
    for (int u = 0; u < 4; ++u)
#pragma unroll
        for (int v = 0; v < 4; ++v) acc[u][v] = 0.f;

    for (int ct = 0; ct < 12; ++ct) {
        int c0 = ct * 16;
        {
            int cc = tid >> 4, n4 = (tid & 15) * 4;
            *(float4*)&Xt[cc][n4] =
                *(const float4*)&xb[(size_t)(c0 + cc) * NPT + m0 + n4];
        }
        {
            int oo = tid >> 2, c4 = (tid & 3) * 4;
            int o = bcol0 + bo * 64 + oo;
            float4 w = *(const float4*)&cw[(size_t)o * 384 + C_ + c0 + c4];
            Wt[c4 + 0][oo] = w.x; Wt[c4 + 1][oo] = w.y;
            Wt[c4 + 2][oo] = w.z; Wt[c4 + 3][oo] = w.w;
        }
        __syncthreads();
#pragma unroll
        for (int cc = 0; cc < 16; ++cc) {
            float4 av = *(const float4*)&Xt[cc][ty * 4];
            float4 bv = *(const float4*)&Wt[cc][tx * 4];
            float a_[4] = {av.x, av.y, av.z, av.w};
            float b_[4] = {bv.x, bv.y, bv.z, bv.w};
#pragma unroll
            for (int u = 0; u < 4; ++u)
#pragma unroll
                for (int v = 0; v < 4; ++v)
                    acc[u][v] = fmaf(a_[u], b_[v], acc[u][v]);
        }
        __syncthreads();
    }
    if (!storeBf16) {
        float* Bf = (float*)Bp;
#pragma unroll
        for (int u = 0; u < 4; ++u) {
            float4 pk = {acc[u][0], acc[u][1], acc[u][2], acc[u][3]};
            *(float4*)&Bf[(size_t)(m0 + ty * 4 + u) * ldB + bo * 64 + tx * 4] = pk;
        }
    } else {
        unsigned short* Bh = (unsigned short*)Bp;
#pragma unroll
        for (int u = 0; u < 4; ++u) {
            ushort4 pk;
            pk.x = f2u(acc[u][0]); pk.y = f2u(acc[u][1]);
            pk.z = f2u(acc[u][2]); pk.w = f2u(acc[u][3]);
            *(ushort4*)&Bh[(size_t)(m0 + ty * 4 + u) * ldB + bo * 64 + tx * 4] = pk;
        }
    }
}

// ---------------------------------------------------------------------------
// K5: fused epilogue (fallback path, multi-batch). Unchanged (proven).
// ---------------------------------------------------------------------------
__global__ __launch_bounds__(256) void k_outA(
    const float* __restrict__ x, const float* __restrict__ cw,
    const float* __restrict__ e0, const float* __restrict__ cb,
    const float* __restrict__ gam, const float* __restrict__ bet,
    float* __restrict__ out, const void* __restrict__ Bq,
    int bbase, int o0base, int bcol0, int ldB, int readBf16,
    int botiles, int bstrideBytes)
{
    int per = 49 * botiles;
    int blk = blockIdx.x;
    int bi  = blk / per;
    int r   = blk % per;
    int b   = bbase + bi;
    int nt = r % 49, ot = r / 49;
    int n0 = nt * 64, o0 = o0base + ot * 64;
    const char* Bp = (const char*)Bq + (size_t)bi * (size_t)bstrideBytes;

    __shared__ float Xi[16][68];
    __shared__ float Wd[16][68];
    __shared__ int jidx[64 * KNN];
    int tid = threadIdx.x;
    int tx = tid & 15, ty = tid >> 4;
    const float* xb = x + (size_t)b * C_ * NPT;

    for (int e = tid; e < 64 * KNN; e += 256)
        jidx[e] = (int)e0[((size_t)b * NPT + n0 + e / KNN) * KNN + e % KNN];

    float zA[4][4];
#pragma unroll
    for (int u = 0; u < 4; ++u)
#pragma unroll
        for (int v = 0; v < 4; ++v) zA[u][v] = 0.f;

    for (int ct = 0; ct < 12; ++ct) {
        int c0 = ct * 16;
        {
            int cc = tid >> 4, n4 = (tid & 15) * 4;
            *(float4*)&Xi[cc][n4] =
                *(const float4*)&xb[(size_t)(c0 + cc) * NPT + n0 + n4];
        }
        {
            int oo = tid >> 2, c4 = (tid & 3) * 4;
            int o = o0 + oo;
            float4 w1 = *(const float4*)&cw[(size_t)o * 384 + c0 + c4];
            float4 w2 = *(const float4*)&cw[(size_t)o * 384 + C_ + c0 + c4];
            Wd[c4 + 0][oo] = w1.x - w2.x; Wd[c4 + 1][oo] = w1.y - w2.y;
            Wd[c4 + 2][oo] = w1.z - w2.z; Wd[c4 + 3][oo] = w1.w - w2.w;
        }
        __syncthreads();
#pragma unroll
        for (int cc = 0; cc < 16; ++cc) {
            float4 av = *(const float4*)&Xi[cc][ty * 4];
            float4 bv = *(const float4*)&Wd[cc][tx * 4];
            float a_[4] = {av.x, av.y, av.z, av.w};
            float b_[4] = {bv.x, bv.y, bv.z, bv.w};
#pragma unroll
            for (int u = 0; u < 4; ++u)
#pragma unroll
                for (int v = 0; v < 4; ++v)
                    zA[u][v] = fmaf(a_[u], b_[v], zA[u][v]);
        }
        __syncthreads();
    }

    const float inv_s = 0.9999950000374997f;  // 1/sqrt(1+1e-5)
    float gs[4], bts[4], cbs[4];
#pragma unroll
    for (int v = 0; v < 4; ++v) {
        int o = o0 + tx * 4 + v;
        gs[v]  = gam[o] * inv_s;
        bts[v] = bet[o];
        cbs[v] = cb[o];
    }

    float best[4][4];
#pragma unroll
    for (int u = 0; u < 4; ++u)
#pragma unroll
        for (int v = 0; v < 4; ++v) best[u][v] = -1e30f;

    int obB = o0 - bcol0;
    for (int k = 0; k < KNN; ++k) {
#pragma unroll
        for (int u = 0; u < 4; ++u) {
            int j = jidx[(ty * 4 + u) * KNN + k];
            float bvv[4];
            if (!readBf16) {
                float4 g = *(const float4*)
                    ((const float*)Bp + (size_t)j * ldB + obB + tx * 4);
                bvv[0] = g.x; bvv[1] = g.y; bvv[2] = g.z; bvv[3] = g.w;
            } else {
                ushort4 g = *(const ushort4*)
                    ((const unsigned short*)Bp + (size_t)j * ldB + obB + tx * 4);
                bvv[0] = u2f(g.x); bvv[1] = u2f(g.y);
                bvv[2] = u2f(g.z); bvv[3] = u2f(g.w);
            }
#pragma unroll
            for (int v = 0; v < 4; ++v) {
                float z = zA[u][v] + bvv[v] + cbs[v];
                float y = fmaf(z, gs[v], bts[v]);
                float ge = 0.5f * y * (1.0f + erff(y * 0.70710678118654752f));
                best[u][v] = fmaxf(best[u][v], ge);
            }
        }
    }

#pragma unroll
    for (int v = 0; v < 4; ++v) {
        int o = o0 + tx * 4 + v;
        float4 pk = {best[0][v], best[1][v], best[2][v], best[3][v]};
        *(float4*)(out + ((size_t)(b * CO_ + o)) * NPT + n0 + ty * 4) = pk;
    }
}

// ---------------------------------------------------------------------------
// K6: generate edge plane1 (center indices) last.
// ---------------------------------------------------------------------------
__global__ __launch_bounds__(256) void k_center(float* __restrict__ e1)
{
    int p = blockIdx.x * 256 + threadIdx.x;
    if (p >= NROWS * KNN) return;
    e1[p] = (float)((p / KNN) % NPT);
}

// ---------------------------------------------------------------------------
extern "C" void kernel_launch(void* const* d_in, const int* in_sizes, int n_in,
                              void* d_out, int out_size, void* d_ws, size_t ws_size,
                              hipStream_t stream)
{
    const float* x   = (const float*)d_in[0];
    const float* cw  = (const float*)d_in[1];
    const float* cb  = (const float*)d_in[2];
    const float* gam = (const float*)d_in[3];
    const float* bet = (const float*)d_in[4];

    // d_out: FLOAT32. out0 = floats [0, 4,816,896); e0 = [4,816,896,
    // 4,929,792); e1 = [4,929,792, 5,042,688).
    // Scratch liveness:
    //   head:   invn64/sqd/invn32/cand       bytes [0, 1,856,512)  dead@refine
    //   packed: fp16 MFMA fragments          bytes [1,856,512, 6,673,408)
    //           dead@screen
    //   xT:     bytes [9,633,792, 19,267,584) dead@refine
    float* ou   = (float*)d_out;
    float* out0 = ou;
    double* invn64 = (double*)d_out;
    double* sqd    = (double*)((char*)d_out + 100352);
    float*  invn32 = (float*)((char*)d_out + 200704);
    unsigned short* cand =
        (unsigned short*)((char*)d_out + 250880);          // 1,605,632 B
    _Float16* packed = (_Float16*)(ou + 464128);           // 4,816,896 B
    float* xT = ou + 2408448;                              // 9.63 MB
    float* e0 = ou + 4816896;
    float* e1 = ou + 4929792;

    k_norm       <<<NROWS / 64, 256, 0, stream>>>(x, invn32, invn64, sqd);
    k_xpose      <<<B_ * 6 * 98, 256, 0, stream>>>(x, xT, invn32, packed);
    k_screen_mfma<<<B_ * 49 * 4, 256, 0, stream>>>(packed, cand);
    k_refine     <<<NROWS / 4, 256, 0, stream>>>(xT, invn64, sqd, cand, e0);

    const size_t BH_BYTES = (size_t)NROWS * 384 * 2;   //  9,633,792 bf16 B
    const size_t ZF_BYTES = (size_t)NROWS * 384 * 4;   // 19,267,584 fp32 zA
    const int    BSTRIDE  = NPT * CO_ * 4;             // fp32 batch-B stride

    if (ws_size >= BH_BYTES + ZF_BYTES) {
        // FAST PATH: split GEMM / gather. B bf16 + zA fp32 in d_ws.
        unsigned short* wsB = (unsigned short*)d_ws;
        float* wsZ = (float*)((char*)d_ws + BH_BYTES);
        k_gemmBoth<<<B_ * 49 * 6, 256, 0, stream>>>(x, cw, cb, wsB, wsZ);
        k_out2    <<<B_ * 49 * 6, 256, 0, stream>>>(e0, gam, bet, out0,
                                                    wsB, wsZ);
    } else if (ws_size >= ZF_BYTES) {
        // MEDIUM: all-batch fp32 B in d_ws, fused epilogue.
        k_gemmB<<<B_ * 49 * 6, 256, 0, stream>>>(
            x, cw, d_ws, 0, 0, 384, 0, 6, BSTRIDE);
        k_outA <<<B_ * 49 * 6, 256, 0, stream>>>(
            x, cw, e0, cb, gam, bet, out0, (const void*)d_ws,
            0, 0, 0, 384, 0, 6, BSTRIDE);
    } else {
        // FALLBACK: d_out aliasing discipline (R3-proven numerics).
        k_gemmB<<<2 * 49 * 6, 256, 0, stream>>>(
            x, cw, (void*)ou, 2, 0, 384, 0, 6, BSTRIDE);
        k_outA <<<2 * 49 * 6, 256, 0, stream>>>(
            x, cw, e0, cb, gam, bet, out0, (const void*)ou,
            2, 0, 0, 384, 0, 6, BSTRIDE);
        k_gemmB<<<49 * 6, 256, 0, stream>>>(
            x, cw, (void*)ou, 1, 0, 384, 0, 6, 0);
        k_outA <<<49 * 6, 256, 0, stream>>>(
            x, cw, e0, cb, gam, bet, out0, (const void*)ou,
            1, 0, 0, 384, 0, 6, 0);
        k_gemmB<<<49 * 3, 256, 0, stream>>>(
            x, cw, (void*)ou, 0, 192, 192, 1, 3, 0);
        k_outA <<<49 * 3, 256, 0, stream>>>(
            x, cw, e0, cb, gam, bet, out0, (const void*)ou,
            0, 192, 192, 192, 1, 3, 0);
        k_gemmB<<<49 * 2, 256, 0, stream>>>(
            x, cw, (void*)ou, 0, 64, 128, 1, 2, 0);
        k_outA <<<49 * 2, 256, 0, stream>>>(
            x, cw, e0, cb, gam, bet, out0, (const void*)ou,
            0, 64, 64, 128, 1, 2, 0);
        k_gemmB<<<49 * 1, 256, 0, stream>>>(
            x, cw, (void*)e1, 0, 0, 64, 1, 1, 0);
        k_outA <<<49 * 1, 256, 0, stream>>>(
            x, cw, e0, cb, gam, bet, out0, (const void*)e1,
            0, 0, 0, 64, 1, 1, 0);
    }
    // Generate e1 (center plane) last.
    k_center<<<(NROWS * KNN + 255) / 256, 256, 0, stream>>>(e1);
}

// Round 9
// 217.087 us; speedup vs baseline: 4.2275x; 1.1364x over previous
//
#include <hip/hip_runtime.h>
#include <hip/hip_bf16.h>
#include <math.h>

#define B_    4
#define C_    192
#define NPT   3136          // H*W points per batch
#define CO_   384           // Cout
#define KNN   9
#define CAND  64            // 4 j-chunks * merged top-16 per row
#define NROWS (B_*NPT)      // 12544 total points
#define SD    10            // per-lane screening stream depth

typedef _Float16 half8 __attribute__((ext_vector_type(8)));
typedef float    f32x4 __attribute__((ext_vector_type(4)));

__device__ __forceinline__ float u2f(unsigned short u) {
    unsigned int t = ((unsigned int)u) << 16;
    float f; __builtin_memcpy(&f, &t, 4); return f;
}
__device__ __forceinline__ unsigned short f2u(float f) {
    __hip_bfloat16 h = __float2bfloat16(f);
    unsigned short u; __builtin_memcpy(&u, &h, 2); return u;
}
__device__ __forceinline__ float gelu_exact(float y) {
    return 0.5f * y * (1.0f + erff(y * 0.70710678118654752f));
}
// sortable u64 key for an f64 (ascending double order == ascending u64 order)
__device__ __forceinline__ unsigned long long dkey(double d) {
    long long sb = __double_as_longlong(d);
    unsigned long long u = (unsigned long long)sb;
    return (sb < 0) ? ~u : (u | 0x8000000000000000ULL);
}

// ---------------------------------------------------------------------------
// K1 v3: per-point f64 norm stats (+ fp32 norm for MFMA rescale).
// ---------------------------------------------------------------------------
__global__ __launch_bounds__(256) void k_norm(
    const float* __restrict__ x,
    float* __restrict__ invn32, double* __restrict__ invn64,
    double* __restrict__ sqd, float* __restrict__ nrm32)
{
    __shared__ double part[4][64];
    int wave = threadIdx.x >> 6, lane = threadIdx.x & 63;
    int p0 = blockIdx.x * 64;          // 64 points per block, 196 blocks
    int row = p0 + lane;
    int b = row / NPT, n = row % NPT;
    const float* xb = x + (size_t)b * C_ * NPT + n;
    double S = 0.0;
    int c0 = wave * 48;
    for (int c = c0; c < c0 + 48; ++c) {
        double v = (double)xb[(size_t)c * NPT];
        S = fma(v, v, S);
    }
    part[wave][lane] = S;
    __syncthreads();
    if (threadIdx.x < 64) {
        double T = ((part[0][lane] + part[1][lane]) + part[2][lane])
                 + part[3][lane];
        double nrm = sqrt(T);
        if (nrm < 1e-12) nrm = 1e-12;
        double iv = 1.0 / nrm;
        int prow = p0 + lane;
        invn64[prow] = iv;
        invn32[prow] = (float)iv;
        sqd[prow] = iv * iv * T;
        nrm32[prow] = (float)nrm;
    }
}

// ---------------------------------------------------------------------------
// K1b v2: LDS-tiled transpose x -> xT (fp32, exact) + fused fp16 pack.
// ---------------------------------------------------------------------------
__global__ __launch_bounds__(256) void k_xpose(
    const float* __restrict__ x, float* __restrict__ xT,
    const float* __restrict__ invn32, _Float16* __restrict__ packed)
{
    __shared__ float t[32][33];
    int blk = blockIdx.x;
    int b  = blk / 588;
    int r  = blk % 588;
    int ct = r / 98, nt = r % 98;
    int c0 = ct * 32, n0 = nt * 32;
    int tid = threadIdx.x;
    int tx = tid & 31, ty8 = tid >> 5;          // 8 rows per pass
    const float* xb = x + (size_t)b * C_ * NPT;
#pragma unroll
    for (int e = 0; e < 4; ++e) {
        int cc = ty8 + e * 8;
        t[cc][tx] = xb[(size_t)(c0 + cc) * NPT + n0 + tx];
    }
    __syncthreads();
#pragma unroll
    for (int e = 0; e < 4; ++e) {
        int nn = ty8 + e * 8;
        xT[(size_t)(b * NPT + n0 + nn) * C_ + c0 + tx] = t[tx][nn];
    }
    if (tid < 128) {
        int f = tid >> 6, l = tid & 63;
        int pt = f * 16 + (l & 15);            // tile-local point
        float iv = invn32[(size_t)b * NPT + n0 + pt];
        int cb = (l >> 4) * 8;                 // tile-local channel base
        half8 h;
#pragma unroll
        for (int e = 0; e < 8; ++e)
            h[e] = (_Float16)(t[cb + e][pt] * iv);
        size_t idx = ((((size_t)(b * 196 + nt * 2 + f)) * 6 + ct) * 64 + l) * 8;
        *(half8*)(packed + idx) = h;
    }
}

// ---------------------------------------------------------------------------
// K1d: pack weights into MFMA A-fragments (fp16), once.
//   wpk[(ot*6+kk)][l][e]:
//     ot in [0,24):  (W1-W2)[o][k]   o = ot*16+(l&15), k = kk*32+(l>>4)*8+e
//     ot in [24,48): W2[o][k]        o = (ot-24)*16+(l&15)
// ---------------------------------------------------------------------------
__global__ __launch_bounds__(256) void k_wpack(
    const float* __restrict__ cw, _Float16* __restrict__ wpk)
{
    int t = blockIdx.x * 256 + threadIdx.x;   // 48*6*64 = 18432
    if (t >= 48 * 6 * 64) return;
    int l  = t & 63;
    int tk = t >> 6;            // ot*6+kk
    int kk = tk % 6, ot = tk / 6;
    int hsel = ot / 24;
    int o = (ot % 24) * 16 + (l & 15);
    int k = kk * 32 + (l >> 4) * 8;
    half8 h;
#pragma unroll
    for (int e = 0; e < 8; ++e) {
        float w2 = cw[(size_t)o * 384 + C_ + k + e];
        float wv = hsel ? w2 : (cw[(size_t)o * 384 + k + e] - w2);
        h[e] = (_Float16)wv;
    }
    *(half8*)(wpk + (size_t)t * 8) = h;
}

// ---------------------------------------------------------------------------
// K2 (MFMA v2): fp16 matrix-core screening, branchless u32-key selection.
// ---------------------------------------------------------------------------
__global__ __launch_bounds__(256) void k_screen_mfma(
    const _Float16* __restrict__ packed, unsigned short* __restrict__ cand)
{
    __shared__ unsigned md[64][4 * SD + 1];   // stride 41
    int blk   = blockIdx.x;
    int chunk = blk & 3;
    int t2    = blk >> 2;
    int b     = t2 / 49;
    int itile = t2 % 49;                 // 64-row i tile
    int tid   = threadIdx.x;
    int wave  = tid >> 6, lane = tid & 63;
    int it    = itile * 4 + wave;        // global 16-row tile within batch

    const _Float16* pb = packed + ((size_t)(b * 196 + it) * 6) * 512 + lane * 8;
    half8 bf[6];
#pragma unroll
    for (int kk = 0; kk < 6; ++kk)
        bf[kk] = *(const half8*)(pb + kk * 512);

    int jt0 = chunk * 48;                 // chunks: 768,768,768,832 cols
    int ntj = (chunk == 3) ? 52 : 48;

    unsigned bd[SD];
#pragma unroll
    for (int q = 0; q < SD; ++q) bd[q] = 0u;

    const _Float16* pa_base =
        packed + ((size_t)(b * 196 + jt0) * 6) * 512 + lane * 8;

    half8 af[6];
#pragma unroll
    for (int kk = 0; kk < 6; ++kk)
        af[kk] = *(const half8*)(pa_base + kk * 512);

    for (int jt = 0; jt < ntj; ++jt) {
        f32x4 acc = {0.f, 0.f, 0.f, 0.f};
#pragma unroll
        for (int kk = 0; kk < 6; ++kk)
            acc = __builtin_amdgcn_mfma_f32_16x16x32_f16(af[kk], bf[kk], acc, 0, 0, 0);

        if (jt + 1 < ntj) {
            const _Float16* pn = pa_base + (size_t)(jt + 1) * 6 * 512;
#pragma unroll
            for (int kk = 0; kk < 6; ++kk)
                af[kk] = *(const half8*)(pn + kk * 512);
        }

        unsigned jb = (unsigned)((jt0 + jt) * 16 + (lane >> 4) * 4);
#pragma unroll
        for (int q = 0; q < 4; ++q) {
            float s = acc[q] + 2.0f;
            unsigned fb = __float_as_uint(s);
            unsigned c = (fb & 0xFFFFF000u) | (jb + (unsigned)q);
#pragma unroll
            for (int t = 0; t < SD; ++t) {
                unsigned old = bd[t];
                unsigned mx = old > c ? old : c;    // v_max_u32
                c           = old > c ? c : old;    // v_min_u32
                bd[t] = mx;
            }
        }
    }

    int ir = wave * 16 + (lane & 15);    // i-row within block (0..63)
    int g  = lane >> 4;                  // stream id
#pragma unroll
    for (int q = 0; q < SD; ++q) md[ir][g * SD + q] = bd[q];
    __syncthreads();

    if (tid < 64) {
        int h[4] = {0, 0, 0, 0};
        unsigned short* cp =
            cand + ((size_t)b * NPT + itile * 64 + tid) * CAND + chunk * 16;
        const unsigned* rd = &md[tid][0];
        for (int s = 0; s < 16; ++s) {
            unsigned best = 0u; int bg = 0;
#pragma unroll
            for (int g2 = 0; g2 < 4; ++g2) {
                unsigned v = (h[g2] < SD) ? rd[g2 * SD + h[g2]] : 0u;
                if (v > best) { best = v; bg = g2; }
            }
            cp[s] = (unsigned short)(best & 0xFFFu);
            h[bg]++;
        }
    }
}

// ---------------------------------------------------------------------------
// K3 v4: f64 refine — LDS xi + LDS cand stats + half-candidate pipeline.
// ---------------------------------------------------------------------------
__global__ __launch_bounds__(256) void k_refine(
    const float* __restrict__ xT, const double* __restrict__ invn64,
    const double* __restrict__ sqd, const unsigned short* __restrict__ cand,
    float* __restrict__ e0)
{
    __shared__ unsigned long long kbuf[4][CAND];
    __shared__ int    icand[4][CAND];
    __shared__ double civ[4][CAND];
    __shared__ double csq[4][CAND];
    __shared__ float  xi[4][C_];
    int wave = threadIdx.x >> 6;
    int lane = threadIdx.x & 63;
    int row  = blockIdx.x * 4 + wave;
    int b    = row / NPT;
    size_t bN = (size_t)b * NPT;

    int jc = (int)cand[(size_t)row * CAND + lane];
    icand[wave][lane] = jc;
    civ[wave][lane] = invn64[bN + jc];
    csq[wave][lane] = sqd[bN + jc];
    const float* xiRow = xT + (size_t)row * C_;
    xi[wave][lane]       = xiRow[lane];
    xi[wave][lane + 64]  = xiRow[lane + 64];
    xi[wave][lane + 128] = xiRow[lane + 128];
    __syncthreads();

    int sub = lane & 7, cg = lane >> 3;
    double ivi = invn64[row], sqi = sqd[row];
    const float* xw = &xi[wave][sub * 4];

    // prologue: first half of candidate cg
    float4 h0a, h0b, h0c;
    {
        int j0 = icand[wave][cg];
        const float* p = xT + (bN + j0) * C_ + sub * 4;
        h0a = *(const float4*)&p[0];
        h0b = *(const float4*)&p[32];
        h0c = *(const float4*)&p[64];
    }

#pragma unroll
    for (int cc = 0; cc < 8; ++cc) {
        int cidx = cc * 8 + cg;
        int jcur = icand[wave][cidx];
        const float* pc = xT + (bN + jcur) * C_ + sub * 4;
        // issue second-half loads of current candidate
        float4 h1a = *(const float4*)&pc[96];
        float4 h1b = *(const float4*)&pc[128];
        float4 h1c = *(const float4*)&pc[160];

        double d0 = 0.0, d1 = 0.0, d2 = 0.0, d3 = 0.0;
        {
            float4 xq;
            xq = *(const float4*)&xw[0];
            d0 = fma((double)xq.x, (double)h0a.x, d0);
            d1 = fma((double)xq.y, (double)h0a.y, d1);
            d2 = fma((double)xq.z, (double)h0a.z, d2);
            d3 = fma((double)xq.w, (double)h0a.w, d3);
            xq = *(const float4*)&xw[32];
            d0 = fma((double)xq.x, (double)h0b.x, d0);
            d1 = fma((double)xq.y, (double)h0b.y, d1);
            d2 = fma((double)xq.z, (double)h0b.z, d2);
            d3 = fma((double)xq.w, (double)h0b.w, d3);
            xq = *(const float4*)&xw[64];
            d0 = fma((double)xq.x, (double)h0c.x, d0);
            d1 = fma((double)xq.y, (double)h0c.y, d1);
            d2 = fma((double)xq.z, (double)h0c.z, d2);
            d3 = fma((double)xq.w, (double)h0c.w, d3);
        }
        // prefetch first half of NEXT candidate into the freed h0 regs
        if (cc < 7) {
            int jn = icand[wave][cidx + 8];
            const float* pn = xT + (bN + jn) * C_ + sub * 4;
            h0a = *(const float4*)&pn[0];
            h0b = *(const float4*)&pn[32];
            h0c = *(const float4*)&pn[64];
        }
        {
            float4 xq;
            xq = *(const float4*)&xw[96];
            d0 = fma((double)xq.x, (double)h1a.x, d0);
            d1 = fma((double)xq.y, (double)h1a.y, d1);
            d2 = fma((double)xq.z, (double)h1a.z, d2);
            d3 = fma((double)xq.w, (double)h1a.w, d3);
            xq = *(const float4*)&xw[128];
            d0 = fma((double)xq.x, (double)h1b.x, d0);
            d1 = fma((double)xq.y, (double)h1b.y, d1);
            d2 = fma((double)xq.z, (double)h1b.z, d2);
            d3 = fma((double)xq.w, (double)h1b.w, d3);
            xq = *(const float4*)&xw[160];
            d0 = fma((double)xq.x, (double)h1c.x, d0);
            d1 = fma((double)xq.y, (double)h1c.y, d1);
            d2 = fma((double)xq.z, (double)h1c.z, d2);
            d3 = fma((double)xq.w, (double)h1c.w, d3);
        }
        double dot = (d0 + d1) + (d2 + d3);
        dot += __shfl_xor(dot, 1);
        dot += __shfl_xor(dot, 2);
        dot += __shfl_xor(dot, 4);
        if (sub == 0) {
            double dist = sqi + csq[wave][cidx]
                        - 2.0 * (ivi * civ[wave][cidx] * dot);
            kbuf[wave][cidx] = dkey(dist);
        }
    }
    __syncthreads();

    // rank-based top-9 (candidates distinct -> ranks are a permutation)
    unsigned long long kd = kbuf[wave][lane];
    int jme = icand[wave][lane];
    int rank = 0;
#pragma unroll
    for (int m = 0; m < CAND; ++m) {
        unsigned long long km = kbuf[wave][m];
        int jm = icand[wave][m];
        rank += ((km < kd) || (km == kd && jm < jme)) ? 1 : 0;
    }
    if (rank < KNN)
        e0[(size_t)row * KNN + rank] = (float)jme;
}

// ---------------------------------------------------------------------------
// K4c: MFMA dual GEMM (fast path). Reuses the NORMALIZED fp16 fragments
//   (packed) as the B operand; per-point norm rescale applied to D (each
//   lane holds one point: col = lane&15). A operand = wpk weight fragments.
//   Wave w of 4: hsel=w>>1 (0: Zf via W1-W2 +cb, 1: Bh bf16 via W2),
//   og=w&1 selects o-half; 12 o-tiles per wave, W frags double-buffered.
// ---------------------------------------------------------------------------
__global__ __launch_bounds__(256) void k_gemm_mfma(
    const _Float16* __restrict__ packed, const _Float16* __restrict__ wpk,
    const float* __restrict__ nrm32, const float* __restrict__ cb,
    unsigned short* __restrict__ Bh, float* __restrict__ Zf)
{
    int pt   = blockIdx.x;              // 0..783 global 16-point tile
    int wave = threadIdx.x >> 6, lane = threadIdx.x & 63;
    int hsel = wave >> 1;               // 0: Zf, 1: Bh
    int og   = wave & 1;                // o half within 384

    const _Float16* px = packed + (size_t)pt * 6 * 512 + lane * 8;
    half8 pf[6];
#pragma unroll
    for (int kk = 0; kk < 6; ++kk) pf[kk] = *(const half8*)(px + kk * 512);

    float s = nrm32[pt * 16 + (lane & 15)];
    size_t row0 = (size_t)pt * 16 + (lane & 15);
    int olane = (lane >> 4) * 4;

    int ot0 = hsel * 24 + og * 12;
    const _Float16* wb = wpk + (size_t)ot0 * 6 * 512 + lane * 8;

    half8 wf[6];
#pragma unroll
    for (int kk = 0; kk < 6; ++kk) wf[kk] = *(const half8*)(wb + kk * 512);

    for (int t = 0; t < 12; ++t) {
        f32x4 acc = {0.f, 0.f, 0.f, 0.f};
#pragma unroll
        for (int kk = 0; kk < 6; ++kk)
            acc = __builtin_amdgcn_mfma_f32_16x16x32_f16(wf[kk], pf[kk], acc, 0, 0, 0);

        if (t < 11) {
            const _Float16* wn = wb + (size_t)(t + 1) * 6 * 512;
#pragma unroll
            for (int kk = 0; kk < 6; ++kk)
                wf[kk] = *(const half8*)(wn + kk * 512);
        }

        int o = (og * 12 + t) * 16 + olane;
        if (hsel == 0) {
            float4 cbv = *(const float4*)&cb[o];
            float4 zv;
            zv.x = acc[0] * s + cbv.x; zv.y = acc[1] * s + cbv.y;
            zv.z = acc[2] * s + cbv.z; zv.w = acc[3] * s + cbv.w;
            *(float4*)&Zf[row0 * 384 + o] = zv;
        } else {
            ushort4 pk;
            pk.x = f2u(acc[0] * s); pk.y = f2u(acc[1] * s);
            pk.z = f2u(acc[2] * s); pk.w = f2u(acc[3] * s);
            *(ushort4*)&Bh[row0 * 384 + o] = pk;
        }
    }
}

// ---------------------------------------------------------------------------
// K5b v2: gather epilogue with quasiconvex-GELU reduction.
// ---------------------------------------------------------------------------
__global__ __launch_bounds__(256) void k_out2(
    const float* __restrict__ e0, const float* __restrict__ gam,
    const float* __restrict__ bet, float* __restrict__ out,
    const unsigned short* __restrict__ Bh, const float* __restrict__ Zf)
{
    __shared__ int jidx[64 * KNN];
    int blk = blockIdx.x;
    int b   = blk / 294;
    int r   = blk % 294;
    int nt  = r % 49, ot = r / 49;
    int n0 = nt * 64, o0 = ot * 64;
    int tid = threadIdx.x;
    int tx = tid & 15, ty = tid >> 4;

    for (int e = tid; e < 64 * KNN; e += 256)
        jidx[e] = (int)e0[((size_t)b * NPT + n0 + e / KNN) * KNN + e % KNN];

    const float inv_s = 0.9999950000374997f;  // 1/sqrt(1+1e-5)
    float gs[4], bts[4];
#pragma unroll
    for (int v = 0; v < 4; ++v) {
        int o = o0 + tx * 4 + v;
        gs[v]  = gam[o] * inv_s;
        bts[v] = bet[o];
    }
    __syncthreads();

    float best[4][4];
#pragma unroll
    for (int u = 0; u < 4; ++u) {
        float4 z = *(const float4*)
            &Zf[(size_t)(b * NPT + n0 + ty * 4 + u) * 384 + o0 + tx * 4];
        float zA[4] = {z.x, z.y, z.z, z.w};

        float ymin[4], ymax[4];
#pragma unroll
        for (int v = 0; v < 4; ++v) { ymin[v] = 1e30f; ymax[v] = -1e30f; }

        const int* jr = &jidx[(ty * 4 + u) * KNN];
#pragma unroll
        for (int k = 0; k < KNN; ++k) {
            int j = jr[k];
            ushort4 g = *(const ushort4*)
                &Bh[(size_t)(b * NPT + j) * 384 + o0 + tx * 4];
            float bvv[4] = {u2f(g.x), u2f(g.y), u2f(g.z), u2f(g.w)};
#pragma unroll
            for (int v = 0; v < 4; ++v) {
                float y = fmaf(zA[v] + bvv[v], gs[v], bts[v]);
                ymin[v] = fminf(ymin[v], y);
                ymax[v] = fmaxf(ymax[v], y);
            }
        }
#pragma unroll
        for (int v = 0; v < 4; ++v)
            best[u][v] = fmaxf(gelu_exact(ymin[v]), gelu_exact(ymax[v]));
    }

#pragma unroll
    for (int v = 0; v < 4; ++v) {
        int o = o0 + tx * 4 + v;
        float4 pk = {best[0][v], best[1][v], best[2][v], best[3][v]};
        *(float4*)(out + ((size_t)(b * CO_ + o)) * NPT + n0 + ty * 4) = pk;
    }
}

// ---------------------------------------------------------------------------
// K4: B = W2 * x (fallback path, multi-batch).
// ---------------------------------------------------------------------------
__global__ __launch_bounds__(256) void k_gemmB(
    const float* __restrict__ x, const float* __restrict__ cw,
    void* __restrict__ Bq, int bbase, int bcol0, int ldB, int storeBf16,
    int botiles, int bstrideBytes)
{
    int per = 49 * botiles;
    int blk = blockIdx.x;
    int bi  = blk / per;
    int r   = blk % per;
    int b   = bbase + bi;
    int bm = r % 49;
    int bo = r / 49;
    int m0 = bm * 64;
    char* Bp = (char*)Bq + (size_t)bi * (size_t)bstrideBytes;

    __shared__ float Xt[16][68];
    __shared__ float Wt[16][68];
    int tid = threadIdx.x;
    int tx = tid & 15, ty = tid >> 4;
    const float* xb = x + (size_t)b * C_ * NPT;
    float acc[4][4];
#pragma unroll
    for (int u = 0; u < 4; ++u)
#pragma unroll
        for (int v = 0; v < 4; ++v) acc[u][v] = 0.f;

    for (int ct = 0; ct < 12; ++ct) {
        int c0 = ct * 16;
        {
            int cc = tid >> 4, n4 = (tid & 15) * 4;
            *(float4*)&Xt[cc][n4] =
                *(const float4*)&xb[(size_t)(c0 + cc) * NPT + m0 + n4];
        }
        {
            int oo = tid >> 2, c4 = (tid & 3) * 4;
            int o = bcol0 + bo * 64 + oo;
            float4 w = *(const float4*)&cw[(size_t)o * 384 + C_ + c0 + c4];
            Wt[c4 + 0][oo] = w.x; Wt[c4 + 1][oo] = w.y;
            Wt[c4 + 2][oo] = w.z; Wt[c4 + 3][oo] = w.w;
        }
        __syncthreads();
#pragma unroll
        for (int cc = 0; cc < 16; ++cc) {
            float4 av = *(const float4*)&Xt[cc][ty * 4];
            float4 bv = *(const float4*)&Wt[cc][tx * 4];
            float a_[4] = {av.x, av.y, av.z, av.w};
            float b_[4] = {bv.x, bv.y, bv.z, bv.w};
#pragma unroll
            for (int u = 0; u < 4; ++u)
#pragma unroll
                for (int v = 0; v < 4; ++v)
                    acc[u][v] = fmaf(a_[u], b_[v], acc[u][v]);
        }
        __syncthreads();
    }
    if (!storeBf16) {
        float* Bf = (float*)Bp;
#pragma unroll
        for (int u = 0; u < 4; ++u) {
            float4 pk = {acc[u][0], acc[u][1], acc[u][2], acc[u][3]};
            *(float4*)&Bf[(size_t)(m0 + ty * 4 + u) * ldB + bo * 64 + tx * 4] = pk;
        }
    } else {
        unsigned short* Bh = (unsigned short*)Bp;
#pragma unroll
        for (int u = 0; u < 4; ++u) {
            ushort4 pk;
            pk.x = f2u(acc[u][0]); pk.y = f2u(acc[u][1]);
            pk.z = f2u(acc[u][2]); pk.w = f2u(acc[u][3]);
            *(ushort4*)&Bh[(size_t)(m0 + ty * 4 + u) * ldB + bo * 64 + tx * 4] = pk;
        }
    }
}

// ---------------------------------------------------------------------------
// K5: fused epilogue (fallback path, multi-batch). Unchanged (proven).
// ---------------------------------------------------------------------------
__global__ __launch_bounds__(256) void k_outA(
    const float* __restrict__ x, const float* __restrict__ cw,
    const float* __restrict__ e0, const float* __restrict__ cb,
    const float* __restrict__ gam, const float* __restrict__ bet,
    float* __restrict__ out, const void* __restrict__ Bq,
    int bbase, int o0base, int bcol0, int ldB, int readBf16,
    int botiles, int bstrideBytes)
{
    int per = 49 * botiles;
    int blk = blockIdx.x;
    int bi  = blk / per;
    int r   = blk % per;
    int b   = bbase + bi;
    int nt = r % 49, ot = r / 49;
    int n0 = nt * 64, o0 = o0base + ot * 64;
    const char* Bp = (const char*)Bq + (size_t)bi * (size_t)bstrideBytes;

    __shared__ float Xi[16][68];
    __shared__ float Wd[16][68];
    __shared__ int jidx[64 * KNN];
    int tid = threadIdx.x;
    int tx = tid & 15, ty = tid >> 4;
    const float* xb = x + (size_t)b * C_ * NPT;

    for (int e = tid; e < 64 * KNN; e += 256)
        jidx[e] = (int)e0[((size_t)b * NPT + n0 + e / KNN) * KNN + e % KNN];

    float zA[4][4];
#pragma unroll
    for (int u = 0; u < 4; ++u)
#pragma unroll
        for (int v = 0; v < 4; ++v) zA[u][v] = 0.f;

    for (int ct = 0; ct < 12; ++ct) {
        int c0 = ct * 16;
        {
            int cc = tid >> 4, n4 = (tid & 15) * 4;
            *(float4*)&Xi[cc][n4] =
                *(const float4*)&xb[(size_t)(c0 + cc) * NPT + n0 + n4];
        }
        {
            int oo = tid >> 2, c4 = (tid & 3) * 4;
            int o = o0 + oo;
            float4 w1 = *(const float4*)&cw[(size_t)o * 384 + c0 + c4];
            float4 w2 = *(const float4*)&cw[(size_t)o * 384 + C_ + c0 + c4];
            Wd[c4 + 0][oo] = w1.x - w2.x; Wd[c4 + 1][oo] = w1.y - w2.y;
            Wd[c4 + 2][oo] = w1.z - w2.z; Wd[c4 + 3][oo] = w1.w - w2.w;
        }
        __syncthreads();
#pragma unroll
        for (int cc = 0; cc < 16; ++cc) {
            float4 av = *(const float4*)&Xi[cc][ty * 4];
            float4 bv = *(const float4*)&Wd[cc][tx * 4];
            float a_[4] = {av.x, av.y, av.z, av.w};
            float b_[4] = {bv.x, bv.y, bv.z, bv.w};
#pragma unroll
            for (int u = 0; u < 4; ++u)
#pragma unroll
                for (int v = 0; v < 4; ++v)
                    zA[u][v] = fmaf(a_[u], b_[v], zA[u][v]);
        }
        __syncthreads();
    }

    const float inv_s = 0.9999950000374997f;  // 1/sqrt(1+1e-5)
    float gs[4], bts[4], cbs[4];
#pragma unroll
    for (int v = 0; v < 4; ++v) {
        int o = o0 + tx * 4 + v;
        gs[v]  = gam[o] * inv_s;
        bts[v] = bet[o];
        cbs[v] = cb[o];
    }

    float best[4][4];
#pragma unroll
    for (int u = 0; u < 4; ++u)
#pragma unroll
        for (int v = 0; v < 4; ++v) best[u][v] = -1e30f;

    int obB = o0 - bcol0;
    for (int k = 0; k < KNN; ++k) {
#pragma unroll
        for (int u = 0; u < 4; ++u) {
            int j = jidx[(ty * 4 + u) * KNN + k];
            float bvv[4];
            if (!readBf16) {
                float4 g = *(const float4*)
                    ((const float*)Bp + (size_t)j * ldB + obB + tx * 4);
                bvv[0] = g.x; bvv[1] = g.y; bvv[2] = g.z; bvv[3] = g.w;
            } else {
                ushort4 g = *(const ushort4*)
                    ((const unsigned short*)Bp + (size_t)j * ldB + obB + tx * 4);
                bvv[0] = u2f(g.x); bvv[1] = u2f(g.y);
                bvv[2] = u2f(g.z); bvv[3] = u2f(g.w);
            }
#pragma unroll
            for (int v = 0; v < 4; ++v) {
                float z = zA[u][v] + bvv[v] + cbs[v];
                float y = fmaf(z, gs[v], bts[v]);
                float ge = 0.5f * y * (1.0f + erff(y * 0.70710678118654752f));
                best[u][v] = fmaxf(best[u][v], ge);
            }
        }
    }

#pragma unroll
    for (int v = 0; v < 4; ++v) {
        int o = o0 + tx * 4 + v;
        float4 pk = {best[0][v], best[1][v], best[2][v], best[3][v]};
        *(float4*)(out + ((size_t)(b * CO_ + o)) * NPT + n0 + ty * 4) = pk;
    }
}

// ---------------------------------------------------------------------------
// K6: generate edge plane1 (center indices) last.
// ---------------------------------------------------------------------------
__global__ __launch_bounds__(256) void k_center(float* __restrict__ e1)
{
    int p = blockIdx.x * 256 + threadIdx.x;
    if (p >= NROWS * KNN) return;
    e1[p] = (float)((p / KNN) % NPT);
}

// ---------------------------------------------------------------------------
extern "C" void kernel_launch(void* const* d_in, const int* in_sizes, int n_in,
                              void* d_out, int out_size, void* d_ws, size_t ws_size,
                              hipStream_t stream)
{
    const float* x   = (const float*)d_in[0];
    const float* cw  = (const float*)d_in[1];
    const float* cb  = (const float*)d_in[2];
    const float* gam = (const float*)d_in[3];
    const float* bet = (const float*)d_in[4];

    // d_out: FLOAT32. out0 = floats [0, 4,816,896); e0 = [4,816,896,
    // 4,929,792); e1 = [4,929,792, 5,042,688).
    // Scratch liveness:
    //   head:   invn64/sqd/invn32/cand  bytes [0, 1,856,512)        dead@refine
    //   packed: fp16 MFMA fragments     bytes [1,856,512, 6,673,408) dead@gemm
    //   nrm32:  fp32 norms              bytes [6,673,408, 6,723,584) dead@gemm
    //   wpk:    fp16 weight fragments   bytes [6,723,584, 7,018,496) dead@gemm
    //   xT:     fp32 transposed x       bytes [9,633,792, 19,267,584) dead@refine
    float* ou   = (float*)d_out;
    float* out0 = ou;
    double* invn64 = (double*)d_out;
    double* sqd    = (double*)((char*)d_out + 100352);
    float*  invn32 = (float*)((char*)d_out + 200704);
    unsigned short* cand =
        (unsigned short*)((char*)d_out + 250880);          // 1,605,632 B
    _Float16* packed = (_Float16*)(ou + 464128);           // 4,816,896 B
    float*    nrm32  = (float*)((char*)d_out + 6673408);   //    50,176 B
    _Float16* wpk    = (_Float16*)((char*)d_out + 6723584);//   294,912 B
    float* xT = ou + 2408448;                              // 9.63 MB
    float* e0 = ou + 4816896;
    float* e1 = ou + 4929792;

    k_norm       <<<NROWS / 64, 256, 0, stream>>>(x, invn32, invn64, sqd, nrm32);
    k_xpose      <<<B_ * 6 * 98, 256, 0, stream>>>(x, xT, invn32, packed);
    k_screen_mfma<<<B_ * 49 * 4, 256, 0, stream>>>(packed, cand);
    k_refine     <<<NROWS / 4, 256, 0, stream>>>(xT, invn64, sqd, cand, e0);

    const size_t BH_BYTES = (size_t)NROWS * 384 * 2;   //  9,633,792 bf16 B
    const size_t ZF_BYTES = (size_t)NROWS * 384 * 4;   // 19,267,584 fp32 zA
    const int    BSTRIDE  = NPT * CO_ * 4;             // fp32 batch-B stride

    if (ws_size >= BH_BYTES + ZF_BYTES) {
        // FAST PATH: MFMA dual GEMM from normalized fragments + rescale.
        unsigned short* wsB = (unsigned short*)d_ws;
        float* wsZ = (float*)((char*)d_ws + BH_BYTES);
        k_wpack    <<<72, 256, 0, stream>>>(cw, wpk);
        k_gemm_mfma<<<784, 256, 0, stream>>>(packed, wpk, nrm32, cb, wsB, wsZ);
        k_out2     <<<B_ * 49 * 6, 256, 0, stream>>>(e0, gam, bet, out0,
                                                     wsB, wsZ);
    } else if (ws_size >= ZF_BYTES) {
        // MEDIUM: all-batch fp32 B in d_ws, fused epilogue.
        k_gemmB<<<B_ * 49 * 6, 256, 0, stream>>>(
            x, cw, d_ws, 0, 0, 384, 0, 6, BSTRIDE);
        k_outA <<<B_ * 49 * 6, 256, 0, stream>>>(
            x, cw, e0, cb, gam, bet, out0, (const void*)d_ws,
            0, 0, 0, 384, 0, 6, BSTRIDE);
    } else {
        // FALLBACK: d_out aliasing discipline (R3-proven numerics).
        k_gemmB<<<2 * 49 * 6, 256, 0, stream>>>(
            x, cw, (void*)ou, 2, 0, 384, 0, 6, BSTRIDE);
        k_outA <<<2 * 49 * 6, 256, 0, stream>>>(
            x, cw, e0, cb, gam, bet, out0, (const void*)ou,
            2, 0, 0, 384, 0, 6, BSTRIDE);
        k_gemmB<<<49 * 6, 256, 0, stream>>>(
            x, cw, (void*)ou, 1, 0, 384, 0, 6, 0);
        k_outA <<<49 * 6, 256, 0, stream>>>(
            x, cw, e0, cb, gam, bet, out0, (const void*)ou,
            1, 0, 0, 384, 0, 6, 0);
        k_gemmB<<<49 * 3, 256, 0, stream>>>(
            x, cw, (void*)ou, 0, 192, 192, 1, 3, 0);
        k_outA <<<49 * 3, 256, 0, stream>>>(
            x, cw, e0, cb, gam, bet, out0, (const void*)ou,
            0, 192, 192, 192, 1, 3, 0);
        k_gemmB<<<49 * 2, 256, 0, stream>>>(
            x, cw, (void*)ou, 0, 64, 128, 1, 2, 0);
        k_outA <<<49 * 2, 256, 0, stream>>>(
            x, cw, e0, cb, gam, bet, out0, (const void*)ou,
            0, 64, 64, 128, 1, 2, 0);
        k_gemmB<<<49 * 1, 256, 0, stream>>>(
            x, cw, (void*)e1, 0, 0, 64, 1, 1, 0);
        k_outA <<<49 * 1, 256, 0, stream>>>(
            x, cw, e0, cb, gam, bet, out0, (const void*)e1,
            0, 0, 0, 64, 1, 1, 0);
    }
    // Generate e1 (center plane) last.
    k_center<<<(NROWS * KNN + 255) / 256, 256, 0, stream>>>(e1);
}

// Round 10
// 207.518 us; speedup vs baseline: 4.4224x; 1.0461x over previous
//
#include <hip/hip_runtime.h>
#include <hip/hip_bf16.h>
#include <math.h>

#define B_    4
#define C_    192
#define NPT   3136          // H*W points per batch
#define CO_   384           // Cout
#define KNN   9
#define CAND  64            // 7 j-chunks * top-9 + 1 sentinel slot
#define NROWS (B_*NPT)      // 12544 total points
#define SD    10            // per-lane screening stream depth

typedef _Float16 half8 __attribute__((ext_vector_type(8)));
typedef float    f32x4 __attribute__((ext_vector_type(4)));

__device__ __forceinline__ float u2f(unsigned short u) {
    unsigned int t = ((unsigned int)u) << 16;
    float f; __builtin_memcpy(&f, &t, 4); return f;
}
__device__ __forceinline__ unsigned short f2u(float f) {
    __hip_bfloat16 h = __float2bfloat16(f);
    unsigned short u; __builtin_memcpy(&u, &h, 2); return u;
}
__device__ __forceinline__ float gelu_exact(float y) {
    return 0.5f * y * (1.0f + erff(y * 0.70710678118654752f));
}
// sortable u64 key for an f64 (ascending double order == ascending u64 order)
__device__ __forceinline__ unsigned long long dkey(double d) {
    long long sb = __double_as_longlong(d);
    unsigned long long u = (unsigned long long)sb;
    return (sb < 0) ? ~u : (u | 0x8000000000000000ULL);
}

// ---------------------------------------------------------------------------
// K1 v3: per-point f64 norm stats (+ fp32 norm for MFMA rescale).
// ---------------------------------------------------------------------------
__global__ __launch_bounds__(256) void k_norm(
    const float* __restrict__ x,
    float* __restrict__ invn32, double* __restrict__ invn64,
    double* __restrict__ sqd, float* __restrict__ nrm32)
{
    __shared__ double part[4][64];
    int wave = threadIdx.x >> 6, lane = threadIdx.x & 63;
    int p0 = blockIdx.x * 64;          // 64 points per block, 196 blocks
    int row = p0 + lane;
    int b = row / NPT, n = row % NPT;
    const float* xb = x + (size_t)b * C_ * NPT + n;
    double S = 0.0;
    int c0 = wave * 48;
    for (int c = c0; c < c0 + 48; ++c) {
        double v = (double)xb[(size_t)c * NPT];
        S = fma(v, v, S);
    }
    part[wave][lane] = S;
    __syncthreads();
    if (threadIdx.x < 64) {
        double T = ((part[0][lane] + part[1][lane]) + part[2][lane])
                 + part[3][lane];
        double nrm = sqrt(T);
        if (nrm < 1e-12) nrm = 1e-12;
        double iv = 1.0 / nrm;
        int prow = p0 + lane;
        invn64[prow] = iv;
        invn32[prow] = (float)iv;
        sqd[prow] = iv * iv * T;
        nrm32[prow] = (float)nrm;
    }
}

// ---------------------------------------------------------------------------
// K1b v2: LDS-tiled transpose x -> xT (fp32, exact) + fused fp16 pack.
// ---------------------------------------------------------------------------
__global__ __launch_bounds__(256) void k_xpose(
    const float* __restrict__ x, float* __restrict__ xT,
    const float* __restrict__ invn32, _Float16* __restrict__ packed)
{
    __shared__ float t[32][33];
    int blk = blockIdx.x;
    int b  = blk / 588;
    int r  = blk % 588;
    int ct = r / 98, nt = r % 98;
    int c0 = ct * 32, n0 = nt * 32;
    int tid = threadIdx.x;
    int tx = tid & 31, ty8 = tid >> 5;          // 8 rows per pass
    const float* xb = x + (size_t)b * C_ * NPT;
#pragma unroll
    for (int e = 0; e < 4; ++e) {
        int cc = ty8 + e * 8;
        t[cc][tx] = xb[(size_t)(c0 + cc) * NPT + n0 + tx];
    }
    __syncthreads();
#pragma unroll
    for (int e = 0; e < 4; ++e) {
        int nn = ty8 + e * 8;
        xT[(size_t)(b * NPT + n0 + nn) * C_ + c0 + tx] = t[tx][nn];
    }
    if (tid < 128) {
        int f = tid >> 6, l = tid & 63;
        int pt = f * 16 + (l & 15);            // tile-local point
        float iv = invn32[(size_t)b * NPT + n0 + pt];
        int cb = (l >> 4) * 8;                 // tile-local channel base
        half8 h;
#pragma unroll
        for (int e = 0; e < 8; ++e)
            h[e] = (_Float16)(t[cb + e][pt] * iv);
        size_t idx = ((((size_t)(b * 196 + nt * 2 + f)) * 6 + ct) * 64 + l) * 8;
        *(half8*)(packed + idx) = h;
    }
}

// ---------------------------------------------------------------------------
// K1d: pack weights into MFMA A-fragments (fp16), once.
// ---------------------------------------------------------------------------
__global__ __launch_bounds__(256) void k_wpack(
    const float* __restrict__ cw, _Float16* __restrict__ wpk)
{
    int t = blockIdx.x * 256 + threadIdx.x;   // 48*6*64 = 18432
    if (t >= 48 * 6 * 64) return;
    int l  = t & 63;
    int tk = t >> 6;            // ot*6+kk
    int kk = tk % 6, ot = tk / 6;
    int hsel = ot / 24;
    int o = (ot % 24) * 16 + (l & 15);
    int k = kk * 32 + (l >> 4) * 8;
    half8 h;
#pragma unroll
    for (int e = 0; e < 8; ++e) {
        float w2 = cw[(size_t)o * 384 + C_ + k + e];
        float wv = hsel ? w2 : (cw[(size_t)o * 384 + k + e] - w2);
        h[e] = (_Float16)wv;
    }
    *(half8*)(wpk + (size_t)t * 8) = h;
}

// ---------------------------------------------------------------------------
// K2 (MFMA v3): 7 uniform j-chunks (28 tiles each), top-9 per chunk.
//   Grid = 7 * (B*49) blocks; chunk = blk/196 -> consecutive blocks share
//   the same chunk's j-fragments in L2. 1372 blocks (was 784) doubles
//   resident waves; per-lane stream shrinks 192 -> 112 candidates.
//   Guarantee: a true top-9 member has <=8 truly-better points anywhere ->
//   within top-9 of its stream (SD=10 kept for approx-order margin) and
//   top-9 of its chunk. 7*9 = 63 slots; slot 63 = sentinel (idx 0, key
//   forced to ~0 in refine) so ranks stay a permutation.
// ---------------------------------------------------------------------------
__global__ __launch_bounds__(256) void k_screen_mfma(
    const _Float16* __restrict__ packed, unsigned short* __restrict__ cand)
{
    __shared__ unsigned md[64][4 * SD + 1];   // stride 41
    int blk   = blockIdx.x;
    int chunk = blk / 196;               // 0..6
    int t2    = blk % 196;
    int b     = t2 / 49;
    int itile = t2 % 49;                 // 64-row i tile
    int tid   = threadIdx.x;
    int wave  = tid >> 6, lane = tid & 63;
    int it    = itile * 4 + wave;        // global 16-row tile within batch

    const _Float16* pb = packed + ((size_t)(b * 196 + it) * 6) * 512 + lane * 8;
    half8 bf[6];
#pragma unroll
    for (int kk = 0; kk < 6; ++kk)
        bf[kk] = *(const half8*)(pb + kk * 512);

    int jt0 = chunk * 28;                 // 7 chunks x 28 tiles (uniform)
    const int ntj = 28;

    unsigned bd[SD];
#pragma unroll
    for (int q = 0; q < SD; ++q) bd[q] = 0u;

    const _Float16* pa_base =
        packed + ((size_t)(b * 196 + jt0) * 6) * 512 + lane * 8;

    half8 af[6];
#pragma unroll
    for (int kk = 0; kk < 6; ++kk)
        af[kk] = *(const half8*)(pa_base + kk * 512);

    for (int jt = 0; jt < ntj; ++jt) {
        f32x4 acc = {0.f, 0.f, 0.f, 0.f};
#pragma unroll
        for (int kk = 0; kk < 6; ++kk)
            acc = __builtin_amdgcn_mfma_f32_16x16x32_f16(af[kk], bf[kk], acc, 0, 0, 0);

        if (jt + 1 < ntj) {
            const _Float16* pn = pa_base + (size_t)(jt + 1) * 6 * 512;
#pragma unroll
            for (int kk = 0; kk < 6; ++kk)
                af[kk] = *(const half8*)(pn + kk * 512);
        }

        unsigned jb = (unsigned)((jt0 + jt) * 16 + (lane >> 4) * 4);
#pragma unroll
        for (int q = 0; q < 4; ++q) {
            float s = acc[q] + 2.0f;
            unsigned fb = __float_as_uint(s);
            unsigned c = (fb & 0xFFFFF000u) | (jb + (unsigned)q);
#pragma unroll
            for (int t = 0; t < SD; ++t) {
                unsigned old = bd[t];
                unsigned mx = old > c ? old : c;    // v_max_u32
                c           = old > c ? c : old;    // v_min_u32
                bd[t] = mx;
            }
        }
    }

    int ir = wave * 16 + (lane & 15);    // i-row within block (0..63)
    int g  = lane >> 4;                  // stream id
#pragma unroll
    for (int q = 0; q < SD; ++q) md[ir][g * SD + q] = bd[q];
    __syncthreads();

    if (tid < 64) {
        int h[4] = {0, 0, 0, 0};
        unsigned short* cp =
            cand + ((size_t)b * NPT + itile * 64 + tid) * CAND + chunk * 9;
        const unsigned* rd = &md[tid][0];
        for (int s = 0; s < 9; ++s) {
            unsigned best = 0u; int bg = 0;
#pragma unroll
            for (int g2 = 0; g2 < 4; ++g2) {
                unsigned v = (h[g2] < SD) ? rd[g2 * SD + h[g2]] : 0u;
                if (v > best) { best = v; bg = g2; }
            }
            cp[s] = (unsigned short)(best & 0xFFFu);
            h[bg]++;
        }
        if (chunk == 0)                   // sentinel slot 63: valid index 0
            cand[((size_t)b * NPT + itile * 64 + tid) * CAND + 63] = 0;
    }
}

// ---------------------------------------------------------------------------
// K3 v5: f64 refine — LDS xi + LDS cand stats + half-candidate pipeline.
//   Slot 63 is a sentinel: its key is forced to ~0ULL (greater than any
//   finite dkey) so its rank is always 63 and ranks 0..62 stay a hole-free
//   permutation of the 63 real (distinct) candidates.
// ---------------------------------------------------------------------------
__global__ __launch_bounds__(256) void k_refine(
    const float* __restrict__ xT, const double* __restrict__ invn64,
    const double* __restrict__ sqd, const unsigned short* __restrict__ cand,
    float* __restrict__ e0)
{
    __shared__ unsigned long long kbuf[4][CAND];
    __shared__ int    icand[4][CAND];
    __shared__ double civ[4][CAND];
    __shared__ double csq[4][CAND];
    __shared__ float  xi[4][C_];
    int wave = threadIdx.x >> 6;
    int lane = threadIdx.x & 63;
    int row  = blockIdx.x * 4 + wave;
    int b    = row / NPT;
    size_t bN = (size_t)b * NPT;

    int jc = (int)cand[(size_t)row * CAND + lane];
    icand[wave][lane] = jc;
    civ[wave][lane] = invn64[bN + jc];
    csq[wave][lane] = sqd[bN + jc];
    const float* xiRow = xT + (size_t)row * C_;
    xi[wave][lane]       = xiRow[lane];
    xi[wave][lane + 64]  = xiRow[lane + 64];
    xi[wave][lane + 128] = xiRow[lane + 128];
    __syncthreads();

    int sub = lane & 7, cg = lane >> 3;
    double ivi = invn64[row], sqi = sqd[row];
    const float* xw = &xi[wave][sub * 4];

    // prologue: first half of candidate cg
    float4 h0a, h0b, h0c;
    {
        int j0 = icand[wave][cg];
        const float* p = xT + (bN + j0) * C_ + sub * 4;
        h0a = *(const float4*)&p[0];
        h0b = *(const float4*)&p[32];
        h0c = *(const float4*)&p[64];
    }

#pragma unroll
    for (int cc = 0; cc < 8; ++cc) {
        int cidx = cc * 8 + cg;
        int jcur = icand[wave][cidx];
        const float* pc = xT + (bN + jcur) * C_ + sub * 4;
        // issue second-half loads of current candidate
        float4 h1a = *(const float4*)&pc[96];
        float4 h1b = *(const float4*)&pc[128];
        float4 h1c = *(const float4*)&pc[160];

        double d0 = 0.0, d1 = 0.0, d2 = 0.0, d3 = 0.0;
        {
            float4 xq;
            xq = *(const float4*)&xw[0];
            d0 = fma((double)xq.x, (double)h0a.x, d0);
            d1 = fma((double)xq.y, (double)h0a.y, d1);
            d2 = fma((double)xq.z, (double)h0a.z, d2);
            d3 = fma((double)xq.w, (double)h0a.w, d3);
            xq = *(const float4*)&xw[32];
            d0 = fma((double)xq.x, (double)h0b.x, d0);
            d1 = fma((double)xq.y, (double)h0b.y, d1);
            d2 = fma((double)xq.z, (double)h0b.z, d2);
            d3 = fma((double)xq.w, (double)h0b.w, d3);
            xq = *(const float4*)&xw[64];
            d0 = fma((double)xq.x, (double)h0c.x, d0);
            d1 = fma((double)xq.y, (double)h0c.y, d1);
            d2 = fma((double)xq.z, (double)h0c.z, d2);
            d3 = fma((double)xq.w, (double)h0c.w, d3);
        }
        // prefetch first half of NEXT candidate into the freed h0 regs
        if (cc < 7) {
            int jn = icand[wave][cidx + 8];
            const float* pn = xT + (bN + jn) * C_ + sub * 4;
            h0a = *(const float4*)&pn[0];
            h0b = *(const float4*)&pn[32];
            h0c = *(const float4*)&pn[64];
        }
        {
            float4 xq;
            xq = *(const float4*)&xw[96];
            d0 = fma((double)xq.x, (double)h1a.x, d0);
            d1 = fma((double)xq.y, (double)h1a.y, d1);
            d2 = fma((double)xq.z, (double)h1a.z, d2);
            d3 = fma((double)xq.w, (double)h1a.w, d3);
            xq = *(const float4*)&xw[128];
            d0 = fma((double)xq.x, (double)h1b.x, d0);
            d1 = fma((double)xq.y, (double)h1b.y, d1);
            d2 = fma((double)xq.z, (double)h1b.z, d2);
            d3 = fma((double)xq.w, (double)h1b.w, d3);
            xq = *(const float4*)&xw[160];
            d0 = fma((double)xq.x, (double)h1c.x, d0);
            d1 = fma((double)xq.y, (double)h1c.y, d1);
            d2 = fma((double)xq.z, (double)h1c.z, d2);
            d3 = fma((double)xq.w, (double)h1c.w, d3);
        }
        double dot = (d0 + d1) + (d2 + d3);
        dot += __shfl_xor(dot, 1);
        dot += __shfl_xor(dot, 2);
        dot += __shfl_xor(dot, 4);
        if (sub == 0) {
            double dist = sqi + csq[wave][cidx]
                        - 2.0 * (ivi * civ[wave][cidx] * dot);
            kbuf[wave][cidx] = dkey(dist);
        }
    }
    // sentinel: slot 63 always ranks last (wave-synchronous overwrite)
    if (lane == 0) kbuf[wave][63] = 0xFFFFFFFFFFFFFFFFULL;
    __syncthreads();

    // rank-based top-9 (real candidates distinct -> ranks 0..62 permutation)
    unsigned long long kd = kbuf[wave][lane];
    int jme = icand[wave][lane];
    int rank = 0;
#pragma unroll
    for (int m = 0; m < CAND; ++m) {
        unsigned long long km = kbuf[wave][m];
        int jm = icand[wave][m];
        rank += ((km < kd) || (km == kd && jm < jme)) ? 1 : 0;
    }
    if (rank < KNN)
        e0[(size_t)row * KNN + rank] = (float)jme;
}

// ---------------------------------------------------------------------------
// K4c: MFMA dual GEMM (fast path). packed = normalized fp16 B operand;
//   per-point norm rescale on D (lane holds one point: col = lane&15).
// ---------------------------------------------------------------------------
__global__ __launch_bounds__(256) void k_gemm_mfma(
    const _Float16* __restrict__ packed, const _Float16* __restrict__ wpk,
    const float* __restrict__ nrm32, const float* __restrict__ cb,
    unsigned short* __restrict__ Bh, float* __restrict__ Zf)
{
    int pt   = blockIdx.x;              // 0..783 global 16-point tile
    int wave = threadIdx.x >> 6, lane = threadIdx.x & 63;
    int hsel = wave >> 1;               // 0: Zf, 1: Bh
    int og   = wave & 1;                // o half within 384

    const _Float16* px = packed + (size_t)pt * 6 * 512 + lane * 8;
    half8 pf[6];
#pragma unroll
    for (int kk = 0; kk < 6; ++kk) pf[kk] = *(const half8*)(px + kk * 512);

    float s = nrm32[pt * 16 + (lane & 15)];
    size_t row0 = (size_t)pt * 16 + (lane & 15);
    int olane = (lane >> 4) * 4;

    int ot0 = hsel * 24 + og * 12;
    const _Float16* wb = wpk + (size_t)ot0 * 6 * 512 + lane * 8;

    half8 wf[6];
#pragma unroll
    for (int kk = 0; kk < 6; ++kk) wf[kk] = *(const half8*)(wb + kk * 512);

    for (int t = 0; t < 12; ++t) {
        f32x4 acc = {0.f, 0.f, 0.f, 0.f};
#pragma unroll
        for (int kk = 0; kk < 6; ++kk)
            acc = __builtin_amdgcn_mfma_f32_16x16x32_f16(wf[kk], pf[kk], acc, 0, 0, 0);

        if (t < 11) {
            const _Float16* wn = wb + (size_t)(t + 1) * 6 * 512;
#pragma unroll
            for (int kk = 0; kk < 6; ++kk)
                wf[kk] = *(const half8*)(wn + kk * 512);
        }

        int o = (og * 12 + t) * 16 + olane;
        if (hsel == 0) {
            float4 cbv = *(const float4*)&cb[o];
            float4 zv;
            zv.x = acc[0] * s + cbv.x; zv.y = acc[1] * s + cbv.y;
            zv.z = acc[2] * s + cbv.z; zv.w = acc[3] * s + cbv.w;
            *(float4*)&Zf[row0 * 384 + o] = zv;
        } else {
            ushort4 pk;
            pk.x = f2u(acc[0] * s); pk.y = f2u(acc[1] * s);
            pk.z = f2u(acc[2] * s); pk.w = f2u(acc[3] * s);
            *(ushort4*)&Bh[row0 * 384 + o] = pk;
        }
    }
}

// ---------------------------------------------------------------------------
// K5b v2: gather epilogue with quasiconvex-GELU reduction.
// ---------------------------------------------------------------------------
__global__ __launch_bounds__(256) void k_out2(
    const float* __restrict__ e0, const float* __restrict__ gam,
    const float* __restrict__ bet, float* __restrict__ out,
    const unsigned short* __restrict__ Bh, const float* __restrict__ Zf)
{
    __shared__ int jidx[64 * KNN];
    int blk = blockIdx.x;
    int b   = blk / 294;
    int r   = blk % 294;
    int nt  = r % 49, ot = r / 49;
    int n0 = nt * 64, o0 = ot * 64;
    int tid = threadIdx.x;
    int tx = tid & 15, ty = tid >> 4;

    for (int e = tid; e < 64 * KNN; e += 256)
        jidx[e] = (int)e0[((size_t)b * NPT + n0 + e / KNN) * KNN + e % KNN];

    const float inv_s = 0.9999950000374997f;  // 1/sqrt(1+1e-5)
    float gs[4], bts[4];
#pragma unroll
    for (int v = 0; v < 4; ++v) {
        int o = o0 + tx * 4 + v;
        gs[v]  = gam[o] * inv_s;
        bts[v] = bet[o];
    }
    __syncthreads();

    float best[4][4];
#pragma unroll
    for (int u = 0; u < 4; ++u) {
        float4 z = *(const float4*)
            &Zf[(size_t)(b * NPT + n0 + ty * 4 + u) * 384 + o0 + tx * 4];
        float zA[4] = {z.x, z.y, z.z, z.w};

        float ymin[4], ymax[4];
#pragma unroll
        for (int v = 0; v < 4; ++v) { ymin[v] = 1e30f; ymax[v] = -1e30f; }

        const int* jr = &jidx[(ty * 4 + u) * KNN];
#pragma unroll
        for (int k = 0; k < KNN; ++k) {
            int j = jr[k];
            ushort4 g = *(const ushort4*)
                &Bh[(size_t)(b * NPT + j) * 384 + o0 + tx * 4];
            float bvv[4] = {u2f(g.x), u2f(g.y), u2f(g.z), u2f(g.w)};
#pragma unroll
            for (int v = 0; v < 4; ++v) {
                float y = fmaf(zA[v] + bvv[v], gs[v], bts[v]);
                ymin[v] = fminf(ymin[v], y);
                ymax[v] = fmaxf(ymax[v], y);
            }
        }
#pragma unroll
        for (int v = 0; v < 4; ++v)
            best[u][v] = fmaxf(gelu_exact(ymin[v]), gelu_exact(ymax[v]));
    }

#pragma unroll
    for (int v = 0; v < 4; ++v) {
        int o = o0 + tx * 4 + v;
        float4 pk = {best[0][v], best[1][v], best[2][v], best[3][v]};
        *(float4*)(out + ((size_t)(b * CO_ + o)) * NPT + n0 + ty * 4) = pk;
    }
}

// ---------------------------------------------------------------------------
// K4: B = W2 * x (fallback path, multi-batch).
// ---------------------------------------------------------------------------
__global__ __launch_bounds__(256) void k_gemmB(
    const float* __restrict__ x, const float* __restrict__ cw,
    void* __restrict__ Bq, int bbase, int bcol0, int ldB, int storeBf16,
    int botiles, int bstrideBytes)
{
    int per = 49 * botiles;
    int blk = blockIdx.x;
    int bi  = blk / per;
    int r   = blk % per;
    int b   = bbase + bi;
    int bm = r % 49;
    int bo = r / 49;
    int m0 = bm * 64;
    char* Bp = (char*)Bq + (size_t)bi * (size_t)bstrideBytes;

    __shared__ float Xt[16][68];
    __shared__ float Wt[16][68];
    int tid = threadIdx.x;
    int tx = tid & 15, ty = tid >> 4;
    const float* xb = x + (size_t)b * C_ * NPT;
    float acc[4][4];
#pragma unroll
    for (int u = 0; u < 4; ++u)
#pragma unroll
        for (int v = 0; v < 4; ++v) acc[u][v] = 0.f;

    for (int ct = 0; ct < 12; ++ct) {
        int c0 = ct * 16;
        {
            int cc = tid >> 4, n4 = (tid & 15) * 4;
            *(float4*)&Xt[cc][n4] =
                *(const float4*)&xb[(size_t)(c0 + cc) * NPT + m0 + n4];
        }
        {
            int oo = tid >> 2, c4 = (tid & 3) * 4;
            int o = bcol0 + bo * 64 + oo;
            float4 w = *(const float4*)&cw[(size_t)o * 384 + C_ + c0 + c4];
            Wt[c4 + 0][oo] = w.x; Wt[c4 + 1][oo] = w.y;
            Wt[c4 + 2][oo] = w.z; Wt[c4 + 3][oo] = w.w;
        }
        __syncthreads();
#pragma unroll
        for (int cc = 0; cc < 16; ++cc) {
            float4 av = *(const float4*)&Xt[cc][ty * 4];
            float4 bv = *(const float4*)&Wt[cc][tx * 4];
            float a_[4] = {av.x, av.y, av.z, av.w};
            float b_[4] = {bv.x, bv.y, bv.z, bv.w};
#pragma unroll
            for (int u = 0; u < 4; ++u)
#pragma unroll
                for (int v = 0; v < 4; ++v)
                    acc[u][v] = fmaf(a_[u], b_[v], acc[u][v]);
        }
        __syncthreads();
    }
    if (!storeBf16) {
        float* Bf = (float*)Bp;
#pragma unroll
        for (int u = 0; u < 4; ++u) {
            float4 pk = {acc[u][0], acc[u][1], acc[u][2], acc[u][3]};
            *(float4*)&Bf[(size_t)(m0 + ty * 4 + u) * ldB + bo * 64 + tx * 4] = pk;
        }
    } else {
        unsigned short* Bh = (unsigned short*)Bp;
#pragma unroll
        for (int u = 0; u < 4; ++u) {
            ushort4 pk;
            pk.x = f2u(acc[u][0]); pk.y = f2u(acc[u][1]);
            pk.z = f2u(acc[u][2]); pk.w = f2u(acc[u][3]);
            *(ushort4*)&Bh[(size_t)(m0 + ty * 4 + u) * ldB + bo * 64 + tx * 4] = pk;
        }
    }
}

// ---------------------------------------------------------------------------
// K5: fused epilogue (fallback path, multi-batch). Unchanged (proven).
// ---------------------------------------------------------------------------
__global__ __launch_bounds__(256) void k_outA(
    const float* __restrict__ x, const float* __restrict__ cw,
    const float* __restrict__ e0, const float* __restrict__ cb,
    const float* __restrict__ gam, const float* __restrict__ bet,
    float* __restrict__ out, const void* __restrict__ Bq,
    int bbase, int o0base, int bcol0, int ldB, int readBf16,
    int botiles, int bstrideBytes)
{
    int per = 49 * botiles;
    int blk = blockIdx.x;
    int bi  = blk / per;
    int r   = blk % per;
    int b   = bbase + bi;
    int nt = r % 49, ot = r / 49;
    int n0 = nt * 64, o0 = o0base + ot * 64;
    const char* Bp = (const char*)Bq + (size_t)bi * (size_t)bstrideBytes;

    __shared__ float Xi[16][68];
    __shared__ float Wd[16][68];
    __shared__ int jidx[64 * KNN];
    int tid = threadIdx.x;
    int tx = tid & 15, ty = tid >> 4;
    const float* xb = x + (size_t)b * C_ * NPT;

    for (int e = tid; e < 64 * KNN; e += 256)
        jidx[e] = (int)e0[((size_t)b * NPT + n0 + e / KNN) * KNN + e % KNN];

    float zA[4][4];
#pragma unroll
    for (int u = 0; u < 4; ++u)
#pragma unroll
        for (int v = 0; v < 4; ++v) zA[u][v] = 0.f;

    for (int ct = 0; ct < 12; ++ct) {
        int c0 = ct * 16;
        {
            int cc = tid >> 4, n4 = (tid & 15) * 4;
            *(float4*)&Xi[cc][n4] =
                *(const float4*)&xb[(size_t)(c0 + cc) * NPT + n0 + n4];
        }
        {
            int oo = tid >> 2, c4 = (tid & 3) * 4;
            int o = o0 + oo;
            float4 w1 = *(const float4*)&cw[(size_t)o * 384 + c0 + c4];
            float4 w2 = *(const float4*)&cw[(size_t)o * 384 + C_ + c0 + c4];
            Wd[c4 + 0][oo] = w1.x - w2.x; Wd[c4 + 1][oo] = w1.y - w2.y;
            Wd[c4 + 2][oo] = w1.z - w2.z; Wd[c4 + 3][oo] = w1.w - w2.w;
        }
        __syncthreads();
#pragma unroll
        for (int cc = 0; cc < 16; ++cc) {
            float4 av = *(const float4*)&Xi[cc][ty * 4];
            float4 bv = *(const float4*)&Wd[cc][tx * 4];
            float a_[4] = {av.x, av.y, av.z, av.w};
            float b_[4] = {bv.x, bv.y, bv.z, bv.w};
#pragma unroll
            for (int u = 0; u < 4; ++u)
#pragma unroll
                for (int v = 0; v < 4; ++v)
                    zA[u][v] = fmaf(a_[u], b_[v], zA[u][v]);
        }
        __syncthreads();
    }

    const float inv_s = 0.9999950000374997f;  // 1/sqrt(1+1e-5)
    float gs[4], bts[4], cbs[4];
#pragma unroll
    for (int v = 0; v < 4; ++v) {
        int o = o0 + tx * 4 + v;
        gs[v]  = gam[o] * inv_s;
        bts[v] = bet[o];
        cbs[v] = cb[o];
    }

    float best[4][4];
#pragma unroll
    for (int u = 0; u < 4; ++u)
#pragma unroll
        for (int v = 0; v < 4; ++v) best[u][v] = -1e30f;

    int obB = o0 - bcol0;
    for (int k = 0; k < KNN; ++k) {
#pragma unroll
        for (int u = 0; u < 4; ++u) {
            int j = jidx[(ty * 4 + u) * KNN + k];
            float bvv[4];
            if (!readBf16) {
                float4 g = *(const float4*)
                    ((const float*)Bp + (size_t)j * ldB + obB + tx * 4);
                bvv[0] = g.x; bvv[1] = g.y; bvv[2] = g.z; bvv[3] = g.w;
            } else {
                ushort4 g = *(const ushort4*)
                    ((const unsigned short*)Bp + (size_t)j * ldB + obB + tx * 4);
                bvv[0] = u2f(g.x); bvv[1] = u2f(g.y);
                bvv[2] = u2f(g.z); bvv[3] = u2f(g.w);
            }
#pragma unroll
            for (int v = 0; v < 4; ++v) {
                float z = zA[u][v] + bvv[v] + cbs[v];
                float y = fmaf(z, gs[v], bts[v]);
                float ge = 0.5f * y * (1.0f + erff(y * 0.70710678118654752f));
                best[u][v] = fmaxf(best[u][v], ge);
            }
        }
    }

#pragma unroll
    for (int v = 0; v < 4; ++v) {
        int o = o0 + tx * 4 + v;
        float4 pk = {best[0][v], best[1][v], best[2][v], best[3][v]};
        *(float4*)(out + ((size_t)(b * CO_ + o)) * NPT + n0 + ty * 4) = pk;
    }
}

// ---------------------------------------------------------------------------
// K6: generate edge plane1 (center indices) last.
// ---------------------------------------------------------------------------
__global__ __launch_bounds__(256) void k_center(float* __restrict__ e1)
{
    int p = blockIdx.x * 256 + threadIdx.x;
    if (p >= NROWS * KNN) return;
    e1[p] = (float)((p / KNN) % NPT);
}

// ---------------------------------------------------------------------------
extern "C" void kernel_launch(void* const* d_in, const int* in_sizes, int n_in,
                              void* d_out, int out_size, void* d_ws, size_t ws_size,
                              hipStream_t stream)
{
    const float* x   = (const float*)d_in[0];
    const float* cw  = (const float*)d_in[1];
    const float* cb  = (const float*)d_in[2];
    const float* gam = (const float*)d_in[3];
    const float* bet = (const float*)d_in[4];

    // d_out: FLOAT32. out0 = floats [0, 4,816,896); e0 = [4,816,896,
    // 4,929,792); e1 = [4,929,792, 5,042,688).
    // Scratch liveness:
    //   head:   invn64/sqd/invn32/cand  bytes [0, 1,856,512)        dead@refine
    //   packed: fp16 MFMA fragments     bytes [1,856,512, 6,673,408) dead@gemm
    //   nrm32:  fp32 norms              bytes [6,673,408, 6,723,584) dead@gemm
    //   wpk:    fp16 weight fragments   bytes [6,723,584, 7,018,496) dead@gemm
    //   xT:     fp32 transposed x       bytes [9,633,792, 19,267,584) dead@refine
    float* ou   = (float*)d_out;
    float* out0 = ou;
    double* invn64 = (double*)d_out;
    double* sqd    = (double*)((char*)d_out + 100352);
    float*  invn32 = (float*)((char*)d_out + 200704);
    unsigned short* cand =
        (unsigned short*)((char*)d_out + 250880);          // 1,605,632 B
    _Float16* packed = (_Float16*)(ou + 464128);           // 4,816,896 B
    float*    nrm32  = (float*)((char*)d_out + 6673408);   //    50,176 B
    _Float16* wpk    = (_Float16*)((char*)d_out + 6723584);//   294,912 B
    float* xT = ou + 2408448;                              // 9.63 MB
    float* e0 = ou + 4816896;
    float* e1 = ou + 4929792;

    k_norm       <<<NROWS / 64, 256, 0, stream>>>(x, invn32, invn64, sqd, nrm32);
    k_xpose      <<<B_ * 6 * 98, 256, 0, stream>>>(x, xT, invn32, packed);
    k_screen_mfma<<<7 * B_ * 49, 256, 0, stream>>>(packed, cand);
    k_refine     <<<NROWS / 4, 256, 0, stream>>>(xT, invn64, sqd, cand, e0);

    const size_t BH_BYTES = (size_t)NROWS * 384 * 2;   //  9,633,792 bf16 B
    const size_t ZF_BYTES = (size_t)NROWS * 384 * 4;   // 19,267,584 fp32 zA
    const int    BSTRIDE  = NPT * CO_ * 4;             // fp32 batch-B stride

    if (ws_size >= BH_BYTES + ZF_BYTES) {
        // FAST PATH: MFMA dual GEMM from normalized fragments + rescale.
        unsigned short* wsB = (unsigned short*)d_ws;
        float* wsZ = (float*)((char*)d_ws + BH_BYTES);
        k_wpack    <<<72, 256, 0, stream>>>(cw, wpk);
        k_gemm_mfma<<<784, 256, 0, stream>>>(packed, wpk, nrm32, cb, wsB, wsZ);
        k_out2     <<<B_ * 49 * 6, 256, 0, stream>>>(e0, gam, bet, out0,
                                                     wsB, wsZ);
    } else if (ws_size >= ZF_BYTES) {
        // MEDIUM: all-batch fp32 B in d_ws, fused epilogue.
        k_gemmB<<<B_ * 49 * 6, 256, 0, stream>>>(
            x, cw, d_ws, 0, 0, 384, 0, 6, BSTRIDE);
        k_outA <<<B_ * 49 * 6, 256, 0, stream>>>(
            x, cw, e0, cb, gam, bet, out0, (const void*)d_ws,
            0, 0, 0, 384, 0, 6, BSTRIDE);
    } else {
        // FALLBACK: d_out aliasing discipline (R3-proven numerics).
        k_gemmB<<<2 * 49 * 6, 256, 0, stream>>>(
            x, cw, (void*)ou, 2, 0, 384, 0, 6, BSTRIDE);
        k_outA <<<2 * 49 * 6, 256, 0, stream>>>(
            x, cw, e0, cb, gam, bet, out0, (const void*)ou,
            2, 0, 0, 384, 0, 6, BSTRIDE);
        k_gemmB<<<49 * 6, 256, 0, stream>>>(
            x, cw, (void*)ou, 1, 0, 384, 0, 6, 0);
        k_outA <<<49 * 6, 256, 0, stream>>>(
            x, cw, e0, cb, gam, bet, out0, (const void*)ou,
            1, 0, 0, 384, 0, 6, 0);
        k_gemmB<<<49 * 3, 256, 0, stream>>>(
            x, cw, (void*)ou, 0, 192, 192, 1, 3, 0);
        k_outA <<<49 * 3, 256, 0, stream>>>(
            x, cw, e0, cb, gam, bet, out0, (const void*)ou,
            0, 192, 192, 192, 1, 3, 0);
        k_gemmB<<<49 * 2, 256, 0, stream>>>(
            x, cw, (void*)ou, 0, 64, 128, 1, 2, 0);
        k_outA <<<49 * 2, 256, 0, stream>>>(
            x, cw, e0, cb, gam, bet, out0, (const void*)ou,
            0, 64, 64, 128, 1, 2, 0);
        k_gemmB<<<49 * 1, 256, 0, stream>>>(
            x, cw, (void*)e1, 0, 0, 64, 1, 1, 0);
        k_outA <<<49 * 1, 256, 0, stream>>>(
            x, cw, e0, cb, gam, bet, out0, (const void*)e1,
            0, 0, 0, 64, 1, 1, 0);
    }
    // Generate e1 (center plane) last.
    k_center<<<(NROWS * KNN + 255) / 256, 256, 0, stream>>>(e1);
}

// Round 11
// 188.489 us; speedup vs baseline: 4.8689x; 1.1010x over previous
//
#include <hip/hip_runtime.h>
#include <hip/hip_bf16.h>
#include <math.h>

#define B_    4
#define C_    192
#define NPT   3136          // H*W points per batch
#define CO_   384           // Cout
#define KNN   9
#define K2    24            // exact-refine set size (approx-top-24 of 63)
#define NROWS (B_*NPT)      // 12544 total points
#define SD    10            // per-lane screening stream depth

typedef _Float16 half8 __attribute__((ext_vector_type(8)));
typedef float    f32x4 __attribute__((ext_vector_type(4)));

__device__ __forceinline__ float u2f(unsigned short u) {
    unsigned int t = ((unsigned int)u) << 16;
    float f; __builtin_memcpy(&f, &t, 4); return f;
}
__device__ __forceinline__ unsigned short f2u(float f) {
    __hip_bfloat16 h = __float2bfloat16(f);
    unsigned short u; __builtin_memcpy(&u, &h, 2); return u;
}
__device__ __forceinline__ float gelu_exact(float y) {
    return 0.5f * y * (1.0f + erff(y * 0.70710678118654752f));
}
// sortable u64 key for an f64 (ascending double order == ascending u64 order)
__device__ __forceinline__ unsigned long long dkey(double d) {
    long long sb = __double_as_longlong(d);
    unsigned long long u = (unsigned long long)sb;
    return (sb < 0) ? ~u : (u | 0x8000000000000000ULL);
}

// ---------------------------------------------------------------------------
// K1 v3: per-point f64 norm stats (+ fp32 norm for MFMA rescale).
// ---------------------------------------------------------------------------
__global__ __launch_bounds__(256) void k_norm(
    const float* __restrict__ x,
    float* __restrict__ invn32, double* __restrict__ invn64,
    double* __restrict__ sqd, float* __restrict__ nrm32)
{
    __shared__ double part[4][64];
    int wave = threadIdx.x >> 6, lane = threadIdx.x & 63;
    int p0 = blockIdx.x * 64;          // 64 points per block, 196 blocks
    int row = p0 + lane;
    int b = row / NPT, n = row % NPT;
    const float* xb = x + (size_t)b * C_ * NPT + n;
    double S = 0.0;
    int c0 = wave * 48;
    for (int c = c0; c < c0 + 48; ++c) {
        double v = (double)xb[(size_t)c * NPT];
        S = fma(v, v, S);
    }
    part[wave][lane] = S;
    __syncthreads();
    if (threadIdx.x < 64) {
        double T = ((part[0][lane] + part[1][lane]) + part[2][lane])
                 + part[3][lane];
        double nrm = sqrt(T);
        if (nrm < 1e-12) nrm = 1e-12;
        double iv = 1.0 / nrm;
        int prow = p0 + lane;
        invn64[prow] = iv;
        invn32[prow] = (float)iv;
        sqd[prow] = iv * iv * T;
        nrm32[prow] = (float)nrm;
    }
}

// ---------------------------------------------------------------------------
// K1b v2: LDS-tiled transpose x -> xT (fp32, exact) + fused fp16 pack.
// ---------------------------------------------------------------------------
__global__ __launch_bounds__(256) void k_xpose(
    const float* __restrict__ x, float* __restrict__ xT,
    const float* __restrict__ invn32, _Float16* __restrict__ packed)
{
    __shared__ float t[32][33];
    int blk = blockIdx.x;
    int b  = blk / 588;
    int r  = blk % 588;
    int ct = r / 98, nt = r % 98;
    int c0 = ct * 32, n0 = nt * 32;
    int tid = threadIdx.x;
    int tx = tid & 31, ty8 = tid >> 5;          // 8 rows per pass
    const float* xb = x + (size_t)b * C_ * NPT;
#pragma unroll
    for (int e = 0; e < 4; ++e) {
        int cc = ty8 + e * 8;
        t[cc][tx] = xb[(size_t)(c0 + cc) * NPT + n0 + tx];
    }
    __syncthreads();
#pragma unroll
    for (int e = 0; e < 4; ++e) {
        int nn = ty8 + e * 8;
        xT[(size_t)(b * NPT + n0 + nn) * C_ + c0 + tx] = t[tx][nn];
    }
    if (tid < 128) {
        int f = tid >> 6, l = tid & 63;
        int pt = f * 16 + (l & 15);            // tile-local point
        float iv = invn32[(size_t)b * NPT + n0 + pt];
        int cb = (l >> 4) * 8;                 // tile-local channel base
        half8 h;
#pragma unroll
        for (int e = 0; e < 8; ++e)
            h[e] = (_Float16)(t[cb + e][pt] * iv);
        size_t idx = ((((size_t)(b * 196 + nt * 2 + f)) * 6 + ct) * 64 + l) * 8;
        *(half8*)(packed + idx) = h;
    }
}

// ---------------------------------------------------------------------------
// K1d: pack weights into MFMA A-fragments (fp16), once.
// ---------------------------------------------------------------------------
__global__ __launch_bounds__(256) void k_wpack(
    const float* __restrict__ cw, _Float16* __restrict__ wpk)
{
    int t = blockIdx.x * 256 + threadIdx.x;   // 48*6*64 = 18432
    if (t >= 48 * 6 * 64) return;
    int l  = t & 63;
    int tk = t >> 6;            // ot*6+kk
    int kk = tk % 6, ot = tk / 6;
    int hsel = ot / 24;
    int o = (ot % 24) * 16 + (l & 15);
    int k = kk * 32 + (l >> 4) * 8;
    half8 h;
#pragma unroll
    for (int e = 0; e < 8; ++e) {
        float w2 = cw[(size_t)o * 384 + C_ + k + e];
        float wv = hsel ? w2 : (cw[(size_t)o * 384 + k + e] - w2);
        h[e] = (_Float16)wv;
    }
    *(half8*)(wpk + (size_t)t * 8) = h;
}

// ---------------------------------------------------------------------------
// K2 (MFMA v4): 7 uniform j-chunks, top-9 per chunk, WRITES FULL u32 KEYS
//   (key = scorebits & ~0xFFF | jj): refine reuses the approx scores to
//   shrink the exact-refine set. Slot 63 = sentinel key 0.
// ---------------------------------------------------------------------------
__global__ __launch_bounds__(256) void k_screen_mfma(
    const _Float16* __restrict__ packed, unsigned* __restrict__ cand)
{
    __shared__ unsigned md[64][4 * SD + 1];   // stride 41
    int blk   = blockIdx.x;
    int chunk = blk / 196;               // 0..6
    int t2    = blk % 196;
    int b     = t2 / 49;
    int itile = t2 % 49;                 // 64-row i tile
    int tid   = threadIdx.x;
    int wave  = tid >> 6, lane = tid & 63;
    int it    = itile * 4 + wave;        // global 16-row tile within batch

    const _Float16* pb = packed + ((size_t)(b * 196 + it) * 6) * 512 + lane * 8;
    half8 bf[6];
#pragma unroll
    for (int kk = 0; kk < 6; ++kk)
        bf[kk] = *(const half8*)(pb + kk * 512);

    int jt0 = chunk * 28;                 // 7 chunks x 28 tiles (uniform)
    const int ntj = 28;

    unsigned bd[SD];
#pragma unroll
    for (int q = 0; q < SD; ++q) bd[q] = 0u;

    const _Float16* pa_base =
        packed + ((size_t)(b * 196 + jt0) * 6) * 512 + lane * 8;

    half8 af[6];
#pragma unroll
    for (int kk = 0; kk < 6; ++kk)
        af[kk] = *(const half8*)(pa_base + kk * 512);

    for (int jt = 0; jt < ntj; ++jt) {
        f32x4 acc = {0.f, 0.f, 0.f, 0.f};
#pragma unroll
        for (int kk = 0; kk < 6; ++kk)
            acc = __builtin_amdgcn_mfma_f32_16x16x32_f16(af[kk], bf[kk], acc, 0, 0, 0);

        if (jt + 1 < ntj) {
            const _Float16* pn = pa_base + (size_t)(jt + 1) * 6 * 512;
#pragma unroll
            for (int kk = 0; kk < 6; ++kk)
                af[kk] = *(const half8*)(pn + kk * 512);
        }

        unsigned jb = (unsigned)((jt0 + jt) * 16 + (lane >> 4) * 4);
#pragma unroll
        for (int q = 0; q < 4; ++q) {
            float s = acc[q] + 2.0f;
            unsigned fb = __float_as_uint(s);
            unsigned c = (fb & 0xFFFFF000u) | (jb + (unsigned)q);
#pragma unroll
            for (int t = 0; t < SD; ++t) {
                unsigned old = bd[t];
                unsigned mx = old > c ? old : c;    // v_max_u32
                c           = old > c ? c : old;    // v_min_u32
                bd[t] = mx;
            }
        }
    }

    int ir = wave * 16 + (lane & 15);    // i-row within block (0..63)
    int g  = lane >> 4;                  // stream id
#pragma unroll
    for (int q = 0; q < SD; ++q) md[ir][g * SD + q] = bd[q];
    __syncthreads();

    if (tid < 64) {
        int h[4] = {0, 0, 0, 0};
        size_t rowi = (size_t)b * NPT + itile * 64 + tid;
        unsigned* cp = cand + rowi * 64 + chunk * 9;
        const unsigned* rd = &md[tid][0];
        for (int s = 0; s < 9; ++s) {
            unsigned best = 0u; int bg = 0;
#pragma unroll
            for (int g2 = 0; g2 < 4; ++g2) {
                unsigned v = (h[g2] < SD) ? rd[g2 * SD + h[g2]] : 0u;
                if (v > best) { best = v; bg = g2; }
            }
            cp[s] = best;
            h[bg]++;
        }
        if (chunk == 0)                   // sentinel slot 63: key 0
            cand[rowi * 64 + 63] = 0u;
    }
}

// ---------------------------------------------------------------------------
// K3 v6: key-merge + exact f64 refine on approx-top-K2 only.
//   Preamble: rank 64 stored u32 keys (distinct: index in low 12 bits;
//   sentinel 0 ranks last); lanes with keyrank<K2 compact into icand.
//   Then the proven pipelined f64 dot (3 rounds of 8 lane-groups) and the
//   exact-key rank-9 emit. Identical output whenever true-top-9 is within
//   approx-top-24 (error 1.5e-3 << needed 15 simultaneous band-crossings).
// ---------------------------------------------------------------------------
__global__ __launch_bounds__(256) void k_refine(
    const float* __restrict__ xT, const double* __restrict__ invn64,
    const double* __restrict__ sqd, const unsigned* __restrict__ cand32,
    float* __restrict__ e0)
{
    __shared__ unsigned km[4][64];
    __shared__ int    icand[4][K2];
    __shared__ double civ[4][K2];
    __shared__ double csq[4][K2];
    __shared__ unsigned long long kbuf[4][K2];
    __shared__ float  xi[4][C_];
    int wave = threadIdx.x >> 6;
    int lane = threadIdx.x & 63;
    int row  = blockIdx.x * 4 + wave;
    int b    = row / NPT;
    size_t bN = (size_t)b * NPT;

    unsigned kc = cand32[(size_t)row * 64 + lane];
    km[wave][lane] = kc;
    const float* xiRow = xT + (size_t)row * C_;
    xi[wave][lane]       = xiRow[lane];
    xi[wave][lane + 64]  = xiRow[lane + 64];
    xi[wave][lane + 128] = xiRow[lane + 128];
    __syncthreads();

    // approx rank (descending key); keys distinct -> permutation 0..63
    int keyrank = 0;
#pragma unroll
    for (int m = 0; m < 64; ++m)
        keyrank += (km[wave][m] > kc) ? 1 : 0;
    if (keyrank < K2)
        icand[wave][keyrank] = (int)(kc & 0xFFFu);
    __syncthreads();
    if (lane < K2) {
        int j = icand[wave][lane];
        civ[wave][lane] = invn64[bN + j];
        csq[wave][lane] = sqd[bN + j];
    }
    __syncthreads();

    int sub = lane & 7, cg = lane >> 3;
    double ivi = invn64[row], sqi = sqd[row];
    const float* xw = &xi[wave][sub * 4];

    // prologue: first half of candidate cg
    float4 h0a, h0b, h0c;
    {
        int j0 = icand[wave][cg];
        const float* p = xT + (bN + j0) * C_ + sub * 4;
        h0a = *(const float4*)&p[0];
        h0b = *(const float4*)&p[32];
        h0c = *(const float4*)&p[64];
    }

#pragma unroll
    for (int cc = 0; cc < K2 / 8; ++cc) {
        int cidx = cc * 8 + cg;
        int jcur = icand[wave][cidx];
        const float* pc = xT + (bN + jcur) * C_ + sub * 4;
        // issue second-half loads of current candidate
        float4 h1a = *(const float4*)&pc[96];
        float4 h1b = *(const float4*)&pc[128];
        float4 h1c = *(const float4*)&pc[160];

        double d0 = 0.0, d1 = 0.0, d2 = 0.0, d3 = 0.0;
        {
            float4 xq;
            xq = *(const float4*)&xw[0];
            d0 = fma((double)xq.x, (double)h0a.x, d0);
            d1 = fma((double)xq.y, (double)h0a.y, d1);
            d2 = fma((double)xq.z, (double)h0a.z, d2);
            d3 = fma((double)xq.w, (double)h0a.w, d3);
            xq = *(const float4*)&xw[32];
            d0 = fma((double)xq.x, (double)h0b.x, d0);
            d1 = fma((double)xq.y, (double)h0b.y, d1);
            d2 = fma((double)xq.z, (double)h0b.z, d2);
            d3 = fma((double)xq.w, (double)h0b.w, d3);
            xq = *(const float4*)&xw[64];
            d0 = fma((double)xq.x, (double)h0c.x, d0);
            d1 = fma((double)xq.y, (double)h0c.y, d1);
            d2 = fma((double)xq.z, (double)h0c.z, d2);
            d3 = fma((double)xq.w, (double)h0c.w, d3);
        }
        // prefetch first half of NEXT candidate into the freed h0 regs
        if (cc < K2 / 8 - 1) {
            int jn = icand[wave][cidx + 8];
            const float* pn = xT + (bN + jn) * C_ + sub * 4;
            h0a = *(const float4*)&pn[0];
            h0b = *(const float4*)&pn[32];
            h0c = *(const float4*)&pn[64];
        }
        {
            float4 xq;
            xq = *(const float4*)&xw[96];
            d0 = fma((double)xq.x, (double)h1a.x, d0);
            d1 = fma((double)xq.y, (double)h1a.y, d1);
            d2 = fma((double)xq.z, (double)h1a.z, d2);
            d3 = fma((double)xq.w, (double)h1a.w, d3);
            xq = *(const float4*)&xw[128];
            d0 = fma((double)xq.x, (double)h1b.x, d0);
            d1 = fma((double)xq.y, (double)h1b.y, d1);
            d2 = fma((double)xq.z, (double)h1b.z, d2);
            d3 = fma((double)xq.w, (double)h1b.w, d3);
            xq = *(const float4*)&xw[160];
            d0 = fma((double)xq.x, (double)h1c.x, d0);
            d1 = fma((double)xq.y, (double)h1c.y, d1);
            d2 = fma((double)xq.z, (double)h1c.z, d2);
            d3 = fma((double)xq.w, (double)h1c.w, d3);
        }
        double dot = (d0 + d1) + (d2 + d3);
        dot += __shfl_xor(dot, 1);
        dot += __shfl_xor(dot, 2);
        dot += __shfl_xor(dot, 4);
        if (sub == 0) {
            double dist = sqi + csq[wave][cidx]
                        - 2.0 * (ivi * civ[wave][cidx] * dot);
            kbuf[wave][cidx] = dkey(dist);
        }
    }
    __syncthreads();

    // exact rank-based top-9 over the K2 refined candidates
    if (lane < K2) {
        unsigned long long kd = kbuf[wave][lane];
        int jme = icand[wave][lane];
        int rank = 0;
#pragma unroll
        for (int m = 0; m < K2; ++m) {
            unsigned long long km2 = kbuf[wave][m];
            int jm = icand[wave][m];
            rank += ((km2 < kd) || (km2 == kd && jm < jme)) ? 1 : 0;
        }
        if (rank < KNN)
            e0[(size_t)row * KNN + rank] = (float)jme;
    }
}

// ---------------------------------------------------------------------------
// K4c: MFMA dual GEMM (fast path). packed = normalized fp16 B operand;
//   per-point norm rescale on D (lane holds one point: col = lane&15).
// ---------------------------------------------------------------------------
__global__ __launch_bounds__(256) void k_gemm_mfma(
    const _Float16* __restrict__ packed, const _Float16* __restrict__ wpk,
    const float* __restrict__ nrm32, const float* __restrict__ cb,
    unsigned short* __restrict__ Bh, float* __restrict__ Zf)
{
    int pt   = blockIdx.x;              // 0..783 global 16-point tile
    int wave = threadIdx.x >> 6, lane = threadIdx.x & 63;
    int hsel = wave >> 1;               // 0: Zf, 1: Bh
    int og   = wave & 1;                // o half within 384

    const _Float16* px = packed + (size_t)pt * 6 * 512 + lane * 8;
    half8 pf[6];
#pragma unroll
    for (int kk = 0; kk < 6; ++kk) pf[kk] = *(const half8*)(px + kk * 512);

    float s = nrm32[pt * 16 + (lane & 15)];
    size_t row0 = (size_t)pt * 16 + (lane & 15);
    int olane = (lane >> 4) * 4;

    int ot0 = hsel * 24 + og * 12;
    const _Float16* wb = wpk + (size_t)ot0 * 6 * 512 + lane * 8;

    half8 wf[6];
#pragma unroll
    for (int kk = 0; kk < 6; ++kk) wf[kk] = *(const half8*)(wb + kk * 512);

    for (int t = 0; t < 12; ++t) {
        f32x4 acc = {0.f, 0.f, 0.f, 0.f};
#pragma unroll
        for (int kk = 0; kk < 6; ++kk)
            acc = __builtin_amdgcn_mfma_f32_16x16x32_f16(wf[kk], pf[kk], acc, 0, 0, 0);

        if (t < 11) {
            const _Float16* wn = wb + (size_t)(t + 1) * 6 * 512;
#pragma unroll
            for (int kk = 0; kk < 6; ++kk)
                wf[kk] = *(const half8*)(wn + kk * 512);
        }

        int o = (og * 12 + t) * 16 + olane;
        if (hsel == 0) {
            float4 cbv = *(const float4*)&cb[o];
            float4 zv;
            zv.x = acc[0] * s + cbv.x; zv.y = acc[1] * s + cbv.y;
            zv.z = acc[2] * s + cbv.z; zv.w = acc[3] * s + cbv.w;
            *(float4*)&Zf[row0 * 384 + o] = zv;
        } else {
            ushort4 pk;
            pk.x = f2u(acc[0] * s); pk.y = f2u(acc[1] * s);
            pk.z = f2u(acc[2] * s); pk.w = f2u(acc[3] * s);
            *(ushort4*)&Bh[row0 * 384 + o] = pk;
        }
    }
}

// ---------------------------------------------------------------------------
// K5b v3: gather epilogue, quasiconvex-GELU; also emits its slice of e1
//   (center plane) — k_center folded in for the fast path.
// ---------------------------------------------------------------------------
__global__ __launch_bounds__(256) void k_out2(
    const float* __restrict__ e0, const float* __restrict__ gam,
    const float* __restrict__ bet, float* __restrict__ out,
    const unsigned short* __restrict__ Bh, const float* __restrict__ Zf,
    float* __restrict__ e1)
{
    __shared__ int jidx[64 * KNN];
    int blk = blockIdx.x;
    int b   = blk / 294;
    int r   = blk % 294;
    int nt  = r % 49, ot = r / 49;
    int n0 = nt * 64, o0 = ot * 64;
    int tid = threadIdx.x;
    int tx = tid & 15, ty = tid >> 4;

    for (int e = tid; e < 64 * KNN; e += 256)
        jidx[e] = (int)e0[((size_t)b * NPT + n0 + e / KNN) * KNN + e % KNN];

    // e1 tail: 1176 blocks x 96 = 112,896 elements, disjoint slices
    {
        int p = blk * 96 + tid;
        if (tid < 96) e1[p] = (float)((p / KNN) % NPT);
    }

    const float inv_s = 0.9999950000374997f;  // 1/sqrt(1+1e-5)
    float gs[4], bts[4];
#pragma unroll
    for (int v = 0; v < 4; ++v) {
        int o = o0 + tx * 4 + v;
        gs[v]  = gam[o] * inv_s;
        bts[v] = bet[o];
    }
    __syncthreads();

    float best[4][4];
#pragma unroll
    for (int u = 0; u < 4; ++u) {
        float4 z = *(const float4*)
            &Zf[(size_t)(b * NPT + n0 + ty * 4 + u) * 384 + o0 + tx * 4];
        float zA[4] = {z.x, z.y, z.z, z.w};

        float ymin[4], ymax[4];
#pragma unroll
        for (int v = 0; v < 4; ++v) { ymin[v] = 1e30f; ymax[v] = -1e30f; }

        const int* jr = &jidx[(ty * 4 + u) * KNN];
#pragma unroll
        for (int k = 0; k < KNN; ++k) {
            int j = jr[k];
            ushort4 g = *(const ushort4*)
                &Bh[(size_t)(b * NPT + j) * 384 + o0 + tx * 4];
            float bvv[4] = {u2f(g.x), u2f(g.y), u2f(g.z), u2f(g.w)};
#pragma unroll
            for (int v = 0; v < 4; ++v) {
                float y = fmaf(zA[v] + bvv[v], gs[v], bts[v]);
                ymin[v] = fminf(ymin[v], y);
                ymax[v] = fmaxf(ymax[v], y);
            }
        }
#pragma unroll
        for (int v = 0; v < 4; ++v)
            best[u][v] = fmaxf(gelu_exact(ymin[v]), gelu_exact(ymax[v]));
    }

#pragma unroll
    for (int v = 0; v < 4; ++v) {
        int o = o0 + tx * 4 + v;
        float4 pk = {best[0][v], best[1][v], best[2][v], best[3][v]};
        *(float4*)(out + ((size_t)(b * CO_ + o)) * NPT + n0 + ty * 4) = pk;
    }
}

// ---------------------------------------------------------------------------
// K4: B = W2 * x (fallback path, multi-batch).
// ---------------------------------------------------------------------------
__global__ __launch_bounds__(256) void k_gemmB(
    const float* __restrict__ x, const float* __restrict__ cw,
    void* __restrict__ Bq, int bbase, int bcol0, int ldB, int storeBf16,
    int botiles, int bstrideBytes)
{
    int per = 49 * botiles;
    int blk = blockIdx.x;
    int bi  = blk / per;
    int r   = blk % per;
    int b   = bbase + bi;
    int bm = r % 49;
    int bo = r / 49;
    int m0 = bm * 64;
    char* Bp = (char*)Bq + (size_t)bi * (size_t)bstrideBytes;

    __shared__ float Xt[16][68];
    __shared__ float Wt[16][68];
    int tid = threadIdx.x;
    int tx = tid & 15, ty = tid >> 4;
    const float* xb = x + (size_t)b * C_ * NPT;
    float acc[4][4];
#pragma unroll
    for (int u = 0; u < 4; ++u)
#pragma unroll
        for (int v = 0; v < 4; ++v) acc[u][v] = 0.f;

    for (int ct = 0; ct < 12; ++ct) {
        int c0 = ct * 16;
        {
            int cc = tid >> 4, n4 = (tid & 15) * 4;
            *(float4*)&Xt[cc][n4] =
                *(const float4*)&xb[(size_t)(c0 + cc) * NPT + m0 + n4];
        }
        {
            int oo = tid >> 2, c4 = (tid & 3) * 4;
            int o = bcol0 + bo * 64 + oo;
            float4 w = *(const float4*)&cw[(size_t)o * 384 + C_ + c0 + c4];
            Wt[c4 + 0][oo] = w.x; Wt[c4 + 1][oo] = w.y;
            Wt[c4 + 2][oo] = w.z; Wt[c4 + 3][oo] = w.w;
        }
        __syncthreads();
#pragma unroll
        for (int cc = 0; cc < 16; ++cc) {
            float4 av = *(const float4*)&Xt[cc][ty * 4];
            float4 bv = *(const float4*)&Wt[cc][tx * 4];
            float a_[4] = {av.x, av.y, av.z, av.w};
            float b_[4] = {bv.x, bv.y, bv.z, bv.w};
#pragma unroll
            for (int u = 0; u < 4; ++u)
#pragma unroll
                for (int v = 0; v < 4; ++v)
                    acc[u][v] = fmaf(a_[u], b_[v], acc[u][v]);
        }
        __syncthreads();
    }
    if (!storeBf16) {
        float* Bf = (float*)Bp;
#pragma unroll
        for (int u = 0; u < 4; ++u) {
            float4 pk = {acc[u][0], acc[u][1], acc[u][2], acc[u][3]};
            *(float4*)&Bf[(size_t)(m0 + ty * 4 + u) * ldB + bo * 64 + tx * 4] = pk;
        }
    } else {
        unsigned short* Bh = (unsigned short*)Bp;
#pragma unroll
        for (int u = 0; u < 4; ++u) {
            ushort4 pk;
            pk.x = f2u(acc[u][0]); pk.y = f2u(acc[u][1]);
            pk.z = f2u(acc[u][2]); pk.w = f2u(acc[u][3]);
            *(ushort4*)&Bh[(size_t)(m0 + ty * 4 + u) * ldB + bo * 64 + tx * 4] = pk;
        }
    }
}

// ---------------------------------------------------------------------------
// K5: fused epilogue (fallback path, multi-batch). Unchanged (proven).
// ---------------------------------------------------------------------------
__global__ __launch_bounds__(256) void k_outA(
    const float* __restrict__ x, const float* __restrict__ cw,
    const float* __restrict__ e0, const float* __restrict__ cb,
    const float* __restrict__ gam, const float* __restrict__ bet,
    float* __restrict__ out, const void* __restrict__ Bq,
    int bbase, int o0base, int bcol0, int ldB, int readBf16,
    int botiles, int bstrideBytes)
{
    int per = 49 * botiles;
    int blk = blockIdx.x;
    int bi  = blk / per;
    int r   = blk % per;
    int b   = bbase + bi;
    int nt = r % 49, ot = r / 49;
    int n0 = nt * 64, o0 = o0base + ot * 64;
    const char* Bp = (const char*)Bq + (size_t)bi * (size_t)bstrideBytes;

    __shared__ float Xi[16][68];
    __shared__ float Wd[16][68];
    __shared__ int jidx[64 * KNN];
    int tid = threadIdx.x;
    int tx = tid & 15, ty = tid >> 4;
    const float* xb = x + (size_t)b * C_ * NPT;

    for (int e = tid; e < 64 * KNN; e += 256)
        jidx[e] = (int)e0[((size_t)b * NPT + n0 + e / KNN) * KNN + e % KNN];

    float zA[4][4];
#pragma unroll
    for (int u = 0; u < 4; ++u)
#pragma unroll
        for (int v = 0; v < 4; ++v) zA[u][v] = 0.f;

    for (int ct = 0; ct < 12; ++ct) {
        int c0 = ct * 16;
        {
            int cc = tid >> 4, n4 = (tid & 15) * 4;
            *(float4*)&Xi[cc][n4] =
                *(const float4*)&xb[(size_t)(c0 + cc) * NPT + n0 + n4];
        }
        {
            int oo = tid >> 2, c4 = (tid & 3) * 4;
            int o = o0 + oo;
            float4 w1 = *(const float4*)&cw[(size_t)o * 384 + c0 + c4];
            float4 w2 = *(const float4*)&cw[(size_t)o * 384 + C_ + c0 + c4];
            Wd[c4 + 0][oo] = w1.x - w2.x; Wd[c4 + 1][oo] = w1.y - w2.y;
            Wd[c4 + 2][oo] = w1.z - w2.z; Wd[c4 + 3][oo] = w1.w - w2.w;
        }
        __syncthreads();
#pragma unroll
        for (int cc = 0; cc < 16; ++cc) {
            float4 av = *(const float4*)&Xi[cc][ty * 4];
            float4 bv = *(const float4*)&Wd[cc][tx * 4];
            float a_[4] = {av.x, av.y, av.z, av.w};
            float b_[4] = {bv.x, bv.y, bv.z, bv.w};
#pragma unroll
            for (int u = 0; u < 4; ++u)
#pragma unroll
                for (int v = 0; v < 4; ++v)
                    zA[u][v] = fmaf(a_[u], b_[v], zA[u][v]);
        }
        __syncthreads();
    }

    const float inv_s = 0.9999950000374997f;  // 1/sqrt(1+1e-5)
    float gs[4], bts[4], cbs[4];
#pragma unroll
    for (int v = 0; v < 4; ++v) {
        int o = o0 + tx * 4 + v;
        gs[v]  = gam[o] * inv_s;
        bts[v] = bet[o];
        cbs[v] = cb[o];
    }

    float best[4][4];
#pragma unroll
    for (int u = 0; u < 4; ++u)
#pragma unroll
        for (int v = 0; v < 4; ++v) best[u][v] = -1e30f;

    int obB = o0 - bcol0;
    for (int k = 0; k < KNN; ++k) {
#pragma unroll
        for (int u = 0; u < 4; ++u) {
            int j = jidx[(ty * 4 + u) * KNN + k];
            float bvv[4];
            if (!readBf16) {
                float4 g = *(const float4*)
                    ((const float*)Bp + (size_t)j * ldB + obB + tx * 4);
                bvv[0] = g.x; bvv[1] = g.y; bvv[2] = g.z; bvv[3] = g.w;
            } else {
                ushort4 g = *(const ushort4*)
                    ((const unsigned short*)Bp + (size_t)j * ldB + obB + tx * 4);
                bvv[0] = u2f(g.x); bvv[1] = u2f(g.y);
                bvv[2] = u2f(g.z); bvv[3] = u2f(g.w);
            }
#pragma unroll
            for (int v = 0; v < 4; ++v) {
                float z = zA[u][v] + bvv[v] + cbs[v];
                float y = fmaf(z, gs[v], bts[v]);
                float ge = 0.5f * y * (1.0f + erff(y * 0.70710678118654752f));
                best[u][v] = fmaxf(best[u][v], ge);
            }
        }
    }

#pragma unroll
    for (int v = 0; v < 4; ++v) {
        int o = o0 + tx * 4 + v;
        float4 pk = {best[0][v], best[1][v], best[2][v], best[3][v]};
        *(float4*)(out + ((size_t)(b * CO_ + o)) * NPT + n0 + ty * 4) = pk;
    }
}

// ---------------------------------------------------------------------------
// K6: generate edge plane1 (center indices) — fallback paths only.
// ---------------------------------------------------------------------------
__global__ __launch_bounds__(256) void k_center(float* __restrict__ e1)
{
    int p = blockIdx.x * 256 + threadIdx.x;
    if (p >= NROWS * KNN) return;
    e1[p] = (float)((p / KNN) % NPT);
}

// ---------------------------------------------------------------------------
extern "C" void kernel_launch(void* const* d_in, const int* in_sizes, int n_in,
                              void* d_out, int out_size, void* d_ws, size_t ws_size,
                              hipStream_t stream)
{
    const float* x   = (const float*)d_in[0];
    const float* cw  = (const float*)d_in[1];
    const float* cb  = (const float*)d_in[2];
    const float* gam = (const float*)d_in[3];
    const float* bet = (const float*)d_in[4];

    // d_out: FLOAT32. out0 = floats [0, 4,816,896); e0 = [4,816,896,
    // 4,929,792); e1 = [4,929,792, 5,042,688).
    // Scratch liveness (fast path):
    //   invn64 [0, 100,352) | sqd [100,352, 200,704) | invn32 [200,704,
    //   250,880)                                       dead@refine/gemm
    //   cand32 u32 keys  [250,880, 3,462,144)          dead@refine
    //   packed fp16      [3,462,144, 8,279,040)        dead@gemm
    //   nrm32            [8,279,040, 8,329,216)        dead@gemm
    //   wpk              [8,329,216, 8,624,128)        dead@gemm
    //   xT               [9,633,792, 19,267,584)       dead@refine
    float* ou   = (float*)d_out;
    float* out0 = ou;
    double* invn64 = (double*)d_out;
    double* sqd    = (double*)((char*)d_out + 100352);
    float*  invn32 = (float*)((char*)d_out + 200704);
    unsigned* cand32 = (unsigned*)((char*)d_out + 250880);   // 3,211,264 B
    _Float16* packed = (_Float16*)((char*)d_out + 3462144);  // 4,816,896 B
    float*    nrm32  = (float*)((char*)d_out + 8279040);     //    50,176 B
    _Float16* wpk    = (_Float16*)((char*)d_out + 8329216);  //   294,912 B
    float* xT = ou + 2408448;                                // 9.63 MB
    float* e0 = ou + 4816896;
    float* e1 = ou + 4929792;

    k_norm       <<<NROWS / 64, 256, 0, stream>>>(x, invn32, invn64, sqd, nrm32);
    k_xpose      <<<B_ * 6 * 98, 256, 0, stream>>>(x, xT, invn32, packed);
    k_screen_mfma<<<7 * B_ * 49, 256, 0, stream>>>(packed, cand32);
    k_refine     <<<NROWS / 4, 256, 0, stream>>>(xT, invn64, sqd, cand32, e0);

    const size_t BH_BYTES = (size_t)NROWS * 384 * 2;   //  9,633,792 bf16 B
    const size_t ZF_BYTES = (size_t)NROWS * 384 * 4;   // 19,267,584 fp32 zA
    const int    BSTRIDE  = NPT * CO_ * 4;             // fp32 batch-B stride

    if (ws_size >= BH_BYTES + ZF_BYTES) {
        // FAST PATH: MFMA dual GEMM from normalized fragments + rescale.
        unsigned short* wsB = (unsigned short*)d_ws;
        float* wsZ = (float*)((char*)d_ws + BH_BYTES);
        k_wpack    <<<72, 256, 0, stream>>>(cw, wpk);
        k_gemm_mfma<<<784, 256, 0, stream>>>(packed, wpk, nrm32, cb, wsB, wsZ);
        k_out2     <<<B_ * 49 * 6, 256, 0, stream>>>(e0, gam, bet, out0,
                                                     wsB, wsZ, e1);
    } else if (ws_size >= ZF_BYTES) {
        // MEDIUM: all-batch fp32 B in d_ws, fused epilogue.
        k_gemmB<<<B_ * 49 * 6, 256, 0, stream>>>(
            x, cw, d_ws, 0, 0, 384, 0, 6, BSTRIDE);
        k_outA <<<B_ * 49 * 6, 256, 0, stream>>>(
            x, cw, e0, cb, gam, bet, out0, (const void*)d_ws,
            0, 0, 0, 384, 0, 6, BSTRIDE);
        k_center<<<(NROWS * KNN + 255) / 256, 256, 0, stream>>>(e1);
    } else {
        // FALLBACK: d_out aliasing discipline (R3-proven numerics).
        k_gemmB<<<2 * 49 * 6, 256, 0, stream>>>(
            x, cw, (void*)ou, 2, 0, 384, 0, 6, BSTRIDE);
        k_outA <<<2 * 49 * 6, 256, 0, stream>>>(
            x, cw, e0, cb, gam, bet, out0, (const void*)ou,
            2, 0, 0, 384, 0, 6, BSTRIDE);
        k_gemmB<<<49 * 6, 256, 0, stream>>>(
            x, cw, (void*)ou, 1, 0, 384, 0, 6, 0);
        k_outA <<<49 * 6, 256, 0, stream>>>(
            x, cw, e0, cb, gam, bet, out0, (const void*)ou,
            1, 0, 0, 384, 0, 6, 0);
        k_gemmB<<<49 * 3, 256, 0, stream>>>(
            x, cw, (void*)ou, 0, 192, 192, 1, 3, 0);
        k_outA <<<49 * 3, 256, 0, stream>>>(
            x, cw, e0, cb, gam, bet, out0, (const void*)ou,
            0, 192, 192, 192, 1, 3, 0);
        k_gemmB<<<49 * 2, 256, 0, stream>>>(
            x, cw, (void*)ou, 0, 64, 128, 1, 2, 0);
        k_outA <<<49 * 2, 256, 0, stream>>>(
            x, cw, e0, cb, gam, bet, out0, (const void*)ou,
            0, 64, 64, 128, 1, 2, 0);
        k_gemmB<<<49 * 1, 256, 0, stream>>>(
            x, cw, (void*)e1, 0, 0, 64, 1, 1, 0);
        k_outA <<<49 * 1, 256, 0, stream>>>(
            x, cw, e0, cb, gam, bet, out0, (const void*)e1,
            0, 0, 0, 64, 1, 1, 0);
        k_center<<<(NROWS * KNN + 255) / 256, 256, 0, stream>>>(e1);
    }
}

// Round 12
// 184.931 us; speedup vs baseline: 4.9626x; 1.0192x over previous
//
#include <hip/hip_runtime.h>
#include <hip/hip_bf16.h>
#include <math.h>

#define B_    4
#define C_    192
#define NPT   3136          // H*W points per batch
#define CO_   384           // Cout
#define KNN   9
#define K2    16            // exact-refine set size (approx-top-16 of 63)
#define NROWS (B_*NPT)      // 12544 total points
#define SD    10            // per-list screening depth

typedef _Float16 half8 __attribute__((ext_vector_type(8)));
typedef float    f32x4 __attribute__((ext_vector_type(4)));

__device__ __forceinline__ float u2f(unsigned short u) {
    unsigned int t = ((unsigned int)u) << 16;
    float f; __builtin_memcpy(&f, &t, 4); return f;
}
__device__ __forceinline__ unsigned short f2u(float f) {
    __hip_bfloat16 h = __float2bfloat16(f);
    unsigned short u; __builtin_memcpy(&u, &h, 2); return u;
}
__device__ __forceinline__ float gelu_exact(float y) {
    return 0.5f * y * (1.0f + erff(y * 0.70710678118654752f));
}
// sortable u64 key for an f64 (ascending double order == ascending u64 order)
__device__ __forceinline__ unsigned long long dkey(double d) {
    long long sb = __double_as_longlong(d);
    unsigned long long u = (unsigned long long)sb;
    return (sb < 0) ? ~u : (u | 0x8000000000000000ULL);
}

// ---------------------------------------------------------------------------
// K1 v3: per-point f64 norm stats (+ fp32 norm for MFMA rescale).
// ---------------------------------------------------------------------------
__global__ __launch_bounds__(256) void k_norm(
    const float* __restrict__ x,
    float* __restrict__ invn32, double* __restrict__ invn64,
    double* __restrict__ sqd, float* __restrict__ nrm32)
{
    __shared__ double part[4][64];
    int wave = threadIdx.x >> 6, lane = threadIdx.x & 63;
    int p0 = blockIdx.x * 64;          // 64 points per block, 196 blocks
    int row = p0 + lane;
    int b = row / NPT, n = row % NPT;
    const float* xb = x + (size_t)b * C_ * NPT + n;
    double S = 0.0;
    int c0 = wave * 48;
    for (int c = c0; c < c0 + 48; ++c) {
        double v = (double)xb[(size_t)c * NPT];
        S = fma(v, v, S);
    }
    part[wave][lane] = S;
    __syncthreads();
    if (threadIdx.x < 64) {
        double T = ((part[0][lane] + part[1][lane]) + part[2][lane])
                 + part[3][lane];
        double nrm = sqrt(T);
        if (nrm < 1e-12) nrm = 1e-12;
        double iv = 1.0 / nrm;
        int prow = p0 + lane;
        invn64[prow] = iv;
        invn32[prow] = (float)iv;
        sqd[prow] = iv * iv * T;
        nrm32[prow] = (float)nrm;
    }
}

// ---------------------------------------------------------------------------
// K1b v2: LDS-tiled transpose x -> xT (fp32, exact) + fused fp16 pack.
// ---------------------------------------------------------------------------
__global__ __launch_bounds__(256) void k_xpose(
    const float* __restrict__ x, float* __restrict__ xT,
    const float* __restrict__ invn32, _Float16* __restrict__ packed)
{
    __shared__ float t[32][33];
    int blk = blockIdx.x;
    int b  = blk / 588;
    int r  = blk % 588;
    int ct = r / 98, nt = r % 98;
    int c0 = ct * 32, n0 = nt * 32;
    int tid = threadIdx.x;
    int tx = tid & 31, ty8 = tid >> 5;          // 8 rows per pass
    const float* xb = x + (size_t)b * C_ * NPT;
#pragma unroll
    for (int e = 0; e < 4; ++e) {
        int cc = ty8 + e * 8;
        t[cc][tx] = xb[(size_t)(c0 + cc) * NPT + n0 + tx];
    }
    __syncthreads();
#pragma unroll
    for (int e = 0; e < 4; ++e) {
        int nn = ty8 + e * 8;
        xT[(size_t)(b * NPT + n0 + nn) * C_ + c0 + tx] = t[tx][nn];
    }
    if (tid < 128) {
        int f = tid >> 6, l = tid & 63;
        int pt = f * 16 + (l & 15);            // tile-local point
        float iv = invn32[(size_t)b * NPT + n0 + pt];
        int cb = (l >> 4) * 8;                 // tile-local channel base
        half8 h;
#pragma unroll
        for (int e = 0; e < 8; ++e)
            h[e] = (_Float16)(t[cb + e][pt] * iv);
        size_t idx = ((((size_t)(b * 196 + nt * 2 + f)) * 6 + ct) * 64 + l) * 8;
        *(half8*)(packed + idx) = h;
    }
}

// ---------------------------------------------------------------------------
// K1d: pack weights into MFMA A-fragments (fp16), once.
// ---------------------------------------------------------------------------
__global__ __launch_bounds__(256) void k_wpack(
    const float* __restrict__ cw, _Float16* __restrict__ wpk)
{
    int t = blockIdx.x * 256 + threadIdx.x;   // 48*6*64 = 18432
    if (t >= 48 * 6 * 64) return;
    int l  = t & 63;
    int tk = t >> 6;            // ot*6+kk
    int kk = tk % 6, ot = tk / 6;
    int hsel = ot / 24;
    int o = (ot % 24) * 16 + (l & 15);
    int k = kk * 32 + (l >> 4) * 8;
    half8 h;
#pragma unroll
    for (int e = 0; e < 8; ++e) {
        float w2 = cw[(size_t)o * 384 + C_ + k + e];
        float wv = hsel ? w2 : (cw[(size_t)o * 384 + k + e] - w2);
        h[e] = (_Float16)wv;
    }
    *(half8*)(wpk + (size_t)t * 8) = h;
}

// ---------------------------------------------------------------------------
// K2 (MFMA v5): 7 uniform j-chunks, top-9 per chunk, u32-key output.
//   TWO independent depth-SD lists per lane (acc[0..1] -> A, acc[2..3] -> B)
//   halve the per-tile dependent CE chain (40 -> 20) so the bubble's
//   latency can be hidden at low occupancy. Merge = 8 streams x SD.
//   Stream-depth guarantee unchanged: a true top-9 has <=8 truly-better
//   points anywhere -> within depth-10 of its (56-candidate) list.
// ---------------------------------------------------------------------------
__global__ __launch_bounds__(256) void k_screen_mfma(
    const _Float16* __restrict__ packed, unsigned* __restrict__ cand)
{
    __shared__ unsigned md[64][8 * SD + 1];   // stride 81
    int blk   = blockIdx.x;
    int chunk = blk / 196;               // 0..6
    int t2    = blk % 196;
    int b     = t2 / 49;
    int itile = t2 % 49;                 // 64-row i tile
    int tid   = threadIdx.x;
    int wave  = tid >> 6, lane = tid & 63;
    int it    = itile * 4 + wave;        // global 16-row tile within batch

    const _Float16* pb = packed + ((size_t)(b * 196 + it) * 6) * 512 + lane * 8;
    half8 bf[6];
#pragma unroll
    for (int kk = 0; kk < 6; ++kk)
        bf[kk] = *(const half8*)(pb + kk * 512);

    int jt0 = chunk * 28;                 // 7 chunks x 28 tiles (uniform)
    const int ntj = 28;

    unsigned bdA[SD], bdB[SD];
#pragma unroll
    for (int q = 0; q < SD; ++q) { bdA[q] = 0u; bdB[q] = 0u; }

    const _Float16* pa_base =
        packed + ((size_t)(b * 196 + jt0) * 6) * 512 + lane * 8;

    half8 af[6];
#pragma unroll
    for (int kk = 0; kk < 6; ++kk)
        af[kk] = *(const half8*)(pa_base + kk * 512);

    for (int jt = 0; jt < ntj; ++jt) {
        f32x4 acc = {0.f, 0.f, 0.f, 0.f};
#pragma unroll
        for (int kk = 0; kk < 6; ++kk)
            acc = __builtin_amdgcn_mfma_f32_16x16x32_f16(af[kk], bf[kk], acc, 0, 0, 0);

        if (jt + 1 < ntj) {
            const _Float16* pn = pa_base + (size_t)(jt + 1) * 6 * 512;
#pragma unroll
            for (int kk = 0; kk < 6; ++kk)
                af[kk] = *(const half8*)(pn + kk * 512);
        }

        unsigned jb = (unsigned)((jt0 + jt) * 16 + (lane >> 4) * 4);
        // list A: acc[0], acc[1]   (independent chain from list B)
#pragma unroll
        for (int q = 0; q < 2; ++q) {
            unsigned fb = __float_as_uint(acc[q] + 2.0f);
            unsigned c = (fb & 0xFFFFF000u) | (jb + (unsigned)q);
#pragma unroll
            for (int t = 0; t < SD; ++t) {
                unsigned old = bdA[t];
                unsigned mx = old > c ? old : c;
                c           = old > c ? c : old;
                bdA[t] = mx;
            }
        }
        // list B: acc[2], acc[3]
#pragma unroll
        for (int q = 2; q < 4; ++q) {
            unsigned fb = __float_as_uint(acc[q] + 2.0f);
            unsigned c = (fb & 0xFFFFF000u) | (jb + (unsigned)q);
#pragma unroll
            for (int t = 0; t < SD; ++t) {
                unsigned old = bdB[t];
                unsigned mx = old > c ? old : c;
                c           = old > c ? c : old;
                bdB[t] = mx;
            }
        }
    }

    int ir = wave * 16 + (lane & 15);    // i-row within block (0..63)
    int g  = lane >> 4;                  // lane group -> streams 2g, 2g+1
#pragma unroll
    for (int q = 0; q < SD; ++q) {
        md[ir][(g * 2 + 0) * SD + q] = bdA[q];
        md[ir][(g * 2 + 1) * SD + q] = bdB[q];
    }
    __syncthreads();

    if (tid < 64) {
        int h[8] = {0, 0, 0, 0, 0, 0, 0, 0};
        size_t rowi = (size_t)b * NPT + itile * 64 + tid;
        unsigned* cp = cand + rowi * 64 + chunk * 9;
        const unsigned* rd = &md[tid][0];
        for (int s = 0; s < 9; ++s) {
            unsigned best = 0u; int bg = 0;
#pragma unroll
            for (int g2 = 0; g2 < 8; ++g2) {
                unsigned v = (h[g2] < SD) ? rd[g2 * SD + h[g2]] : 0u;
                if (v > best) { best = v; bg = g2; }
            }
            cp[s] = best;
            h[bg]++;
        }
        if (chunk == 0)                   // sentinel slot 63: key 0
            cand[rowi * 64 + 63] = 0u;
    }
}

// ---------------------------------------------------------------------------
// K3 v7: key-merge + exact f64 refine on approx-top-K2 (=16) only.
//   Preamble ranks the 64 stored u32 keys (distinct; sentinel 0 last);
//   keyrank<K2 lanes compact into icand; then the proven pipelined f64
//   dot (2 rounds of 8 lane-groups) and exact-key rank-9 emit.
// ---------------------------------------------------------------------------
__global__ __launch_bounds__(256) void k_refine(
    const float* __restrict__ xT, const double* __restrict__ invn64,
    const double* __restrict__ sqd, const unsigned* __restrict__ cand32,
    float* __restrict__ e0)
{
    __shared__ unsigned km[4][64];
    __shared__ int    icand[4][K2];
    __shared__ double civ[4][K2];
    __shared__ double csq[4][K2];
    __shared__ unsigned long long kbuf[4][K2];
    __shared__ float  xi[4][C_];
    int wave = threadIdx.x >> 6;
    int lane = threadIdx.x & 63;
    int row  = blockIdx.x * 4 + wave;
    int b    = row / NPT;
    size_t bN = (size_t)b * NPT;

    unsigned kc = cand32[(size_t)row * 64 + lane];
    km[wave][lane] = kc;
    const float* xiRow = xT + (size_t)row * C_;
    xi[wave][lane]       = xiRow[lane];
    xi[wave][lane + 64]  = xiRow[lane + 64];
    xi[wave][lane + 128] = xiRow[lane + 128];
    __syncthreads();

    // approx rank (descending key); keys distinct -> permutation 0..63
    int keyrank = 0;
#pragma unroll
    for (int m = 0; m < 64; ++m)
        keyrank += (km[wave][m] > kc) ? 1 : 0;
    if (keyrank < K2)
        icand[wave][keyrank] = (int)(kc & 0xFFFu);
    __syncthreads();
    if (lane < K2) {
        int j = icand[wave][lane];
        civ[wave][lane] = invn64[bN + j];
        csq[wave][lane] = sqd[bN + j];
    }
    __syncthreads();

    int sub = lane & 7, cg = lane >> 3;
    double ivi = invn64[row], sqi = sqd[row];
    const float* xw = &xi[wave][sub * 4];

    // prologue: first half of candidate cg
    float4 h0a, h0b, h0c;
    {
        int j0 = icand[wave][cg];
        const float* p = xT + (bN + j0) * C_ + sub * 4;
        h0a = *(const float4*)&p[0];
        h0b = *(const float4*)&p[32];
        h0c = *(const float4*)&p[64];
    }

#pragma unroll
    for (int cc = 0; cc < K2 / 8; ++cc) {
        int cidx = cc * 8 + cg;
        int jcur = icand[wave][cidx];
        const float* pc = xT + (bN + jcur) * C_ + sub * 4;
        // issue second-half loads of current candidate
        float4 h1a = *(const float4*)&pc[96];
        float4 h1b = *(const float4*)&pc[128];
        float4 h1c = *(const float4*)&pc[160];

        double d0 = 0.0, d1 = 0.0, d2 = 0.0, d3 = 0.0;
        {
            float4 xq;
            xq = *(const float4*)&xw[0];
            d0 = fma((double)xq.x, (double)h0a.x, d0);
            d1 = fma((double)xq.y, (double)h0a.y, d1);
            d2 = fma((double)xq.z, (double)h0a.z, d2);
            d3 = fma((double)xq.w, (double)h0a.w, d3);
            xq = *(const float4*)&xw[32];
            d0 = fma((double)xq.x, (double)h0b.x, d0);
            d1 = fma((double)xq.y, (double)h0b.y, d1);
            d2 = fma((double)xq.z, (double)h0b.z, d2);
            d3 = fma((double)xq.w, (double)h0b.w, d3);
            xq = *(const float4*)&xw[64];
            d0 = fma((double)xq.x, (double)h0c.x, d0);
            d1 = fma((double)xq.y, (double)h0c.y, d1);
            d2 = fma((double)xq.z, (double)h0c.z, d2);
            d3 = fma((double)xq.w, (double)h0c.w, d3);
        }
        // prefetch first half of NEXT candidate into the freed h0 regs
        if (cc < K2 / 8 - 1) {
            int jn = icand[wave][cidx + 8];
            const float* pn = xT + (bN + jn) * C_ + sub * 4;
            h0a = *(const float4*)&pn[0];
            h0b = *(const float4*)&pn[32];
            h0c = *(const float4*)&pn[64];
        }
        {
            float4 xq;
            xq = *(const float4*)&xw[96];
            d0 = fma((double)xq.x, (double)h1a.x, d0);
            d1 = fma((double)xq.y, (double)h1a.y, d1);
            d2 = fma((double)xq.z, (double)h1a.z, d2);
            d3 = fma((double)xq.w, (double)h1a.w, d3);
            xq = *(const float4*)&xw[128];
            d0 = fma((double)xq.x, (double)h1b.x, d0);
            d1 = fma((double)xq.y, (double)h1b.y, d1);
            d2 = fma((double)xq.z, (double)h1b.z, d2);
            d3 = fma((double)xq.w, (double)h1b.w, d3);
            xq = *(const float4*)&xw[160];
            d0 = fma((double)xq.x, (double)h1c.x, d0);
            d1 = fma((double)xq.y, (double)h1c.y, d1);
            d2 = fma((double)xq.z, (double)h1c.z, d2);
            d3 = fma((double)xq.w, (double)h1c.w, d3);
        }
        double dot = (d0 + d1) + (d2 + d3);
        dot += __shfl_xor(dot, 1);
        dot += __shfl_xor(dot, 2);
        dot += __shfl_xor(dot, 4);
        if (sub == 0) {
            double dist = sqi + csq[wave][cidx]
                        - 2.0 * (ivi * civ[wave][cidx] * dot);
            kbuf[wave][cidx] = dkey(dist);
        }
    }
    __syncthreads();

    // exact rank-based top-9 over the K2 refined candidates
    if (lane < K2) {
        unsigned long long kd = kbuf[wave][lane];
        int jme = icand[wave][lane];
        int rank = 0;
#pragma unroll
        for (int m = 0; m < K2; ++m) {
            unsigned long long km2 = kbuf[wave][m];
            int jm = icand[wave][m];
            rank += ((km2 < kd) || (km2 == kd && jm < jme)) ? 1 : 0;
        }
        if (rank < KNN)
            e0[(size_t)row * KNN + rank] = (float)jme;
    }
}

// ---------------------------------------------------------------------------
// K4c: MFMA dual GEMM (fast path). packed = normalized fp16 B operand;
//   per-point norm rescale on D (lane holds one point: col = lane&15).
// ---------------------------------------------------------------------------
__global__ __launch_bounds__(256) void k_gemm_mfma(
    const _Float16* __restrict__ packed, const _Float16* __restrict__ wpk,
    const float* __restrict__ nrm32, const float* __restrict__ cb,
    unsigned short* __restrict__ Bh, float* __restrict__ Zf)
{
    int pt   = blockIdx.x;              // 0..783 global 16-point tile
    int wave = threadIdx.x >> 6, lane = threadIdx.x & 63;
    int hsel = wave >> 1;               // 0: Zf, 1: Bh
    int og   = wave & 1;                // o half within 384

    const _Float16* px = packed + (size_t)pt * 6 * 512 + lane * 8;
    half8 pf[6];
#pragma unroll
    for (int kk = 0; kk < 6; ++kk) pf[kk] = *(const half8*)(px + kk * 512);

    float s = nrm32[pt * 16 + (lane & 15)];
    size_t row0 = (size_t)pt * 16 + (lane & 15);
    int olane = (lane >> 4) * 4;

    int ot0 = hsel * 24 + og * 12;
    const _Float16* wb = wpk + (size_t)ot0 * 6 * 512 + lane * 8;

    half8 wf[6];
#pragma unroll
    for (int kk = 0; kk < 6; ++kk) wf[kk] = *(const half8*)(wb + kk * 512);

    for (int t = 0; t < 12; ++t) {
        f32x4 acc = {0.f, 0.f, 0.f, 0.f};
#pragma unroll
        for (int kk = 0; kk < 6; ++kk)
            acc = __builtin_amdgcn_mfma_f32_16x16x32_f16(wf[kk], pf[kk], acc, 0, 0, 0);

        if (t < 11) {
            const _Float16* wn = wb + (size_t)(t + 1) * 6 * 512;
#pragma unroll
            for (int kk = 0; kk < 6; ++kk)
                wf[kk] = *(const half8*)(wn + kk * 512);
        }

        int o = (og * 12 + t) * 16 + olane;
        if (hsel == 0) {
            float4 cbv = *(const float4*)&cb[o];
            float4 zv;
            zv.x = acc[0] * s + cbv.x; zv.y = acc[1] * s + cbv.y;
            zv.z = acc[2] * s + cbv.z; zv.w = acc[3] * s + cbv.w;
            *(float4*)&Zf[row0 * 384 + o] = zv;
        } else {
            ushort4 pk;
            pk.x = f2u(acc[0] * s); pk.y = f2u(acc[1] * s);
            pk.z = f2u(acc[2] * s); pk.w = f2u(acc[3] * s);
            *(ushort4*)&Bh[row0 * 384 + o] = pk;
        }
    }
}

// ---------------------------------------------------------------------------
// K5b v3: gather epilogue, quasiconvex-GELU; also emits its slice of e1.
// ---------------------------------------------------------------------------
__global__ __launch_bounds__(256) void k_out2(
    const float* __restrict__ e0, const float* __restrict__ gam,
    const float* __restrict__ bet, float* __restrict__ out,
    const unsigned short* __restrict__ Bh, const float* __restrict__ Zf,
    float* __restrict__ e1)
{
    __shared__ int jidx[64 * KNN];
    int blk = blockIdx.x;
    int b   = blk / 294;
    int r   = blk % 294;
    int nt  = r % 49, ot = r / 49;
    int n0 = nt * 64, o0 = ot * 64;
    int tid = threadIdx.x;
    int tx = tid & 15, ty = tid >> 4;

    for (int e = tid; e < 64 * KNN; e += 256)
        jidx[e] = (int)e0[((size_t)b * NPT + n0 + e / KNN) * KNN + e % KNN];

    // e1 tail: 1176 blocks x 96 = 112,896 elements, disjoint slices
    {
        int p = blk * 96 + tid;
        if (tid < 96) e1[p] = (float)((p / KNN) % NPT);
    }

    const float inv_s = 0.9999950000374997f;  // 1/sqrt(1+1e-5)
    float gs[4], bts[4];
#pragma unroll
    for (int v = 0; v < 4; ++v) {
        int o = o0 + tx * 4 + v;
        gs[v]  = gam[o] * inv_s;
        bts[v] = bet[o];
    }
    __syncthreads();

    float best[4][4];
#pragma unroll
    for (int u = 0; u < 4; ++u) {
        float4 z = *(const float4*)
            &Zf[(size_t)(b * NPT + n0 + ty * 4 + u) * 384 + o0 + tx * 4];
        float zA[4] = {z.x, z.y, z.z, z.w};

        float ymin[4], ymax[4];
#pragma unroll
        for (int v = 0; v < 4; ++v) { ymin[v] = 1e30f; ymax[v] = -1e30f; }

        const int* jr = &jidx[(ty * 4 + u) * KNN];
#pragma unroll
        for (int k = 0; k < KNN; ++k) {
            int j = jr[k];
            ushort4 g = *(const ushort4*)
                &Bh[(size_t)(b * NPT + j) * 384 + o0 + tx * 4];
            float bvv[4] = {u2f(g.x), u2f(g.y), u2f(g.z), u2f(g.w)};
#pragma unroll
            for (int v = 0; v < 4; ++v) {
                float y = fmaf(zA[v] + bvv[v], gs[v], bts[v]);
                ymin[v] = fminf(ymin[v], y);
                ymax[v] = fmaxf(ymax[v], y);
            }
        }
#pragma unroll
        for (int v = 0; v < 4; ++v)
            best[u][v] = fmaxf(gelu_exact(ymin[v]), gelu_exact(ymax[v]));
    }

#pragma unroll
    for (int v = 0; v < 4; ++v) {
        int o = o0 + tx * 4 + v;
        float4 pk = {best[0][v], best[1][v], best[2][v], best[3][v]};
        *(float4*)(out + ((size_t)(b * CO_ + o)) * NPT + n0 + ty * 4) = pk;
    }
}

// ---------------------------------------------------------------------------
// K4: B = W2 * x (fallback path, multi-batch).
// ---------------------------------------------------------------------------
__global__ __launch_bounds__(256) void k_gemmB(
    const float* __restrict__ x, const float* __restrict__ cw,
    void* __restrict__ Bq, int bbase, int bcol0, int ldB, int storeBf16,
    int botiles, int bstrideBytes)
{
    int per = 49 * botiles;
    int blk = blockIdx.x;
    int bi  = blk / per;
    int r   = blk % per;
    int b   = bbase + bi;
    int bm = r % 49;
    int bo = r / 49;
    int m0 = bm * 64;
    char* Bp = (char*)Bq + (size_t)bi * (size_t)bstrideBytes;

    __shared__ float Xt[16][68];
    __shared__ float Wt[16][68];
    int tid = threadIdx.x;
    int tx = tid & 15, ty = tid >> 4;
    const float* xb = x + (size_t)b * C_ * NPT;
    float acc[4][4];
#pragma unroll
    for (int u = 0; u < 4; ++u)
#pragma unroll
        for (int v = 0; v < 4; ++v) acc[u][v] = 0.f;

    for (int ct = 0; ct < 12; ++ct) {
        int c0 = ct * 16;
        {
            int cc = tid >> 4, n4 = (tid & 15) * 4;
            *(float4*)&Xt[cc][n4] =
                *(const float4*)&xb[(size_t)(c0 + cc) * NPT + m0 + n4];
        }
        {
            int oo = tid >> 2, c4 = (tid & 3) * 4;
            int o = bcol0 + bo * 64 + oo;
            float4 w = *(const float4*)&cw[(size_t)o * 384 + C_ + c0 + c4];
            Wt[c4 + 0][oo] = w.x; Wt[c4 + 1][oo] = w.y;
            Wt[c4 + 2][oo] = w.z; Wt[c4 + 3][oo] = w.w;
        }
        __syncthreads();
#pragma unroll
        for (int cc = 0; cc < 16; ++cc) {
            float4 av = *(const float4*)&Xt[cc][ty * 4];
            float4 bv = *(const float4*)&Wt[cc][tx * 4];
            float a_[4] = {av.x, av.y, av.z, av.w};
            float b_[4] = {bv.x, bv.y, bv.z, bv.w};
#pragma unroll
            for (int u = 0; u < 4; ++u)
#pragma unroll
                for (int v = 0; v < 4; ++v)
                    acc[u][v] = fmaf(a_[u], b_[v], acc[u][v]);
        }
        __syncthreads();
    }
    if (!storeBf16) {
        float* Bf = (float*)Bp;
#pragma unroll
        for (int u = 0; u < 4; ++u) {
            float4 pk = {acc[u][0], acc[u][1], acc[u][2], acc[u][3]};
            *(float4*)&Bf[(size_t)(m0 + ty * 4 + u) * ldB + bo * 64 + tx * 4] = pk;
        }
    } else {
        unsigned short* Bh = (unsigned short*)Bp;
#pragma unroll
        for (int u = 0; u < 4; ++u) {
            ushort4 pk;
            pk.x = f2u(acc[u][0]); pk.y = f2u(acc[u][1]);
            pk.z = f2u(acc[u][2]); pk.w = f2u(acc[u][3]);
            *(ushort4*)&Bh[(size_t)(m0 + ty * 4 + u) * ldB + bo * 64 + tx * 4] = pk;
        }
    }
}

// ---------------------------------------------------------------------------
// K5: fused epilogue (fallback path, multi-batch). Unchanged (proven).
// ---------------------------------------------------------------------------
__global__ __launch_bounds__(256) void k_outA(
    const float* __restrict__ x, const float* __restrict__ cw,
    const float* __restrict__ e0, const float* __restrict__ cb,
    const float* __restrict__ gam, const float* __restrict__ bet,
    float* __restrict__ out, const void* __restrict__ Bq,
    int bbase, int o0base, int bcol0, int ldB, int readBf16,
    int botiles, int bstrideBytes)
{
    int per = 49 * botiles;
    int blk = blockIdx.x;
    int bi  = blk / per;
    int r   = blk % per;
    int b   = bbase + bi;
    int nt = r % 49, ot = r / 49;
    int n0 = nt * 64, o0 = o0base + ot * 64;
    const char* Bp = (const char*)Bq + (size_t)bi * (size_t)bstrideBytes;

    __shared__ float Xi[16][68];
    __shared__ float Wd[16][68];
    __shared__ int jidx[64 * KNN];
    int tid = threadIdx.x;
    int tx = tid & 15, ty = tid >> 4;
    const float* xb = x + (size_t)b * C_ * NPT;

    for (int e = tid; e < 64 * KNN; e += 256)
        jidx[e] = (int)e0[((size_t)b * NPT + n0 + e / KNN) * KNN + e % KNN];

    float zA[4][4];
#pragma unroll
    for (int u = 0; u < 4; ++u)
#pragma unroll
        for (int v = 0; v < 4; ++v) zA[u][v] = 0.f;

    for (int ct = 0; ct < 12; ++ct) {
        int c0 = ct * 16;
        {
            int cc = tid >> 4, n4 = (tid & 15) * 4;
            *(float4*)&Xi[cc][n4] =
                *(const float4*)&xb[(size_t)(c0 + cc) * NPT + n0 + n4];
        }
        {
            int oo = tid >> 2, c4 = (tid & 3) * 4;
            int o = o0 + oo;
            float4 w1 = *(const float4*)&cw[(size_t)o * 384 + c0 + c4];
            float4 w2 = *(const float4*)&cw[(size_t)o * 384 + C_ + c0 + c4];
            Wd[c4 + 0][oo] = w1.x - w2.x; Wd[c4 + 1][oo] = w1.y - w2.y;
            Wd[c4 + 2][oo] = w1.z - w2.z; Wd[c4 + 3][oo] = w1.w - w2.w;
        }
        __syncthreads();
#pragma unroll
        for (int cc = 0; cc < 16; ++cc) {
            float4 av = *(const float4*)&Xi[cc][ty * 4];
            float4 bv = *(const float4*)&Wd[cc][tx * 4];
            float a_[4] = {av.x, av.y, av.z, av.w};
            float b_[4] = {bv.x, bv.y, bv.z, bv.w};
#pragma unroll
            for (int u = 0; u < 4; ++u)
#pragma unroll
                for (int v = 0; v < 4; ++v)
                    zA[u][v] = fmaf(a_[u], b_[v], zA[u][v]);
        }
        __syncthreads();
    }

    const float inv_s = 0.9999950000374997f;  // 1/sqrt(1+1e-5)
    float gs[4], bts[4], cbs[4];
#pragma unroll
    for (int v = 0; v < 4; ++v) {
        int o = o0 + tx * 4 + v;
        gs[v]  = gam[o] * inv_s;
        bts[v] = bet[o];
        cbs[v] = cb[o];
    }

    float best[4][4];
#pragma unroll
    for (int u = 0; u < 4; ++u)
#pragma unroll
        for (int v = 0; v < 4; ++v) best[u][v] = -1e30f;

    int obB = o0 - bcol0;
    for (int k = 0; k < KNN; ++k) {
#pragma unroll
        for (int u = 0; u < 4; ++u) {
            int j = jidx[(ty * 4 + u) * KNN + k];
            float bvv[4];
            if (!readBf16) {
                float4 g = *(const float4*)
                    ((const float*)Bp + (size_t)j * ldB + obB + tx * 4);
                bvv[0] = g.x; bvv[1] = g.y; bvv[2] = g.z; bvv[3] = g.w;
            } else {
                ushort4 g = *(const ushort4*)
                    ((const unsigned short*)Bp + (size_t)j * ldB + obB + tx * 4);
                bvv[0] = u2f(g.x); bvv[1] = u2f(g.y);
                bvv[2] = u2f(g.z); bvv[3] = u2f(g.w);
            }
#pragma unroll
            for (int v = 0; v < 4; ++v) {
                float z = zA[u][v] + bvv[v] + cbs[v];
                float y = fmaf(z, gs[v], bts[v]);
                float ge = 0.5f * y * (1.0f + erff(y * 0.70710678118654752f));
                best[u][v] = fmaxf(best[u][v], ge);
            }
        }
    }

#pragma unroll
    for (int v = 0; v < 4; ++v) {
        int o = o0 + tx * 4 + v;
        float4 pk = {best[0][v], best[1][v], best[2][v], best[3][v]};
        *(float4*)(out + ((size_t)(b * CO_ + o)) * NPT + n0 + ty * 4) = pk;
    }
}

// ---------------------------------------------------------------------------
// K6: generate edge plane1 (center indices) — fallback paths only.
// ---------------------------------------------------------------------------
__global__ __launch_bounds__(256) void k_center(float* __restrict__ e1)
{
    int p = blockIdx.x * 256 + threadIdx.x;
    if (p >= NROWS * KNN) return;
    e1[p] = (float)((p / KNN) % NPT);
}

// ---------------------------------------------------------------------------
extern "C" void kernel_launch(void* const* d_in, const int* in_sizes, int n_in,
                              void* d_out, int out_size, void* d_ws, size_t ws_size,
                              hipStream_t stream)
{
    const float* x   = (const float*)d_in[0];
    const float* cw  = (const float*)d_in[1];
    const float* cb  = (const float*)d_in[2];
    const float* gam = (const float*)d_in[3];
    const float* bet = (const float*)d_in[4];

    // d_out: FLOAT32. out0 = floats [0, 4,816,896); e0 = [4,816,896,
    // 4,929,792); e1 = [4,929,792, 5,042,688).
    // Scratch liveness (fast path):
    //   invn64 [0, 100,352) | sqd [100,352, 200,704) | invn32 [200,704,
    //   250,880)                                       dead@refine/gemm
    //   cand32 u32 keys  [250,880, 3,462,144)          dead@refine
    //   packed fp16      [3,462,144, 8,279,040)        dead@gemm
    //   nrm32            [8,279,040, 8,329,216)        dead@gemm
    //   wpk              [8,329,216, 8,624,128)        dead@gemm
    //   xT               [9,633,792, 19,267,584)       dead@refine
    float* ou   = (float*)d_out;
    float* out0 = ou;
    double* invn64 = (double*)d_out;
    double* sqd    = (double*)((char*)d_out + 100352);
    float*  invn32 = (float*)((char*)d_out + 200704);
    unsigned* cand32 = (unsigned*)((char*)d_out + 250880);   // 3,211,264 B
    _Float16* packed = (_Float16*)((char*)d_out + 3462144);  // 4,816,896 B
    float*    nrm32  = (float*)((char*)d_out + 8279040);     //    50,176 B
    _Float16* wpk    = (_Float16*)((char*)d_out + 8329216);  //   294,912 B
    float* xT = ou + 2408448;                                // 9.63 MB
    float* e0 = ou + 4816896;
    float* e1 = ou + 4929792;

    k_norm       <<<NROWS / 64, 256, 0, stream>>>(x, invn32, invn64, sqd, nrm32);
    k_xpose      <<<B_ * 6 * 98, 256, 0, stream>>>(x, xT, invn32, packed);
    k_screen_mfma<<<7 * B_ * 49, 256, 0, stream>>>(packed, cand32);
    k_refine     <<<NROWS / 4, 256, 0, stream>>>(xT, invn64, sqd, cand32, e0);

    const size_t BH_BYTES = (size_t)NROWS * 384 * 2;   //  9,633,792 bf16 B
    const size_t ZF_BYTES = (size_t)NROWS * 384 * 4;   // 19,267,584 fp32 zA
    const int    BSTRIDE  = NPT * CO_ * 4;             // fp32 batch-B stride

    if (ws_size >= BH_BYTES + ZF_BYTES) {
        // FAST PATH: MFMA dual GEMM from normalized fragments + rescale.
        unsigned short* wsB = (unsigned short*)d_ws;
        float* wsZ = (float*)((char*)d_ws + BH_BYTES);
        k_wpack    <<<72, 256, 0, stream>>>(cw, wpk);
        k_gemm_mfma<<<784, 256, 0, stream>>>(packed, wpk, nrm32, cb, wsB, wsZ);
        k_out2     <<<B_ * 49 * 6, 256, 0, stream>>>(e0, gam, bet, out0,
                                                     wsB, wsZ, e1);
    } else if (ws_size >= ZF_BYTES) {
        // MEDIUM: all-batch fp32 B in d_ws, fused epilogue.
        k_gemmB<<<B_ * 49 * 6, 256, 0, stream>>>(
            x, cw, d_ws, 0, 0, 384, 0, 6, BSTRIDE);
        k_outA <<<B_ * 49 * 6, 256, 0, stream>>>(
            x, cw, e0, cb, gam, bet, out0, (const void*)d_ws,
            0, 0, 0, 384, 0, 6, BSTRIDE);
        k_center<<<(NROWS * KNN + 255) / 256, 256, 0, stream>>>(e1);
    } else {
        // FALLBACK: d_out aliasing discipline (R3-proven numerics).
        k_gemmB<<<2 * 49 * 6, 256, 0, stream>>>(
            x, cw, (void*)ou, 2, 0, 384, 0, 6, BSTRIDE);
        k_outA <<<2 * 49 * 6, 256, 0, stream>>>(
            x, cw, e0, cb, gam, bet, out0, (const void*)ou,
            2, 0, 0, 384, 0, 6, BSTRIDE);
        k_gemmB<<<49 * 6, 256, 0, stream>>>(
            x, cw, (void*)ou, 1, 0, 384, 0, 6, 0);
        k_outA <<<49 * 6, 256, 0, stream>>>(
            x, cw, e0, cb, gam, bet, out0, (const void*)ou,
            1, 0, 0, 384, 0, 6, 0);
        k_gemmB<<<49 * 3, 256, 0, stream>>>(
            x, cw, (void*)ou, 0, 192, 192, 1, 3, 0);
        k_outA <<<49 * 3, 256, 0, stream>>>(
            x, cw, e0, cb, gam, bet, out0, (const void*)ou,
            0, 192, 192, 192, 1, 3, 0);
        k_gemmB<<<49 * 2, 256, 0, stream>>>(
            x, cw, (void*)ou, 0, 64, 128, 1, 2, 0);
        k_outA <<<49 * 2, 256, 0, stream>>>(
            x, cw, e0, cb, gam, bet, out0, (const void*)ou,
            0, 64, 64, 128, 1, 2, 0);
        k_gemmB<<<49 * 1, 256, 0, stream>>>(
            x, cw, (void*)e1, 0, 0, 64, 1, 1, 0);
        k_outA <<<49 * 1, 256, 0, stream>>>(
            x, cw, e0, cb, gam, bet, out0, (const void*)e1,
            0, 0, 0, 64, 1, 1, 0);
        k_center<<<(NROWS * KNN + 255) / 256, 256, 0, stream>>>(e1);
    }
}